// Round 5
// baseline (20314.175 us; speedup 1.0000x reference)
//
#include <hip/hip_runtime.h>
#include <math.h>

// Problem constants: U=H=1024, B=32, T=256.
#define UU 1024
#define BB 32
#define TT 256
#define NCHUNK 6
#define GRIDN 192

// Weight pack geometry (ushort elems). Per cell: [2 planes][sections r,z,nx,nh]
#define WPS   6291456u
#define WCELL (2u * WPS)
#define SR  0u
#define SZ  2097152u
#define SNX 4194304u
#define SNH 5242880u
// Act pack: per slot [2 planes][64 ks][4 hi][32 b][8 e]; x-half [0,32768), h-half +32768
#define APS   65536u
#define ASLOT (2u * APS)
#define AEX(u, b) ((((((u) >> 5) * 4 + (((u) >> 3) & 3)) * 32 + (b)) * 8) + ((u) & 7))

// Dynamic LDS layout (bytes)
#define LDSB     156160
#define SCR_OFF  131072   // 16 KB scratch (combine dumps / att ctx reduce)
#define GM_OFF   147456   // 8 KB gate matrix [4][2][64][4] f32
#define SC_OFF   155648   // score buffer (<=48 floats)
#define RED_OFF  155904   // [16] f32
#define MISC_OFF 155968   // finisher flag

typedef __attribute__((ext_vector_type(8))) short bf16x8;
typedef __attribute__((ext_vector_type(4))) float f32x4;
#define MF(a, b, c) __builtin_amdgcn_mfma_f32_16x16x32_bf16((a), (b), (c), 0, 0, 0)

__device__ __forceinline__ ushort bf16rne(float v) {
    uint x = __float_as_uint(v);
    uint r = (x + 0x7fffu + ((x >> 16) & 1u)) >> 16;
    return (ushort)r;
}
__device__ __forceinline__ float ubf2f(ushort u) {
    return __uint_as_float(((uint)u) << 16);
}
__device__ __forceinline__ void split2(float v, ushort& h, ushort& l) {
    h = bf16rne(v);
    l = bf16rne(v - ubf2f(h));
}

// ---------------------------------------------------------------------------
// Weight pack (unchanged from round 4, proven correct).
// ---------------------------------------------------------------------------
__global__ void packw_kernel(const float* __restrict__ Wih,
                             const float* __restrict__ Whh,
                             ushort* __restrict__ wp) {
    int tile = blockIdx.x;
    int sec, jt, ks, nks;
    size_t soff;
    if (tile < 8192) {
        sec = tile >> 12; int l = tile & 4095; jt = l >> 6; ks = l & 63; nks = 64;
        soff = sec ? SZ : SR;
    } else {
        int l2 = tile - 8192; sec = 2 + (l2 >> 11); int l = l2 & 2047; jt = l >> 5; ks = l & 31; nks = 32;
        soff = (sec == 2) ? SNX : SNH;
    }
    int p = threadIdx.x;
    int e0 = (p & 3) * 2, ul = (p >> 2) & 15, hi = p >> 6;
    int u = jt * 16 + ul;
    int kk = ks * 32 + hi * 8 + e0;
    float2 w;
    if (sec < 2) {
        int row = (sec ? 1024 : 0) + u;
        if (kk < 1024) w = *(const float2*)&Wih[(size_t)row * UU + kk];
        else           w = *(const float2*)&Whh[(size_t)row * UU + kk - 1024];
    } else if (sec == 2) {
        w = *(const float2*)&Wih[(size_t)(2048 + u) * UU + kk];
    } else {
        w = *(const float2*)&Whh[(size_t)(2048 + u) * UU + kk];
    }
    ushort h0, l0, h1, l1;
    split2(w.x, h0, l0); split2(w.y, h1, l1);
    size_t ob = soff + ((((size_t)jt * nks + ks) * 4 + hi) * 16 + ul) * 8 + e0;
    *(uint*)(wp + ob)       = (uint)h0 | ((uint)h1 << 16);
    *(uint*)(wp + WPS + ob) = (uint)l0 | ((uint)l1 << 16);
}

// ---------------------------------------------------------------------------
// q_all[t][b][u] = sum_k inputs[b][t][k] * global_W[k][u]  (fp32)
// ---------------------------------------------------------------------------
__global__ void qall_kernel(const float* __restrict__ x,
                            const float* __restrict__ gW,
                            float* __restrict__ q) {
    __shared__ float xs[32][65];
    int r0 = blockIdx.x * 32, u0 = blockIdx.y * 32;
    int tid = threadIdx.x;
    int rr = tid >> 3, ju = tid & 7;
    float4 acc = {0.f, 0.f, 0.f, 0.f};
    for (int k0 = 0; k0 < UU; k0 += 64) {
        for (int e = tid; e < 32 * 64; e += 256) {
            int lr = e >> 6, lk = e & 63;
            int r = r0 + lr;
            int tt = r >> 5, bb = r & 31;
            xs[lr][lk] = x[((size_t)bb * TT + tt) * UU + k0 + lk];
        }
        __syncthreads();
        #pragma unroll 4
        for (int kk = 0; kk < 64; ++kk) {
            float4 gv = *(const float4*)&gW[(size_t)(k0 + kk) * UU + u0 + ju * 4];
            float xv = xs[rr][kk];
            acc.x += xv * gv.x; acc.y += xv * gv.y;
            acc.z += xv * gv.z; acc.w += xv * gv.w;
        }
        __syncthreads();
    }
    *(float4*)&q[(size_t)(r0 + rr) * UU + u0 + ju * 4] = acc;
}

// ---------------------------------------------------------------------------
// Init: hist row0, Pf slots 0/1, packed h-halves, gpack x t=0/1, biases,
// plus attention counter + grid-barrier counter.
// ---------------------------------------------------------------------------
__global__ void init_kernel(const float* __restrict__ inputs,
                            const float* __restrict__ gbih, const float* __restrict__ gbhh,
                            const float* __restrict__ pbih, const float* __restrict__ pbhh,
                            const float* __restrict__ ebih, const float* __restrict__ ebhh,
                            float* __restrict__ hist, float* __restrict__ Pf,
                            ushort* __restrict__ gpack, ushort* __restrict__ ppack,
                            ushort* __restrict__ epack, float* __restrict__ biasp,
                            int* __restrict__ cnt, int* __restrict__ bar) {
    if (blockIdx.x == 0 && threadIdx.x < 33) {
        if (threadIdx.x < 32) cnt[threadIdx.x] = 0;
        else bar[0] = 0;
    }
    if (blockIdx.x < 128) {
        int i = blockIdx.x * 256 + threadIdx.x;
        int b = i >> 10, u = i & 1023;
        hist[i] = 0.f;
        Pf[i] = 0.f; Pf[32768 + i] = 0.f;
        int ex = AEX(u, b);
        int eh = ex + 32768;
        gpack[eh] = 0; gpack[APS + eh] = 0;
        ppack[eh] = 0; ppack[APS + eh] = 0;
        ppack[ASLOT + eh] = 0; ppack[ASLOT + APS + eh] = 0;
        epack[eh] = 0; epack[APS + eh] = 0;
        float x0 = inputs[((size_t)b * TT + 0) * UU + u];
        float x1 = inputs[((size_t)b * TT + 1) * UU + u];
        ushort h, l;
        split2(x0, h, l); gpack[ex] = h; gpack[APS + ex] = l;
        split2(x1, h, l); gpack[ASLOT + ex] = h; gpack[ASLOT + APS + ex] = l;
    } else {
        int idx = (blockIdx.x - 128) * 256 + threadIdx.x;
        int cell = idx >> 12, g4 = (idx >> 10) & 3, u = idx & 1023;
        const float* bih = (cell == 0) ? gbih : (cell == 1) ? pbih : ebih;
        const float* bhh = (cell == 0) ? gbhh : (cell == 1) ? pbhh : ebhh;
        float v;
        if (g4 == 0) v = bih[u] + bhh[u];
        else if (g4 == 1) v = bih[1024 + u] + bhh[1024 + u];
        else if (g4 == 2) v = bih[2048 + u];
        else v = bhh[2048 + u];
        biasp[idx] = v;
    }
}

// ---------------------------------------------------------------------------
// Software grid barrier: monotone counter. All GRIDN blocks co-resident.
// ---------------------------------------------------------------------------
__device__ __forceinline__ void grid_barrier(int* bar, int target) {
    __syncthreads();
    if (threadIdx.x == 0) {
        __threadfence();
        atomicAdd(bar, 1);
        while (__hip_atomic_load(bar, __ATOMIC_ACQUIRE, __HIP_MEMORY_SCOPE_AGENT) < target) {
            __builtin_amdgcn_s_sleep(8);
        }
        __threadfence();
    }
    __syncthreads();
}

// ---------------------------------------------------------------------------
// Persistent kernel: 192 blocks x 512 threads, 1 block/CU.
// Block = (cell = blk>>6, jt = blk&63) GEMM owner + (chunk = blk>>5, b = blk&31) att task.
// Weights: hi-plane + n-lo in VGPRs, r/z-lo in LDS — loaded ONCE.
// ---------------------------------------------------------------------------
__global__ __launch_bounds__(512, 2)
void persist_kernel(const float* __restrict__ inputs,
                    const ushort* __restrict__ wpack,
                    const float* __restrict__ biasp,
                    ushort* __restrict__ gpack, ushort* __restrict__ ppack,
                    ushort* __restrict__ epack,
                    float* __restrict__ hist, float* __restrict__ Pf,
                    const float* __restrict__ qall,
                    float* __restrict__ out,
                    float* __restrict__ attC, float* __restrict__ attML,
                    int* __restrict__ cnt, int* __restrict__ bar) {
    extern __shared__ char smraw[];
    float* lds_scr = (float*)(smraw + SCR_OFF);
    float* lds_gm  = (float*)(smraw + GM_OFF);
    float* lds_sc  = (float*)(smraw + SC_OFF);
    float* lds_red = (float*)(smraw + RED_OFF);
    int*   lds_flag = (int*)(smraw + MISC_OFF);

    const int blk = blockIdx.x, tid = threadIdx.x;
    const int cell = blk >> 6, jt = blk & 63;
    const int w = tid >> 6, lane = tid & 63;
    const int l15 = lane & 15, hi4 = lane >> 4;
    const int ab = blk & 31, ac = blk >> 5;   // attention task
    const ushort* wp = wpack + (size_t)cell * WCELL;

    // ---- load persistent weights ----
    bf16x8 whiR[8], whiZ[8], whiNX[4], whiNH[4], wloNX[4], wloNH[4];
    #pragma unroll
    for (int i = 0; i < 8; ++i) {
        const int ks = w * 8 + i;
        const size_t aoff = ((size_t)(jt * 256 + ks * 4 + hi4)) * 128 + (size_t)l15 * 8;
        whiR[i] = *(const bf16x8*)(wp + SR + aoff);
        whiZ[i] = *(const bf16x8*)(wp + SZ + aoff);
        bf16x8 rlo = *(const bf16x8*)(wp + SR + WPS + aoff);
        bf16x8 zlo = *(const bf16x8*)(wp + SZ + WPS + aoff);
        *(bf16x8*)(smraw + (((w * 16 + i) * 64 + lane) << 4)) = rlo;
        *(bf16x8*)(smraw + (((w * 16 + 8 + i) * 64 + lane) << 4)) = zlo;
    }
    #pragma unroll
    for (int i = 0; i < 4; ++i) {
        const int ks = w * 4 + i;
        const size_t aoff = ((size_t)(jt * 128 + ks * 4 + hi4)) * 128 + (size_t)l15 * 8;
        whiNX[i] = *(const bf16x8*)(wp + SNX + aoff);
        whiNH[i] = *(const bf16x8*)(wp + SNH + aoff);
        wloNX[i] = *(const bf16x8*)(wp + SNX + WPS + aoff);
        wloNH[i] = *(const bf16x8*)(wp + SNH + WPS + aoff);
    }
    // per-thread epilogue constants
    const int ebt = tid >> 8, eli = (tid >> 2) & 63, ei = tid & 3;
    const int eb = ebt * 16 + (eli & 15);
    const int eu = jt * 16 + (eli >> 4) * 4 + ei;
    const float* bc = biasp + cell * 4096;
    const float br  = bc[eu];
    const float bz  = bc[1024 + eu];
    const float bni = bc[2048 + eu];
    const float bnh = bc[3072 + eu];
    const int eex = AEX(eu, eb);
    __syncthreads();

    int ep = 0;
    for (int t = 0; t <= TT + 1; ++t) {
        const int tc = t - cell;
        const bool gemmWork = (tc >= 0 && tc < TT);
        f32x4 accR0 = {0,0,0,0}, accR1 = {0,0,0,0};
        f32x4 accZ0 = {0,0,0,0}, accZ1 = {0,0,0,0};
        f32x4 accNX0 = {0,0,0,0}, accNX1 = {0,0,0,0};
        f32x4 accNH0 = {0,0,0,0}, accNH1 = {0,0,0,0};
        if (gemmWork) {
            ushort* apk = (cell == 0) ? gpack : (cell == 1) ? ppack : epack;
            const ushort* ap = apk + (size_t)(tc & 3) * ASLOT;
            const ushort* bb = ap + ((size_t)hi4 * 32 + l15) * 8;
            #pragma unroll
            for (int i = 0; i < 8; ++i) {
                const int ks = w * 8 + i;
                const ushort* bp = bb + (size_t)ks * 1024;
                bf16x8 bh0 = *(const bf16x8*)(bp);
                bf16x8 bh1 = *(const bf16x8*)(bp + 128);
                bf16x8 bl0 = *(const bf16x8*)(bp + APS);
                bf16x8 bl1 = *(const bf16x8*)(bp + APS + 128);
                bf16x8 rlo = *(const bf16x8*)(smraw + (((w * 16 + i) * 64 + lane) << 4));
                bf16x8 zlo = *(const bf16x8*)(smraw + (((w * 16 + 8 + i) * 64 + lane) << 4));
                accR0 = MF(whiR[i], bh0, accR0); accR0 = MF(whiR[i], bl0, accR0); accR0 = MF(rlo, bh0, accR0);
                accR1 = MF(whiR[i], bh1, accR1); accR1 = MF(whiR[i], bl1, accR1); accR1 = MF(rlo, bh1, accR1);
                accZ0 = MF(whiZ[i], bh0, accZ0); accZ0 = MF(whiZ[i], bl0, accZ0); accZ0 = MF(zlo, bh0, accZ0);
                accZ1 = MF(whiZ[i], bh1, accZ1); accZ1 = MF(whiZ[i], bl1, accZ1); accZ1 = MF(zlo, bh1, accZ1);
            }
            #pragma unroll
            for (int i = 0; i < 4; ++i) {
                const int ksx = w * 4 + i;
                const int ksh = 32 + w * 4 + i;
                const ushort* bpx = bb + (size_t)ksx * 1024;
                const ushort* bph = bb + (size_t)ksh * 1024;
                bf16x8 xh0 = *(const bf16x8*)(bpx);
                bf16x8 xh1 = *(const bf16x8*)(bpx + 128);
                bf16x8 xl0 = *(const bf16x8*)(bpx + APS);
                bf16x8 xl1 = *(const bf16x8*)(bpx + APS + 128);
                bf16x8 hh0 = *(const bf16x8*)(bph);
                bf16x8 hh1 = *(const bf16x8*)(bph + 128);
                bf16x8 hl0 = *(const bf16x8*)(bph + APS);
                bf16x8 hl1 = *(const bf16x8*)(bph + APS + 128);
                accNX0 = MF(whiNX[i], xh0, accNX0); accNX0 = MF(whiNX[i], xl0, accNX0); accNX0 = MF(wloNX[i], xh0, accNX0);
                accNX1 = MF(whiNX[i], xh1, accNX1); accNX1 = MF(whiNX[i], xl1, accNX1); accNX1 = MF(wloNX[i], xh1, accNX1);
                accNH0 = MF(whiNH[i], hh0, accNH0); accNH0 = MF(whiNH[i], hl0, accNH0); accNH0 = MF(wloNH[i], hh0, accNH0);
                accNH1 = MF(whiNH[i], hh1, accNH1); accNH1 = MF(whiNH[i], hl1, accNH1); accNH1 = MF(wloNH[i], hh1, accNH1);
            }
        }
        // ---- cross-wave K combine: 4 rounds (R, Z, NX, NH) via 16KB scratch ----
        const int rset = tid >> 8, rln = (tid >> 2) & 63, ri = tid & 3;
        __syncthreads();
        #define COMBINE_ROUND(g, A0, A1) \
            *(f32x4*)&lds_scr[(((0 * 8 + w) * 64 + lane)) * 4] = A0; \
            *(f32x4*)&lds_scr[(((1 * 8 + w) * 64 + lane)) * 4] = A1; \
            __syncthreads(); \
            { float s_ = 0.f; \
              _Pragma("unroll") \
              for (int w2 = 0; w2 < 8; ++w2) s_ += lds_scr[((rset * 8 + w2) * 64 + rln) * 4 + ri]; \
              lds_gm[(((g) * 2 + rset) * 64 + rln) * 4 + ri] = s_; } \
            __syncthreads();
        COMBINE_ROUND(0, accR0, accR1)
        COMBINE_ROUND(1, accZ0, accZ1)
        COMBINE_ROUND(2, accNX0, accNX1)
        COMBINE_ROUND(3, accNH0, accNH1)
        #undef COMBINE_ROUND
        // ---- epilogue ----
        if (gemmWork) {
            const float R  = lds_gm[((0 * 2 + ebt) * 64 + eli) * 4 + ei];
            const float Z  = lds_gm[((1 * 2 + ebt) * 64 + eli) * 4 + ei];
            const float iN = lds_gm[((2 * 2 + ebt) * 64 + eli) * 4 + ei];
            const float hN = lds_gm[((3 * 2 + ebt) * 64 + eli) * 4 + ei];
            float hprev;
            if (cell == 0)      hprev = hist[((size_t)tc * BB + eb) * UU + eu];
            else if (cell == 1) hprev = Pf[(size_t)(tc & 3) * BB * UU + (size_t)eb * UU + eu];
            else                hprev = (tc > 0) ? out[((size_t)eb * TT + tc - 1) * UU + eu] : 0.f;
            const float r = 1.f / (1.f + expf(-(R + br)));
            const float z = 1.f / (1.f + expf(-(Z + bz)));
            const float n2 = tanhf(iN + bni + r * (hN + bnh));
            const float val = (1.f - z) * n2 + z * hprev;
            ushort vh, vl; split2(val, vh, vl);
            if (cell == 0) {
                hist[((size_t)(tc + 1) * BB + eb) * UU + eu] = val;
                ushort* d = gpack + (size_t)((tc + 1) & 3) * ASLOT;
                d[eex + 32768] = vh; d[APS + eex + 32768] = vl;
            } else if (cell == 1) {
                ushort* d = epack + (size_t)(tc & 3) * ASLOT;
                d[eex] = vh; d[APS + eex] = vl;
                if (tc + 2 < TT) {
                    Pf[(size_t)((tc + 2) & 3) * BB * UU + (size_t)eb * UU + eu] = val;
                    ushort* d2 = ppack + (size_t)((tc + 2) & 3) * ASLOT;
                    d2[eex + 32768] = vh; d2[APS + eex + 32768] = vl;
                    const float gx = val + inputs[((size_t)eb * TT + tc + 2) * UU + eu];
                    ushort gh, gl; split2(gx, gh, gl);
                    ushort* d3 = gpack + (size_t)((tc + 2) & 3) * ASLOT;
                    d3[eex] = gh; d3[APS + eex] = gl;
                }
            } else {
                out[((size_t)eb * TT + tc) * UU + eu] = val;
                if (tc + 1 < TT) {
                    ushort* d = epack + (size_t)((tc + 1) & 3) * ASLOT;
                    d[eex + 32768] = vh; d[APS + eex + 32768] = vl;
                }
            }
        }
        // ---- attention chunk (ac, ab) + finisher combine ----
        if (t < TT) {
            const int nt2 = t + 1;
            const int cstr = (nt2 + NCHUNK - 1) / NCHUNK;
            const int r0 = ac * cstr;
            const int r1e = r0 + cstr;
            const int r1 = (r1e < nt2) ? r1e : nt2;
            const int n = r1 - r0;
            const float* qb = qall + ((size_t)t * BB + ab) * UU;
            float4 q0 = *(const float4*)&qb[lane * 4];
            float4 q1 = *(const float4*)&qb[256 + lane * 4];
            float4 q2 = *(const float4*)&qb[512 + lane * 4];
            float4 q3 = *(const float4*)&qb[768 + lane * 4];
            for (int tp = r0 + w; tp < r1; tp += 8) {
                const float* hr = hist + ((size_t)tp * BB + ab) * UU;
                float4 h0 = *(const float4*)&hr[lane * 4];
                float4 h1 = *(const float4*)&hr[256 + lane * 4];
                float4 h2 = *(const float4*)&hr[512 + lane * 4];
                float4 h3 = *(const float4*)&hr[768 + lane * 4];
                float s = h0.x*q0.x + h0.y*q0.y + h0.z*q0.z + h0.w*q0.w
                        + h1.x*q1.x + h1.y*q1.y + h1.z*q1.z + h1.w*q1.w
                        + h2.x*q2.x + h2.y*q2.y + h2.z*q2.z + h2.w*q2.w
                        + h3.x*q3.x + h3.y*q3.y + h3.z*q3.z + h3.w*q3.w;
                #pragma unroll
                for (int off = 32; off; off >>= 1) s += __shfl_xor(s, off);
                if (lane == 0) lds_sc[tp - r0] = s;
            }
            __syncthreads();
            float v = (tid < n) ? lds_sc[tid] : -INFINITY;
            float mx = v;
            #pragma unroll
            for (int off = 32; off; off >>= 1) mx = fmaxf(mx, __shfl_xor(mx, off));
            if (lane == 0) lds_red[w] = mx;
            __syncthreads();
            mx = lds_red[0];
            #pragma unroll
            for (int w2 = 1; w2 < 8; ++w2) mx = fmaxf(mx, lds_red[w2]);
            float ev = (tid < n) ? expf(v - mx) : 0.f;
            float ssum = ev;
            #pragma unroll
            for (int off = 32; off; off >>= 1) ssum += __shfl_xor(ssum, off);
            if (lane == 0) lds_red[8 + w] = ssum;
            __syncthreads();
            float lsum = 0.f;
            #pragma unroll
            for (int w2 = 0; w2 < 8; ++w2) lsum += lds_red[8 + w2];
            if (tid < n) lds_sc[tid] = ev;
            if (tid == 0) {
                attML[((size_t)ac * BB + ab) * 2]     = (n > 0) ? mx : -INFINITY;
                attML[((size_t)ac * BB + ab) * 2 + 1] = (n > 0) ? lsum : 0.f;
            }
            __syncthreads();
            #pragma unroll
            for (int half = 0; half < 2; ++half) {
                float4 a0 = {0,0,0,0}, a1 = {0,0,0,0};
                for (int i2 = w; i2 < n; i2 += 8) {
                    const float a = lds_sc[i2];
                    const float* hr = hist + ((size_t)(r0 + i2) * BB + ab) * UU + half * 512;
                    float4 h0 = *(const float4*)&hr[lane * 4];
                    float4 h1 = *(const float4*)&hr[256 + lane * 4];
                    a0.x += a*h0.x; a0.y += a*h0.y; a0.z += a*h0.z; a0.w += a*h0.w;
                    a1.x += a*h1.x; a1.y += a*h1.y; a1.z += a*h1.z; a1.w += a*h1.w;
                }
                *(float4*)&lds_scr[w * 512 + lane * 4] = a0;
                *(float4*)&lds_scr[w * 512 + 256 + lane * 4] = a1;
                __syncthreads();
                float s2 = 0.f;
                #pragma unroll
                for (int w2 = 0; w2 < 8; ++w2) s2 += lds_scr[w2 * 512 + tid];
                attC[((size_t)ac * BB + ab) * UU + half * 512 + tid] = s2;
                __syncthreads();
            }
            __threadfence();
            if (tid == 0) {
                int old = atomicAdd(cnt + ab, 1);
                lds_flag[0] = ((old % NCHUNK) == (NCHUNK - 1)) ? 1 : 0;
            }
            __syncthreads();
            if (lds_flag[0]) {
                __threadfence();
                float mm[NCHUNK], ll[NCHUNK];
                #pragma unroll
                for (int c = 0; c < NCHUNK; ++c) {
                    mm[c] = attML[((size_t)c * BB + ab) * 2];
                    ll[c] = attML[((size_t)c * BB + ab) * 2 + 1];
                }
                float M = mm[0];
                #pragma unroll
                for (int c = 1; c < NCHUNK; ++c) M = fmaxf(M, mm[c]);
                float den = 0.f, wc[NCHUNK];
                #pragma unroll
                for (int c = 0; c < NCHUNK; ++c) { wc[c] = expf(mm[c] - M); den += wc[c] * ll[c]; }
                const float inv = 1.f / den;
                ushort* d = ppack + (size_t)(t & 3) * ASLOT;
                #pragma unroll
                for (int rep = 0; rep < 2; ++rep) {
                    const int e = tid + rep * 512;
                    float s3 = 0.f;
                    #pragma unroll
                    for (int c = 0; c < NCHUNK; ++c) s3 += wc[c] * attC[((size_t)c * BB + ab) * UU + e];
                    const float xv = s3 * inv + inputs[((size_t)ab * TT + t) * UU + e];
                    ushort vh2, vl2; split2(xv, vh2, vl2);
                    const int ex2 = AEX(e, ab);
                    d[ex2] = vh2; d[APS + ex2] = vl2;
                }
            }
        }
        ++ep;
        grid_barrier(bar, GRIDN * ep);
    }
}

extern "C" void kernel_launch(void* const* d_in, const int* in_sizes, int n_in,
                              void* d_out, int out_size, void* d_ws, size_t ws_size,
                              hipStream_t stream) {
    (void)in_sizes; (void)n_in; (void)out_size; (void)ws_size;
    const float* inputs = (const float*)d_in[0];
    const float* gW   = (const float*)d_in[1];
    const float* gWih = (const float*)d_in[2];
    const float* gWhh = (const float*)d_in[3];
    const float* gbih = (const float*)d_in[4];
    const float* gbhh = (const float*)d_in[5];
    const float* pWih = (const float*)d_in[6];
    const float* pWhh = (const float*)d_in[7];
    const float* pbih = (const float*)d_in[8];
    const float* pbhh = (const float*)d_in[9];
    const float* eWih = (const float*)d_in[10];
    const float* eWhh = (const float*)d_in[11];
    const float* ebih = (const float*)d_in[12];
    const float* ebhh = (const float*)d_in[13];
    float* out = (float*)d_out;

    char* ws = (char*)d_ws;
    size_t off = 0;
    auto alloc = [&](size_t bytes) {
        void* p = ws + off;
        off += (bytes + 255) & ~(size_t)255;
        return p;
    };
    ushort* wpack = (ushort*)alloc((size_t)3 * WCELL * 2);
    ushort* gpack = (ushort*)alloc((size_t)4 * ASLOT * 2);
    ushort* ppack = (ushort*)alloc((size_t)4 * ASLOT * 2);
    ushort* epack = (ushort*)alloc((size_t)4 * ASLOT * 2);
    float* hist  = (float*)alloc((size_t)(TT + 1) * BB * UU * 4);
    float* qall  = (float*)alloc((size_t)TT * BB * UU * 4);
    float* Pf    = (float*)alloc((size_t)4 * BB * UU * 4);
    float* biasp = (float*)alloc((size_t)3 * 4096 * 4);
    float* attC  = (float*)alloc((size_t)NCHUNK * BB * UU * 4);
    float* attML = (float*)alloc((size_t)NCHUNK * BB * 2 * 4);
    int*   cnt   = (int*)alloc(32 * 4);
    int*   bar   = (int*)alloc(4);

    packw_kernel<<<12288, 256, 0, stream>>>(gWih, gWhh, wpack);
    packw_kernel<<<12288, 256, 0, stream>>>(pWih, pWhh, wpack + WCELL);
    packw_kernel<<<12288, 256, 0, stream>>>(eWih, eWhh, wpack + 2 * (size_t)WCELL);
    qall_kernel<<<dim3(256, 32), 256, 0, stream>>>(inputs, gW, qall);
    init_kernel<<<176, 256, 0, stream>>>(inputs, gbih, gbhh, pbih, pbhh, ebih, ebhh,
                                         hist, Pf, gpack, ppack, epack, biasp, cnt, bar);

    hipFuncSetAttribute((const void*)persist_kernel,
                        hipFuncAttributeMaxDynamicSharedMemorySize, LDSB);
    void* args[] = {(void*)&inputs, (void*)&wpack, (void*)&biasp,
                    (void*)&gpack, (void*)&ppack, (void*)&epack,
                    (void*)&hist, (void*)&Pf, (void*)&qall, (void*)&out,
                    (void*)&attC, (void*)&attML, (void*)&cnt, (void*)&bar};
    hipError_t ce = hipLaunchCooperativeKernel((const void*)persist_kernel,
                                               dim3(GRIDN), dim3(512), args,
                                               (unsigned)LDSB, stream);
    if (ce != hipSuccess) {
        (void)hipGetLastError();
        // All 192 blocks (1/CU, LDS-bound) are co-resident on a 256-CU part;
        // the software barrier works under a plain launch too.
        persist_kernel<<<GRIDN, 512, LDSB, stream>>>(inputs, wpack, biasp,
                                                     gpack, ppack, epack,
                                                     hist, Pf, qall, out,
                                                     attC, attML, cnt, bar);
    }
}

// Round 6
// 19760.017 us; speedup vs baseline: 1.0280x; 1.0280x over previous
//
#include <hip/hip_runtime.h>
#include <math.h>

// Problem constants: U=H=1024, B=32, T=256.
#define UU 1024
#define BB 32
#define TT 256
#define NCHUNK 6
#define GRIDN 192

// Weight pack geometry (ushort elems). Per cell: [2 planes][sections r,z,nx,nh]
#define WPS   6291456u
#define WCELL (2u * WPS)
#define SR  0u
#define SZ  2097152u
#define SNX 4194304u
#define SNH 5242880u
// Act pack: per slot [2 planes][64 ks][4 hi][32 b][8 e]; x-half [0,32768), h-half +32768
#define APS   65536u
#define ASLOT (2u * APS)
#define AEX(u, b) ((((((u) >> 5) * 4 + (((u) >> 3) & 3)) * 32 + (b)) * 8) + ((u) & 7))

// Dynamic LDS layout (bytes): [0,128K) r/z lo-plane weights; then scratch.
#define SCR_OFF  131072   // 16 KB scratch (combine dumps / att ctx reduce)
#define GM_OFF   147456   // 8 KB gate matrix [4 gates][2 bt][64 lane][4]
#define RED_OFF  155648   // 16 f32
#define FLAG_OFF 155712
#define LDSB     155776

typedef __attribute__((ext_vector_type(8))) short bf16x8;
typedef __attribute__((ext_vector_type(4))) float f32x4;
#define MF(a, b, c) __builtin_amdgcn_mfma_f32_16x16x32_bf16((a), (b), (c), 0, 0, 0)

__device__ __forceinline__ ushort bf16rne(float v) {
    uint x = __float_as_uint(v);
    uint r = (x + 0x7fffu + ((x >> 16) & 1u)) >> 16;
    return (ushort)r;
}
__device__ __forceinline__ float ubf2f(ushort u) {
    return __uint_as_float(((uint)u) << 16);
}
__device__ __forceinline__ void split2(float v, ushort& h, ushort& l) {
    h = bf16rne(v);
    l = bf16rne(v - ubf2f(h));
}

// ---------------------------------------------------------------------------
// Weight pack (unchanged, proven).
// ---------------------------------------------------------------------------
__global__ void packw_kernel(const float* __restrict__ Wih,
                             const float* __restrict__ Whh,
                             ushort* __restrict__ wp) {
    int tile = blockIdx.x;
    int sec, jt, ks, nks;
    size_t soff;
    if (tile < 8192) {
        sec = tile >> 12; int l = tile & 4095; jt = l >> 6; ks = l & 63; nks = 64;
        soff = sec ? SZ : SR;
    } else {
        int l2 = tile - 8192; sec = 2 + (l2 >> 11); int l = l2 & 2047; jt = l >> 5; ks = l & 31; nks = 32;
        soff = (sec == 2) ? SNX : SNH;
    }
    int p = threadIdx.x;
    int e0 = (p & 3) * 2, ul = (p >> 2) & 15, hi = p >> 6;
    int u = jt * 16 + ul;
    int kk = ks * 32 + hi * 8 + e0;
    float2 w;
    if (sec < 2) {
        int row = (sec ? 1024 : 0) + u;
        if (kk < 1024) w = *(const float2*)&Wih[(size_t)row * UU + kk];
        else           w = *(const float2*)&Whh[(size_t)row * UU + kk - 1024];
    } else if (sec == 2) {
        w = *(const float2*)&Wih[(size_t)(2048 + u) * UU + kk];
    } else {
        w = *(const float2*)&Whh[(size_t)(2048 + u) * UU + kk];
    }
    ushort h0, l0, h1, l1;
    split2(w.x, h0, l0); split2(w.y, h1, l1);
    size_t ob = soff + ((((size_t)jt * nks + ks) * 4 + hi) * 16 + ul) * 8 + e0;
    *(uint*)(wp + ob)       = (uint)h0 | ((uint)h1 << 16);
    *(uint*)(wp + WPS + ob) = (uint)l0 | ((uint)l1 << 16);
}

// ---------------------------------------------------------------------------
// q_all[t][b][u] = sum_k inputs[b][t][k] * global_W[k][u]  (fp32)
// ---------------------------------------------------------------------------
__global__ void qall_kernel(const float* __restrict__ x,
                            const float* __restrict__ gW,
                            float* __restrict__ q) {
    __shared__ float xs[32][65];
    int r0 = blockIdx.x * 32, u0 = blockIdx.y * 32;
    int tid = threadIdx.x;
    int rr = tid >> 3, ju = tid & 7;
    float4 acc = {0.f, 0.f, 0.f, 0.f};
    for (int k0 = 0; k0 < UU; k0 += 64) {
        for (int e = tid; e < 32 * 64; e += 256) {
            int lr = e >> 6, lk = e & 63;
            int r = r0 + lr;
            int tt = r >> 5, bb = r & 31;
            xs[lr][lk] = x[((size_t)bb * TT + tt) * UU + k0 + lk];
        }
        __syncthreads();
        #pragma unroll 4
        for (int kk = 0; kk < 64; ++kk) {
            float4 gv = *(const float4*)&gW[(size_t)(k0 + kk) * UU + u0 + ju * 4];
            float xv = xs[rr][kk];
            acc.x += xv * gv.x; acc.y += xv * gv.y;
            acc.z += xv * gv.z; acc.w += xv * gv.w;
        }
        __syncthreads();
    }
    *(float4*)&q[(size_t)(r0 + rr) * UU + u0 + ju * 4] = acc;
}

// ---------------------------------------------------------------------------
// Init (unchanged, proven).
// ---------------------------------------------------------------------------
__global__ void init_kernel(const float* __restrict__ inputs,
                            const float* __restrict__ gbih, const float* __restrict__ gbhh,
                            const float* __restrict__ pbih, const float* __restrict__ pbhh,
                            const float* __restrict__ ebih, const float* __restrict__ ebhh,
                            float* __restrict__ hist, float* __restrict__ Pf,
                            ushort* __restrict__ gpack, ushort* __restrict__ ppack,
                            ushort* __restrict__ epack, float* __restrict__ biasp,
                            int* __restrict__ cnt, int* __restrict__ bar) {
    if (blockIdx.x == 0 && threadIdx.x < 33) {
        if (threadIdx.x < 32) cnt[threadIdx.x] = 0;
        else bar[0] = 0;
    }
    if (blockIdx.x < 128) {
        int i = blockIdx.x * 256 + threadIdx.x;
        int b = i >> 10, u = i & 1023;
        hist[i] = 0.f;
        Pf[i] = 0.f; Pf[32768 + i] = 0.f;
        int ex = AEX(u, b);
        int eh = ex + 32768;
        gpack[eh] = 0; gpack[APS + eh] = 0;
        ppack[eh] = 0; ppack[APS + eh] = 0;
        ppack[ASLOT + eh] = 0; ppack[ASLOT + APS + eh] = 0;
        epack[eh] = 0; epack[APS + eh] = 0;
        float x0 = inputs[((size_t)b * TT + 0) * UU + u];
        float x1 = inputs[((size_t)b * TT + 1) * UU + u];
        ushort h, l;
        split2(x0, h, l); gpack[ex] = h; gpack[APS + ex] = l;
        split2(x1, h, l); gpack[ASLOT + ex] = h; gpack[ASLOT + APS + ex] = l;
    } else {
        int idx = (blockIdx.x - 128) * 256 + threadIdx.x;
        int cell = idx >> 12, g4 = (idx >> 10) & 3, u = idx & 1023;
        const float* bih = (cell == 0) ? gbih : (cell == 1) ? pbih : ebih;
        const float* bhh = (cell == 0) ? gbhh : (cell == 1) ? pbhh : ebhh;
        float v;
        if (g4 == 0) v = bih[u] + bhh[u];
        else if (g4 == 1) v = bih[1024 + u] + bhh[1024 + u];
        else if (g4 == 2) v = bih[2048 + u];
        else v = bhh[2048 + u];
        biasp[idx] = v;
    }
}

__device__ __forceinline__ void grid_barrier(int* bar, int target) {
    __syncthreads();
    if (threadIdx.x == 0) {
        __threadfence();
        atomicAdd(bar, 1);
        while (__hip_atomic_load(bar, __ATOMIC_ACQUIRE, __HIP_MEMORY_SCOPE_AGENT) < target) {
            __builtin_amdgcn_s_sleep(8);
        }
        __threadfence();
    }
    __syncthreads();
}

// ---------------------------------------------------------------------------
// Persistent kernel v2: 192 blocks x 256 threads, 1 block/CU, VGPR cap 512.
// Wave w owns K-quarter: R/Z ks = w*16..w*16+15; N reuses the SAME b-frags
// (waves 0/1 -> nx halves, waves 2/3 -> nh halves).
// Registers: hi R/Z/N + lo N (64 bf16x8 = 256 regs). LDS: lo R/Z (128 KB).
// ---------------------------------------------------------------------------
__global__ __launch_bounds__(256, 1)
void persist_kernel(const float* __restrict__ inputs,
                    const ushort* __restrict__ wpack,
                    const float* __restrict__ biasp,
                    ushort* __restrict__ gpack, ushort* __restrict__ ppack,
                    ushort* __restrict__ epack,
                    float* __restrict__ hist, float* __restrict__ Pf,
                    const float* __restrict__ qall,
                    float* __restrict__ out,
                    float* __restrict__ attC, float* __restrict__ attML,
                    int* __restrict__ cnt, int* __restrict__ bar) {
    extern __shared__ char smraw[];
    float* lds_scr  = (float*)(smraw + SCR_OFF);
    float* lds_gm   = (float*)(smraw + GM_OFF);
    float* lds_red  = (float*)(smraw + RED_OFF);
    int*   lds_flag = (int*)(smraw + FLAG_OFF);

    const int blk = blockIdx.x, tid = threadIdx.x;
    const int cell = blk >> 6, jt = blk & 63;
    const int w = tid >> 6, lane = tid & 63;
    const int l15 = lane & 15, hi4 = lane >> 4;
    const int ab = blk & 31, ac = blk >> 5;
    const ushort* wp = wpack + (size_t)cell * WCELL;

    // ---- persistent weights ----
    bf16x8 whiR[16], whiZ[16], whiN[16], wloN[16];
    #pragma unroll
    for (int i = 0; i < 16; ++i) {
        const int ks = w * 16 + i;
        const size_t aoff = ((size_t)(jt * 256 + ks * 4 + hi4)) * 128 + (size_t)l15 * 8;
        whiR[i] = *(const bf16x8*)(wp + SR + aoff);
        whiZ[i] = *(const bf16x8*)(wp + SZ + aoff);
        bf16x8 rlo = *(const bf16x8*)(wp + SR + WPS + aoff);
        bf16x8 zlo = *(const bf16x8*)(wp + SZ + WPS + aoff);
        *(bf16x8*)(smraw + (((w * 32 + i) * 64 + lane) << 4)) = rlo;
        *(bf16x8*)(smraw + (((w * 32 + 16 + i) * 64 + lane) << 4)) = zlo;
        const int ksn = (w & 1) * 16 + i;
        const size_t noff = ((size_t)(jt * 128 + ksn * 4 + hi4)) * 128 + (size_t)l15 * 8;
        const size_t sN = (w < 2) ? SNX : SNH;
        whiN[i] = *(const bf16x8*)(wp + sN + noff);
        wloN[i] = *(const bf16x8*)(wp + sN + WPS + noff);
    }
    // ---- epilogue constants (2 outputs/thread) ----
    int eb_[2], eu_[2], eex_[2];
    float bR_[2], bZ_[2], bNI_[2], bNH_[2];
    {
        const float* bc = biasp + cell * 4096;
        #pragma unroll
        for (int rep = 0; rep < 2; ++rep) {
            const int e = tid + rep * 256;
            const int ebt = e >> 8, eli = (e >> 2) & 63, ei = e & 3;
            eb_[rep] = ebt * 16 + (eli & 15);
            eu_[rep] = jt * 16 + (eli >> 4) * 4 + ei;
            eex_[rep] = AEX(eu_[rep], eb_[rep]);
            bR_[rep]  = bc[eu_[rep]];
            bZ_[rep]  = bc[1024 + eu_[rep]];
            bNI_[rep] = bc[2048 + eu_[rep]];
            bNH_[rep] = bc[3072 + eu_[rep]];
        }
    }
    __syncthreads();

    int ep = 0;
    for (int t = 0; t <= TT + 1; ++t) {
        const int tc = t - cell;
        const bool gemmWork = (tc >= 0 && tc < TT);
        if (gemmWork) {
            f32x4 aR0 = {0,0,0,0}, aR1 = {0,0,0,0};
            f32x4 aZ0 = {0,0,0,0}, aZ1 = {0,0,0,0};
            f32x4 aN0 = {0,0,0,0}, aN1 = {0,0,0,0};
            ushort* apk = (cell == 0) ? gpack : (cell == 1) ? ppack : epack;
            const ushort* ap = apk + (size_t)(tc & 3) * ASLOT;
            const ushort* bbp = ap + ((size_t)hi4 * 32 + l15) * 8;
            #pragma unroll
            for (int i = 0; i < 16; ++i) {
                const int ks = w * 16 + i;
                const ushort* bp = bbp + (size_t)ks * 1024;
                bf16x8 bh0 = *(const bf16x8*)(bp);
                bf16x8 bh1 = *(const bf16x8*)(bp + 128);
                bf16x8 bl0 = *(const bf16x8*)(bp + APS);
                bf16x8 bl1 = *(const bf16x8*)(bp + APS + 128);
                bf16x8 rlo = *(const bf16x8*)(smraw + (((w * 32 + i) * 64 + lane) << 4));
                bf16x8 zlo = *(const bf16x8*)(smraw + (((w * 32 + 16 + i) * 64 + lane) << 4));
                aR0 = MF(whiR[i], bh0, aR0); aR0 = MF(whiR[i], bl0, aR0); aR0 = MF(rlo, bh0, aR0);
                aR1 = MF(whiR[i], bh1, aR1); aR1 = MF(whiR[i], bl1, aR1); aR1 = MF(rlo, bh1, aR1);
                aZ0 = MF(whiZ[i], bh0, aZ0); aZ0 = MF(whiZ[i], bl0, aZ0); aZ0 = MF(zlo, bh0, aZ0);
                aZ1 = MF(whiZ[i], bh1, aZ1); aZ1 = MF(whiZ[i], bl1, aZ1); aZ1 = MF(zlo, bh1, aZ1);
                aN0 = MF(whiN[i], bh0, aN0); aN0 = MF(whiN[i], bl0, aN0); aN0 = MF(wloN[i], bh0, aN0);
                aN1 = MF(whiN[i], bh1, aN1); aN1 = MF(whiN[i], bl1, aN1); aN1 = MF(wloN[i], bh1, aN1);
            }
            // ---- combine rounds: R -> gm0, Z -> gm1, N -> gm2 (iN), gm3 (hN) ----
            __syncthreads();
            *(f32x4*)&lds_scr[((0 * 4 + w) * 64 + lane) * 4] = aR0;
            *(f32x4*)&lds_scr[((1 * 4 + w) * 64 + lane) * 4] = aR1;
            __syncthreads();
            #pragma unroll
            for (int rep = 0; rep < 2; ++rep) {
                const int e = tid + rep * 256;
                const int bt = e >> 8, ln = (e >> 2) & 63, c = e & 3;
                float s = lds_scr[((bt * 4 + 0) * 64 + ln) * 4 + c] + lds_scr[((bt * 4 + 1) * 64 + ln) * 4 + c]
                        + lds_scr[((bt * 4 + 2) * 64 + ln) * 4 + c] + lds_scr[((bt * 4 + 3) * 64 + ln) * 4 + c];
                lds_gm[((0 * 2 + bt) * 64 + ln) * 4 + c] = s;
            }
            __syncthreads();
            *(f32x4*)&lds_scr[((0 * 4 + w) * 64 + lane) * 4] = aZ0;
            *(f32x4*)&lds_scr[((1 * 4 + w) * 64 + lane) * 4] = aZ1;
            __syncthreads();
            #pragma unroll
            for (int rep = 0; rep < 2; ++rep) {
                const int e = tid + rep * 256;
                const int bt = e >> 8, ln = (e >> 2) & 63, c = e & 3;
                float s = lds_scr[((bt * 4 + 0) * 64 + ln) * 4 + c] + lds_scr[((bt * 4 + 1) * 64 + ln) * 4 + c]
                        + lds_scr[((bt * 4 + 2) * 64 + ln) * 4 + c] + lds_scr[((bt * 4 + 3) * 64 + ln) * 4 + c];
                lds_gm[((1 * 2 + bt) * 64 + ln) * 4 + c] = s;
            }
            __syncthreads();
            *(f32x4*)&lds_scr[((0 * 4 + w) * 64 + lane) * 4] = aN0;
            *(f32x4*)&lds_scr[((1 * 4 + w) * 64 + lane) * 4] = aN1;
            __syncthreads();
            #pragma unroll
            for (int rep = 0; rep < 2; ++rep) {
                const int e = tid + rep * 256;
                const int bt = e >> 8, ln = (e >> 2) & 63, c = e & 3;
                float iN = lds_scr[((bt * 4 + 0) * 64 + ln) * 4 + c] + lds_scr[((bt * 4 + 1) * 64 + ln) * 4 + c];
                float hN = lds_scr[((bt * 4 + 2) * 64 + ln) * 4 + c] + lds_scr[((bt * 4 + 3) * 64 + ln) * 4 + c];
                lds_gm[((2 * 2 + bt) * 64 + ln) * 4 + c] = iN;
                lds_gm[((3 * 2 + bt) * 64 + ln) * 4 + c] = hN;
            }
            __syncthreads();
            // ---- epilogue (2 outputs/thread) ----
            #pragma unroll
            for (int rep = 0; rep < 2; ++rep) {
                const int e = tid + rep * 256;
                const int ebt = e >> 8, eli = (e >> 2) & 63, ei = e & 3;
                const int eb = eb_[rep], eu = eu_[rep], eex = eex_[rep];
                const float R  = lds_gm[((0 * 2 + ebt) * 64 + eli) * 4 + ei];
                const float Z  = lds_gm[((1 * 2 + ebt) * 64 + eli) * 4 + ei];
                const float iN = lds_gm[((2 * 2 + ebt) * 64 + eli) * 4 + ei];
                const float hN = lds_gm[((3 * 2 + ebt) * 64 + eli) * 4 + ei];
                float hprev;
                if (cell == 0)      hprev = hist[((size_t)tc * BB + eb) * UU + eu];
                else if (cell == 1) hprev = Pf[(size_t)(tc & 3) * BB * UU + (size_t)eb * UU + eu];
                else                hprev = (tc > 0) ? out[((size_t)eb * TT + tc - 1) * UU + eu] : 0.f;
                const float r = 1.f / (1.f + expf(-(R + bR_[rep])));
                const float z = 1.f / (1.f + expf(-(Z + bZ_[rep])));
                const float n2 = tanhf(iN + bNI_[rep] + r * (hN + bNH_[rep]));
                const float val = (1.f - z) * n2 + z * hprev;
                ushort vh, vl; split2(val, vh, vl);
                if (cell == 0) {
                    hist[((size_t)(tc + 1) * BB + eb) * UU + eu] = val;
                    ushort* d = gpack + (size_t)((tc + 1) & 3) * ASLOT;
                    d[eex + 32768] = vh; d[APS + eex + 32768] = vl;
                } else if (cell == 1) {
                    ushort* d = epack + (size_t)(tc & 3) * ASLOT;
                    d[eex] = vh; d[APS + eex] = vl;
                    if (tc + 2 < TT) {
                        Pf[(size_t)((tc + 2) & 3) * BB * UU + (size_t)eb * UU + eu] = val;
                        ushort* d2 = ppack + (size_t)((tc + 2) & 3) * ASLOT;
                        d2[eex + 32768] = vh; d2[APS + eex + 32768] = vl;
                        const float gx = val + inputs[((size_t)eb * TT + tc + 2) * UU + eu];
                        ushort gh, gl; split2(gx, gh, gl);
                        ushort* d3 = gpack + (size_t)((tc + 2) & 3) * ASLOT;
                        d3[eex] = gh; d3[APS + eex] = gl;
                    }
                } else {
                    out[((size_t)eb * TT + tc) * UU + eu] = val;
                    if (tc + 1 < TT) {
                        ushort* d = epack + (size_t)((tc + 1) & 3) * ASLOT;
                        d[eex + 32768] = vh; d[APS + eex + 32768] = vl;
                    }
                }
            }
        }
        // ---- attention chunk (ac, ab): single-pass online softmax ----
        if (t < TT) {
            const int nt2 = t + 1;
            const int cstr = (nt2 + NCHUNK - 1) / NCHUNK;
            const int r0 = ac * cstr;
            const int r1x = r0 + cstr;
            const int r1 = (r1x < nt2) ? r1x : nt2;
            const int n = r1 - r0;
            if (n <= 0) {
                #pragma unroll
                for (int rep = 0; rep < 4; ++rep)
                    attC[((size_t)ac * BB + ab) * UU + tid + rep * 256] = 0.f;
                if (tid == 0) {
                    attML[((size_t)ac * BB + ab) * 2] = -INFINITY;
                    attML[((size_t)ac * BB + ab) * 2 + 1] = 0.f;
                }
            } else {
                const float* qb = qall + ((size_t)t * BB + ab) * UU;
                float4 q0 = *(const float4*)&qb[lane * 4];
                float4 q1 = *(const float4*)&qb[256 + lane * 4];
                float4 q2 = *(const float4*)&qb[512 + lane * 4];
                float4 q3 = *(const float4*)&qb[768 + lane * 4];
                float m_run = -INFINITY, l_run = 0.f;
                float4 c0 = {0,0,0,0}, c1 = {0,0,0,0}, c2 = {0,0,0,0}, c3 = {0,0,0,0};
                for (int tp = r0 + w; tp < r1; tp += 4) {
                    const float* hr = hist + ((size_t)tp * BB + ab) * UU;
                    float4 h0 = *(const float4*)&hr[lane * 4];
                    float4 h1 = *(const float4*)&hr[256 + lane * 4];
                    float4 h2 = *(const float4*)&hr[512 + lane * 4];
                    float4 h3 = *(const float4*)&hr[768 + lane * 4];
                    float s = h0.x*q0.x + h0.y*q0.y + h0.z*q0.z + h0.w*q0.w
                            + h1.x*q1.x + h1.y*q1.y + h1.z*q1.z + h1.w*q1.w
                            + h2.x*q2.x + h2.y*q2.y + h2.z*q2.z + h2.w*q2.w
                            + h3.x*q3.x + h3.y*q3.y + h3.z*q3.z + h3.w*q3.w;
                    #pragma unroll
                    for (int off = 32; off; off >>= 1) s += __shfl_xor(s, off);
                    const float mn = fmaxf(m_run, s);
                    const float sc = expf(m_run - mn);
                    const float e2 = expf(s - mn);
                    c0.x = c0.x*sc + e2*h0.x; c0.y = c0.y*sc + e2*h0.y; c0.z = c0.z*sc + e2*h0.z; c0.w = c0.w*sc + e2*h0.w;
                    c1.x = c1.x*sc + e2*h1.x; c1.y = c1.y*sc + e2*h1.y; c1.z = c1.z*sc + e2*h1.z; c1.w = c1.w*sc + e2*h1.w;
                    c2.x = c2.x*sc + e2*h2.x; c2.y = c2.y*sc + e2*h2.y; c2.z = c2.z*sc + e2*h2.z; c2.w = c2.w*sc + e2*h2.w;
                    c3.x = c3.x*sc + e2*h3.x; c3.y = c3.y*sc + e2*h3.y; c3.z = c3.z*sc + e2*h3.z; c3.w = c3.w*sc + e2*h3.w;
                    l_run = l_run * sc + e2;
                    m_run = mn;
                }
                *(float4*)&lds_scr[w * 1024 + lane * 4] = c0;
                *(float4*)&lds_scr[w * 1024 + 256 + lane * 4] = c1;
                *(float4*)&lds_scr[w * 1024 + 512 + lane * 4] = c2;
                *(float4*)&lds_scr[w * 1024 + 768 + lane * 4] = c3;
                if (lane == 0) { lds_red[w] = m_run; lds_red[4 + w] = l_run; }
                __syncthreads();
                const float M = fmaxf(fmaxf(lds_red[0], lds_red[1]), fmaxf(lds_red[2], lds_red[3]));
                float ww0 = expf(lds_red[0] - M), ww1 = expf(lds_red[1] - M);
                float ww2 = expf(lds_red[2] - M), ww3 = expf(lds_red[3] - M);
                const float L = ww0 * lds_red[4] + ww1 * lds_red[5] + ww2 * lds_red[6] + ww3 * lds_red[7];
                #pragma unroll
                for (int rep = 0; rep < 4; ++rep) {
                    const int e = tid + rep * 256;
                    float s = ww0 * lds_scr[e] + ww1 * lds_scr[1024 + e]
                            + ww2 * lds_scr[2048 + e] + ww3 * lds_scr[3072 + e];
                    attC[((size_t)ac * BB + ab) * UU + e] = s;
                }
                if (tid == 0) {
                    attML[((size_t)ac * BB + ab) * 2] = M;
                    attML[((size_t)ac * BB + ab) * 2 + 1] = L;
                }
            }
            __threadfence();
            if (tid == 0) {
                int old = atomicAdd(cnt + ab, 1);
                lds_flag[0] = ((old % NCHUNK) == (NCHUNK - 1)) ? 1 : 0;
            }
            __syncthreads();
            if (lds_flag[0]) {
                __threadfence();
                float mm[NCHUNK], ll[NCHUNK];
                #pragma unroll
                for (int c = 0; c < NCHUNK; ++c) {
                    mm[c] = attML[((size_t)c * BB + ab) * 2];
                    ll[c] = attML[((size_t)c * BB + ab) * 2 + 1];
                }
                float M2 = mm[0];
                #pragma unroll
                for (int c = 1; c < NCHUNK; ++c) M2 = fmaxf(M2, mm[c]);
                float den = 0.f, wc[NCHUNK];
                #pragma unroll
                for (int c = 0; c < NCHUNK; ++c) { wc[c] = expf(mm[c] - M2); den += wc[c] * ll[c]; }
                const float inv = 1.f / den;
                ushort* d = ppack + (size_t)(t & 3) * ASLOT;
                #pragma unroll
                for (int rep = 0; rep < 4; ++rep) {
                    const int e = tid + rep * 256;
                    float s3 = 0.f;
                    #pragma unroll
                    for (int c = 0; c < NCHUNK; ++c) s3 += wc[c] * attC[((size_t)c * BB + ab) * UU + e];
                    const float xv = s3 * inv + inputs[((size_t)ab * TT + t) * UU + e];
                    ushort vh2, vl2; split2(xv, vh2, vl2);
                    const int ex2 = AEX(e, ab);
                    d[ex2] = vh2; d[APS + ex2] = vl2;
                }
            }
        }
        ++ep;
        grid_barrier(bar, GRIDN * ep);
    }
}

extern "C" void kernel_launch(void* const* d_in, const int* in_sizes, int n_in,
                              void* d_out, int out_size, void* d_ws, size_t ws_size,
                              hipStream_t stream) {
    (void)in_sizes; (void)n_in; (void)out_size; (void)ws_size;
    const float* inputs = (const float*)d_in[0];
    const float* gW   = (const float*)d_in[1];
    const float* gWih = (const float*)d_in[2];
    const float* gWhh = (const float*)d_in[3];
    const float* gbih = (const float*)d_in[4];
    const float* gbhh = (const float*)d_in[5];
    const float* pWih = (const float*)d_in[6];
    const float* pWhh = (const float*)d_in[7];
    const float* pbih = (const float*)d_in[8];
    const float* pbhh = (const float*)d_in[9];
    const float* eWih = (const float*)d_in[10];
    const float* eWhh = (const float*)d_in[11];
    const float* ebih = (const float*)d_in[12];
    const float* ebhh = (const float*)d_in[13];
    float* out = (float*)d_out;

    char* ws = (char*)d_ws;
    size_t off = 0;
    auto alloc = [&](size_t bytes) {
        void* p = ws + off;
        off += (bytes + 255) & ~(size_t)255;
        return p;
    };
    ushort* wpack = (ushort*)alloc((size_t)3 * WCELL * 2);
    ushort* gpack = (ushort*)alloc((size_t)4 * ASLOT * 2);
    ushort* ppack = (ushort*)alloc((size_t)4 * ASLOT * 2);
    ushort* epack = (ushort*)alloc((size_t)4 * ASLOT * 2);
    float* hist  = (float*)alloc((size_t)(TT + 1) * BB * UU * 4);
    float* qall  = (float*)alloc((size_t)TT * BB * UU * 4);
    float* Pf    = (float*)alloc((size_t)4 * BB * UU * 4);
    float* biasp = (float*)alloc((size_t)3 * 4096 * 4);
    float* attC  = (float*)alloc((size_t)NCHUNK * BB * UU * 4);
    float* attML = (float*)alloc((size_t)NCHUNK * BB * 2 * 4);
    int*   cnt   = (int*)alloc(32 * 4);
    int*   bar   = (int*)alloc(4);

    packw_kernel<<<12288, 256, 0, stream>>>(gWih, gWhh, wpack);
    packw_kernel<<<12288, 256, 0, stream>>>(pWih, pWhh, wpack + WCELL);
    packw_kernel<<<12288, 256, 0, stream>>>(eWih, eWhh, wpack + 2 * (size_t)WCELL);
    qall_kernel<<<dim3(256, 32), 256, 0, stream>>>(inputs, gW, qall);
    init_kernel<<<176, 256, 0, stream>>>(inputs, gbih, gbhh, pbih, pbhh, ebih, ebhh,
                                         hist, Pf, gpack, ppack, epack, biasp, cnt, bar);

    hipFuncSetAttribute((const void*)persist_kernel,
                        hipFuncAttributeMaxDynamicSharedMemorySize, LDSB);
    void* args[] = {(void*)&inputs, (void*)&wpack, (void*)&biasp,
                    (void*)&gpack, (void*)&ppack, (void*)&epack,
                    (void*)&hist, (void*)&Pf, (void*)&qall, (void*)&out,
                    (void*)&attC, (void*)&attML, (void*)&cnt, (void*)&bar};
    hipError_t ce = hipLaunchCooperativeKernel((const void*)persist_kernel,
                                               dim3(GRIDN), dim3(256), args,
                                               (unsigned)LDSB, stream);
    if (ce != hipSuccess) {
        (void)hipGetLastError();
        // 192 blocks at 1 block/CU on a 256-CU part are co-resident; the
        // monotone-counter barrier is safe under a plain launch too.
        persist_kernel<<<GRIDN, 256, LDSB, stream>>>(inputs, wpack, biasp,
                                                     gpack, ppack, epack,
                                                     hist, Pf, qall, out,
                                                     attC, attML, cnt, bar);
    }
}

// Round 7
// 9726.482 us; speedup vs baseline: 2.0885x; 2.0316x over previous
//
#include <hip/hip_runtime.h>
#include <math.h>

// Problem constants: U=H=1024, B=32, T=256.
#define UU 1024
#define BB 32
#define TT 256
#define NCHUNK 6
#define GRIDN 192

// Weight pack geometry (ushort elems). Per cell: [2 planes][sections r,z,nx,nh]
#define WPS   6291456u
#define WCELL (2u * WPS)
#define SR  0u
#define SZ  2097152u
#define SNX 4194304u
#define SNH 5242880u
// Act pack: per slot [2 planes][64 ks][4 hi][32 b][8 e]; x-half [0,32768), h-half +32768
#define APS   65536u
#define ASLOT (2u * APS)
#define AEX(u, b) ((((((u) >> 5) * 4 + (((u) >> 3) & 3)) * 32 + (b)) * 8) + ((u) & 7))

// Dynamic LDS layout (bytes): [0,128K) r/z lo-plane weights; then scratch.
#define SCR_OFF  131072   // 16 KB scratch (combine dumps / att ctx reduce)
#define GM_OFF   147456   // 8 KB gate matrix [4 gates][2 bt][64 lane][4]
#define RED_OFF  155648   // 16 f32
#define FLAG_OFF 155712
#define LDSB     155776

typedef __attribute__((ext_vector_type(8))) short bf16x8;
typedef __attribute__((ext_vector_type(4))) float f32x4;
#define MF(a, b, c) __builtin_amdgcn_mfma_f32_16x16x32_bf16((a), (b), (c), 0, 0, 0)

__device__ __forceinline__ ushort bf16rne(float v) {
    uint x = __float_as_uint(v);
    uint r = (x + 0x7fffu + ((x >> 16) & 1u)) >> 16;
    return (ushort)r;
}
__device__ __forceinline__ float ubf2f(ushort u) {
    return __uint_as_float(((uint)u) << 16);
}
__device__ __forceinline__ void split2(float v, ushort& h, ushort& l) {
    h = bf16rne(v);
    l = bf16rne(v - ubf2f(h));
}

// ---------------------------------------------------------------------------
// Weight pack (unchanged, proven).
// ---------------------------------------------------------------------------
__global__ void packw_kernel(const float* __restrict__ Wih,
                             const float* __restrict__ Whh,
                             ushort* __restrict__ wp) {
    int tile = blockIdx.x;
    int sec, jt, ks, nks;
    size_t soff;
    if (tile < 8192) {
        sec = tile >> 12; int l = tile & 4095; jt = l >> 6; ks = l & 63; nks = 64;
        soff = sec ? SZ : SR;
    } else {
        int l2 = tile - 8192; sec = 2 + (l2 >> 11); int l = l2 & 2047; jt = l >> 5; ks = l & 31; nks = 32;
        soff = (sec == 2) ? SNX : SNH;
    }
    int p = threadIdx.x;
    int e0 = (p & 3) * 2, ul = (p >> 2) & 15, hi = p >> 6;
    int u = jt * 16 + ul;
    int kk = ks * 32 + hi * 8 + e0;
    float2 w;
    if (sec < 2) {
        int row = (sec ? 1024 : 0) + u;
        if (kk < 1024) w = *(const float2*)&Wih[(size_t)row * UU + kk];
        else           w = *(const float2*)&Whh[(size_t)row * UU + kk - 1024];
    } else if (sec == 2) {
        w = *(const float2*)&Wih[(size_t)(2048 + u) * UU + kk];
    } else {
        w = *(const float2*)&Whh[(size_t)(2048 + u) * UU + kk];
    }
    ushort h0, l0, h1, l1;
    split2(w.x, h0, l0); split2(w.y, h1, l1);
    size_t ob = soff + ((((size_t)jt * nks + ks) * 4 + hi) * 16 + ul) * 8 + e0;
    *(uint*)(wp + ob)       = (uint)h0 | ((uint)h1 << 16);
    *(uint*)(wp + WPS + ob) = (uint)l0 | ((uint)l1 << 16);
}

// ---------------------------------------------------------------------------
// q_all[t][b][u] = sum_k inputs[b][t][k] * global_W[k][u]  (fp32)
// ---------------------------------------------------------------------------
__global__ void qall_kernel(const float* __restrict__ x,
                            const float* __restrict__ gW,
                            float* __restrict__ q) {
    __shared__ float xs[32][65];
    int r0 = blockIdx.x * 32, u0 = blockIdx.y * 32;
    int tid = threadIdx.x;
    int rr = tid >> 3, ju = tid & 7;
    float4 acc = {0.f, 0.f, 0.f, 0.f};
    for (int k0 = 0; k0 < UU; k0 += 64) {
        for (int e = tid; e < 32 * 64; e += 256) {
            int lr = e >> 6, lk = e & 63;
            int r = r0 + lr;
            int tt = r >> 5, bb = r & 31;
            xs[lr][lk] = x[((size_t)bb * TT + tt) * UU + k0 + lk];
        }
        __syncthreads();
        #pragma unroll 4
        for (int kk = 0; kk < 64; ++kk) {
            float4 gv = *(const float4*)&gW[(size_t)(k0 + kk) * UU + u0 + ju * 4];
            float xv = xs[rr][kk];
            acc.x += xv * gv.x; acc.y += xv * gv.y;
            acc.z += xv * gv.z; acc.w += xv * gv.w;
        }
        __syncthreads();
    }
    *(float4*)&q[(size_t)(r0 + rr) * UU + u0 + ju * 4] = acc;
}

// ---------------------------------------------------------------------------
// Init (unchanged, proven).
// ---------------------------------------------------------------------------
__global__ void init_kernel(const float* __restrict__ inputs,
                            const float* __restrict__ gbih, const float* __restrict__ gbhh,
                            const float* __restrict__ pbih, const float* __restrict__ pbhh,
                            const float* __restrict__ ebih, const float* __restrict__ ebhh,
                            float* __restrict__ hist, float* __restrict__ Pf,
                            ushort* __restrict__ gpack, ushort* __restrict__ ppack,
                            ushort* __restrict__ epack, float* __restrict__ biasp,
                            int* __restrict__ cnt, int* __restrict__ bar) {
    if (blockIdx.x == 0 && threadIdx.x < 33) {
        if (threadIdx.x < 32) cnt[threadIdx.x] = 0;
        else bar[0] = 0;
    }
    if (blockIdx.x < 128) {
        int i = blockIdx.x * 256 + threadIdx.x;
        int b = i >> 10, u = i & 1023;
        hist[i] = 0.f;
        Pf[i] = 0.f; Pf[32768 + i] = 0.f;
        int ex = AEX(u, b);
        int eh = ex + 32768;
        gpack[eh] = 0; gpack[APS + eh] = 0;
        ppack[eh] = 0; ppack[APS + eh] = 0;
        ppack[ASLOT + eh] = 0; ppack[ASLOT + APS + eh] = 0;
        epack[eh] = 0; epack[APS + eh] = 0;
        float x0 = inputs[((size_t)b * TT + 0) * UU + u];
        float x1 = inputs[((size_t)b * TT + 1) * UU + u];
        ushort h, l;
        split2(x0, h, l); gpack[ex] = h; gpack[APS + ex] = l;
        split2(x1, h, l); gpack[ASLOT + ex] = h; gpack[ASLOT + APS + ex] = l;
    } else {
        int idx = (blockIdx.x - 128) * 256 + threadIdx.x;
        int cell = idx >> 12, g4 = (idx >> 10) & 3, u = idx & 1023;
        const float* bih = (cell == 0) ? gbih : (cell == 1) ? pbih : ebih;
        const float* bhh = (cell == 0) ? gbhh : (cell == 1) ? pbhh : ebhh;
        float v;
        if (g4 == 0) v = bih[u] + bhh[u];
        else if (g4 == 1) v = bih[1024 + u] + bhh[1024 + u];
        else if (g4 == 2) v = bih[2048 + u];
        else v = bhh[2048 + u];
        biasp[idx] = v;
    }
}

// ---------------------------------------------------------------------------
// Grid barrier, fence-correct version:
//  - arrive: one wbl2 (via tid0 __threadfence after __syncthreads) + RELAXED add
//  - wait:   RELAXED polls (sc1 bypass load, NO per-poll L2 invalidate)
//  - exit:   ONE acquire load (single buffer_inv) -> fresh L2 for this stage
// ---------------------------------------------------------------------------
__device__ __forceinline__ void grid_barrier(int* bar, int target) {
    __syncthreads();   // drains vmcnt: all block stores are at least in L2
    if (threadIdx.x == 0) {
        __threadfence();   // wbl2: flush this XCD's dirty lines to L3
        __hip_atomic_fetch_add(bar, 1, __ATOMIC_RELAXED, __HIP_MEMORY_SCOPE_AGENT);
        while (__hip_atomic_load(bar, __ATOMIC_RELAXED, __HIP_MEMORY_SCOPE_AGENT) < target) {
            __builtin_amdgcn_s_sleep(8);
        }
        (void)__hip_atomic_load(bar, __ATOMIC_ACQUIRE, __HIP_MEMORY_SCOPE_AGENT);  // one inv
    }
    __syncthreads();
}

// ---------------------------------------------------------------------------
// Persistent kernel: 192 blocks x 256 threads, 1 block/CU.
// Weights resident: hi R/Z/N + lo N in regs (64 bf16x8), lo R/Z in LDS.
// ---------------------------------------------------------------------------
__global__ __launch_bounds__(256, 1)
void persist_kernel(const float* __restrict__ inputs,
                    const ushort* __restrict__ wpack,
                    const float* __restrict__ biasp,
                    ushort* __restrict__ gpack, ushort* __restrict__ ppack,
                    ushort* __restrict__ epack,
                    float* __restrict__ hist, float* __restrict__ Pf,
                    const float* __restrict__ qall,
                    float* __restrict__ out,
                    float* __restrict__ attC, float* __restrict__ attML,
                    int* __restrict__ cnt, int* __restrict__ bar) {
    extern __shared__ char smraw[];
    float* lds_scr  = (float*)(smraw + SCR_OFF);
    float* lds_gm   = (float*)(smraw + GM_OFF);
    float* lds_red  = (float*)(smraw + RED_OFF);
    int*   lds_flag = (int*)(smraw + FLAG_OFF);

    const int blk = blockIdx.x, tid = threadIdx.x;
    const int cell = blk >> 6, jt = blk & 63;
    const int w = tid >> 6, lane = tid & 63;
    const int l15 = lane & 15, hi4 = lane >> 4;
    const int ab = blk & 31, ac = blk >> 5;
    const ushort* wp = wpack + (size_t)cell * WCELL;

    // ---- persistent weights ----
    bf16x8 whiR[16], whiZ[16], whiN[16], wloN[16];
    #pragma unroll
    for (int i = 0; i < 16; ++i) {
        const int ks = w * 16 + i;
        const size_t aoff = ((size_t)(jt * 256 + ks * 4 + hi4)) * 128 + (size_t)l15 * 8;
        whiR[i] = *(const bf16x8*)(wp + SR + aoff);
        whiZ[i] = *(const bf16x8*)(wp + SZ + aoff);
        bf16x8 rlo = *(const bf16x8*)(wp + SR + WPS + aoff);
        bf16x8 zlo = *(const bf16x8*)(wp + SZ + WPS + aoff);
        *(bf16x8*)(smraw + (((w * 32 + i) * 64 + lane) << 4)) = rlo;
        *(bf16x8*)(smraw + (((w * 32 + 16 + i) * 64 + lane) << 4)) = zlo;
        const int ksn = (w & 1) * 16 + i;
        const size_t noff = ((size_t)(jt * 128 + ksn * 4 + hi4)) * 128 + (size_t)l15 * 8;
        const size_t sN = (w < 2) ? SNX : SNH;
        whiN[i] = *(const bf16x8*)(wp + sN + noff);
        wloN[i] = *(const bf16x8*)(wp + sN + WPS + noff);
    }
    // ---- epilogue constants (2 outputs/thread) ----
    int eb_[2], eu_[2], eex_[2];
    float bR_[2], bZ_[2], bNI_[2], bNH_[2];
    {
        const float* bc = biasp + cell * 4096;
        #pragma unroll
        for (int rep = 0; rep < 2; ++rep) {
            const int e = tid + rep * 256;
            const int ebt = e >> 8, eli = (e >> 2) & 63, ei = e & 3;
            eb_[rep] = ebt * 16 + (eli & 15);
            eu_[rep] = jt * 16 + (eli >> 4) * 4 + ei;
            eex_[rep] = AEX(eu_[rep], eb_[rep]);
            bR_[rep]  = bc[eu_[rep]];
            bZ_[rep]  = bc[1024 + eu_[rep]];
            bNI_[rep] = bc[2048 + eu_[rep]];
            bNH_[rep] = bc[3072 + eu_[rep]];
        }
    }
    __syncthreads();

    int ep = 0;
    for (int t = 0; t <= TT + 1; ++t) {
        const int tc = t - cell;
        const bool gemmWork = (tc >= 0 && tc < TT);
        if (gemmWork) {
            f32x4 aR0 = {0,0,0,0}, aR1 = {0,0,0,0};
            f32x4 aZ0 = {0,0,0,0}, aZ1 = {0,0,0,0};
            f32x4 aN0 = {0,0,0,0}, aN1 = {0,0,0,0};
            ushort* apk = (cell == 0) ? gpack : (cell == 1) ? ppack : epack;
            const ushort* ap = apk + (size_t)(tc & 3) * ASLOT;
            const ushort* bbp = ap + ((size_t)hi4 * 32 + l15) * 8;
            #pragma unroll
            for (int i = 0; i < 16; ++i) {
                const int ks = w * 16 + i;
                const ushort* bp = bbp + (size_t)ks * 1024;
                bf16x8 bh0 = *(const bf16x8*)(bp);
                bf16x8 bh1 = *(const bf16x8*)(bp + 128);
                bf16x8 bl0 = *(const bf16x8*)(bp + APS);
                bf16x8 bl1 = *(const bf16x8*)(bp + APS + 128);
                bf16x8 rlo = *(const bf16x8*)(smraw + (((w * 32 + i) * 64 + lane) << 4));
                bf16x8 zlo = *(const bf16x8*)(smraw + (((w * 32 + 16 + i) * 64 + lane) << 4));
                aR0 = MF(whiR[i], bh0, aR0); aR0 = MF(whiR[i], bl0, aR0); aR0 = MF(rlo, bh0, aR0);
                aR1 = MF(whiR[i], bh1, aR1); aR1 = MF(whiR[i], bl1, aR1); aR1 = MF(rlo, bh1, aR1);
                aZ0 = MF(whiZ[i], bh0, aZ0); aZ0 = MF(whiZ[i], bl0, aZ0); aZ0 = MF(zlo, bh0, aZ0);
                aZ1 = MF(whiZ[i], bh1, aZ1); aZ1 = MF(whiZ[i], bl1, aZ1); aZ1 = MF(zlo, bh1, aZ1);
                aN0 = MF(whiN[i], bh0, aN0); aN0 = MF(whiN[i], bl0, aN0); aN0 = MF(wloN[i], bh0, aN0);
                aN1 = MF(whiN[i], bh1, aN1); aN1 = MF(whiN[i], bl1, aN1); aN1 = MF(wloN[i], bh1, aN1);
            }
            // ---- combine rounds: R -> gm0, Z -> gm1, N -> gm2 (iN), gm3 (hN) ----
            __syncthreads();
            *(f32x4*)&lds_scr[((0 * 4 + w) * 64 + lane) * 4] = aR0;
            *(f32x4*)&lds_scr[((1 * 4 + w) * 64 + lane) * 4] = aR1;
            __syncthreads();
            #pragma unroll
            for (int rep = 0; rep < 2; ++rep) {
                const int e = tid + rep * 256;
                const int bt = e >> 8, ln = (e >> 2) & 63, c = e & 3;
                float s = lds_scr[((bt * 4 + 0) * 64 + ln) * 4 + c] + lds_scr[((bt * 4 + 1) * 64 + ln) * 4 + c]
                        + lds_scr[((bt * 4 + 2) * 64 + ln) * 4 + c] + lds_scr[((bt * 4 + 3) * 64 + ln) * 4 + c];
                lds_gm[((0 * 2 + bt) * 64 + ln) * 4 + c] = s;
            }
            __syncthreads();
            *(f32x4*)&lds_scr[((0 * 4 + w) * 64 + lane) * 4] = aZ0;
            *(f32x4*)&lds_scr[((1 * 4 + w) * 64 + lane) * 4] = aZ1;
            __syncthreads();
            #pragma unroll
            for (int rep = 0; rep < 2; ++rep) {
                const int e = tid + rep * 256;
                const int bt = e >> 8, ln = (e >> 2) & 63, c = e & 3;
                float s = lds_scr[((bt * 4 + 0) * 64 + ln) * 4 + c] + lds_scr[((bt * 4 + 1) * 64 + ln) * 4 + c]
                        + lds_scr[((bt * 4 + 2) * 64 + ln) * 4 + c] + lds_scr[((bt * 4 + 3) * 64 + ln) * 4 + c];
                lds_gm[((1 * 2 + bt) * 64 + ln) * 4 + c] = s;
            }
            __syncthreads();
            *(f32x4*)&lds_scr[((0 * 4 + w) * 64 + lane) * 4] = aN0;
            *(f32x4*)&lds_scr[((1 * 4 + w) * 64 + lane) * 4] = aN1;
            __syncthreads();
            #pragma unroll
            for (int rep = 0; rep < 2; ++rep) {
                const int e = tid + rep * 256;
                const int bt = e >> 8, ln = (e >> 2) & 63, c = e & 3;
                float iN = lds_scr[((bt * 4 + 0) * 64 + ln) * 4 + c] + lds_scr[((bt * 4 + 1) * 64 + ln) * 4 + c];
                float hN = lds_scr[((bt * 4 + 2) * 64 + ln) * 4 + c] + lds_scr[((bt * 4 + 3) * 64 + ln) * 4 + c];
                lds_gm[((2 * 2 + bt) * 64 + ln) * 4 + c] = iN;
                lds_gm[((3 * 2 + bt) * 64 + ln) * 4 + c] = hN;
            }
            __syncthreads();
            // ---- epilogue (2 outputs/thread) ----
            #pragma unroll
            for (int rep = 0; rep < 2; ++rep) {
                const int e = tid + rep * 256;
                const int ebt = e >> 8, eli = (e >> 2) & 63, ei = e & 3;
                const int eb = eb_[rep], eu = eu_[rep], eex = eex_[rep];
                const float R  = lds_gm[((0 * 2 + ebt) * 64 + eli) * 4 + ei];
                const float Z  = lds_gm[((1 * 2 + ebt) * 64 + eli) * 4 + ei];
                const float iN = lds_gm[((2 * 2 + ebt) * 64 + eli) * 4 + ei];
                const float hN = lds_gm[((3 * 2 + ebt) * 64 + eli) * 4 + ei];
                float hprev;
                if (cell == 0)      hprev = hist[((size_t)tc * BB + eb) * UU + eu];
                else if (cell == 1) hprev = Pf[(size_t)(tc & 3) * BB * UU + (size_t)eb * UU + eu];
                else                hprev = (tc > 0) ? out[((size_t)eb * TT + tc - 1) * UU + eu] : 0.f;
                const float r = 1.f / (1.f + expf(-(R + bR_[rep])));
                const float z = 1.f / (1.f + expf(-(Z + bZ_[rep])));
                const float n2 = tanhf(iN + bNI_[rep] + r * (hN + bNH_[rep]));
                const float val = (1.f - z) * n2 + z * hprev;
                ushort vh, vl; split2(val, vh, vl);
                if (cell == 0) {
                    hist[((size_t)(tc + 1) * BB + eb) * UU + eu] = val;
                    ushort* d = gpack + (size_t)((tc + 1) & 3) * ASLOT;
                    d[eex + 32768] = vh; d[APS + eex + 32768] = vl;
                } else if (cell == 1) {
                    ushort* d = epack + (size_t)(tc & 3) * ASLOT;
                    d[eex] = vh; d[APS + eex] = vl;
                    if (tc + 2 < TT) {
                        Pf[(size_t)((tc + 2) & 3) * BB * UU + (size_t)eb * UU + eu] = val;
                        ushort* d2 = ppack + (size_t)((tc + 2) & 3) * ASLOT;
                        d2[eex + 32768] = vh; d2[APS + eex + 32768] = vl;
                        const float gx = val + inputs[((size_t)eb * TT + tc + 2) * UU + eu];
                        ushort gh, gl; split2(gx, gh, gl);
                        ushort* d3 = gpack + (size_t)((tc + 2) & 3) * ASLOT;
                        d3[eex] = gh; d3[APS + eex] = gl;
                    }
                } else {
                    out[((size_t)eb * TT + tc) * UU + eu] = val;
                    if (tc + 1 < TT) {
                        ushort* d = epack + (size_t)((tc + 1) & 3) * ASLOT;
                        d[eex + 32768] = vh; d[APS + eex + 32768] = vl;
                    }
                }
            }
        }
        // ---- attention chunk (ac, ab): single-pass online softmax ----
        if (t < TT) {
            const int nt2 = t + 1;
            const int cstr = (nt2 + NCHUNK - 1) / NCHUNK;
            const int r0 = ac * cstr;
            const int r1x = r0 + cstr;
            const int r1 = (r1x < nt2) ? r1x : nt2;
            const int n = r1 - r0;
            if (n <= 0) {
                #pragma unroll
                for (int rep = 0; rep < 4; ++rep)
                    attC[((size_t)ac * BB + ab) * UU + tid + rep * 256] = 0.f;
                if (tid == 0) {
                    attML[((size_t)ac * BB + ab) * 2] = -INFINITY;
                    attML[((size_t)ac * BB + ab) * 2 + 1] = 0.f;
                }
            } else {
                const float* qb = qall + ((size_t)t * BB + ab) * UU;
                float4 q0 = *(const float4*)&qb[lane * 4];
                float4 q1 = *(const float4*)&qb[256 + lane * 4];
                float4 q2 = *(const float4*)&qb[512 + lane * 4];
                float4 q3 = *(const float4*)&qb[768 + lane * 4];
                float m_run = -INFINITY, l_run = 0.f;
                float4 c0 = {0,0,0,0}, c1 = {0,0,0,0}, c2 = {0,0,0,0}, c3 = {0,0,0,0};
                for (int tp = r0 + w; tp < r1; tp += 4) {
                    const float* hr = hist + ((size_t)tp * BB + ab) * UU;
                    float4 h0 = *(const float4*)&hr[lane * 4];
                    float4 h1 = *(const float4*)&hr[256 + lane * 4];
                    float4 h2 = *(const float4*)&hr[512 + lane * 4];
                    float4 h3 = *(const float4*)&hr[768 + lane * 4];
                    float s = h0.x*q0.x + h0.y*q0.y + h0.z*q0.z + h0.w*q0.w
                            + h1.x*q1.x + h1.y*q1.y + h1.z*q1.z + h1.w*q1.w
                            + h2.x*q2.x + h2.y*q2.y + h2.z*q2.z + h2.w*q2.w
                            + h3.x*q3.x + h3.y*q3.y + h3.z*q3.z + h3.w*q3.w;
                    #pragma unroll
                    for (int off = 32; off; off >>= 1) s += __shfl_xor(s, off);
                    const float mn = fmaxf(m_run, s);
                    const float sc = expf(m_run - mn);
                    const float e2 = expf(s - mn);
                    c0.x = c0.x*sc + e2*h0.x; c0.y = c0.y*sc + e2*h0.y; c0.z = c0.z*sc + e2*h0.z; c0.w = c0.w*sc + e2*h0.w;
                    c1.x = c1.x*sc + e2*h1.x; c1.y = c1.y*sc + e2*h1.y; c1.z = c1.z*sc + e2*h1.z; c1.w = c1.w*sc + e2*h1.w;
                    c2.x = c2.x*sc + e2*h2.x; c2.y = c2.y*sc + e2*h2.y; c2.z = c2.z*sc + e2*h2.z; c2.w = c2.w*sc + e2*h2.w;
                    c3.x = c3.x*sc + e2*h3.x; c3.y = c3.y*sc + e2*h3.y; c3.z = c3.z*sc + e2*h3.z; c3.w = c3.w*sc + e2*h3.w;
                    l_run = l_run * sc + e2;
                    m_run = mn;
                }
                *(float4*)&lds_scr[w * 1024 + lane * 4] = c0;
                *(float4*)&lds_scr[w * 1024 + 256 + lane * 4] = c1;
                *(float4*)&lds_scr[w * 1024 + 512 + lane * 4] = c2;
                *(float4*)&lds_scr[w * 1024 + 768 + lane * 4] = c3;
                if (lane == 0) { lds_red[w] = m_run; lds_red[4 + w] = l_run; }
                __syncthreads();
                const float M = fmaxf(fmaxf(lds_red[0], lds_red[1]), fmaxf(lds_red[2], lds_red[3]));
                float ww0 = expf(lds_red[0] - M), ww1 = expf(lds_red[1] - M);
                float ww2 = expf(lds_red[2] - M), ww3 = expf(lds_red[3] - M);
                const float L = ww0 * lds_red[4] + ww1 * lds_red[5] + ww2 * lds_red[6] + ww3 * lds_red[7];
                #pragma unroll
                for (int rep = 0; rep < 4; ++rep) {
                    const int e = tid + rep * 256;
                    float s = ww0 * lds_scr[e] + ww1 * lds_scr[1024 + e]
                            + ww2 * lds_scr[2048 + e] + ww3 * lds_scr[3072 + e];
                    attC[((size_t)ac * BB + ab) * UU + e] = s;
                }
                if (tid == 0) {
                    attML[((size_t)ac * BB + ab) * 2] = M;
                    attML[((size_t)ac * BB + ab) * 2 + 1] = L;
                }
            }
            // publish chunk results, then count arrivals (fence by tid0 only)
            __syncthreads();   // drains vmcnt: chunk stores are in L2
            if (tid == 0) {
                __threadfence();   // wbl2: chunk results -> L3
                int old = __hip_atomic_fetch_add(cnt + ab, 1, __ATOMIC_RELAXED,
                                                 __HIP_MEMORY_SCOPE_AGENT);
                lds_flag[0] = ((old % NCHUNK) == (NCHUNK - 1)) ? 1 : 0;
            }
            __syncthreads();
            if (lds_flag[0]) {
                // Finisher: all 6 same-ab chunk blocks share this XCD's L2
                // (blk%8 == ab%8), and this block's L2 was invalidated at stage
                // start and hasn't read attC since -> normal loads are fresh.
                float mm[NCHUNK], ll[NCHUNK];
                #pragma unroll
                for (int c = 0; c < NCHUNK; ++c) {
                    mm[c] = attML[((size_t)c * BB + ab) * 2];
                    ll[c] = attML[((size_t)c * BB + ab) * 2 + 1];
                }
                float M2 = mm[0];
                #pragma unroll
                for (int c = 1; c < NCHUNK; ++c) M2 = fmaxf(M2, mm[c]);
                float den = 0.f, wc[NCHUNK];
                #pragma unroll
                for (int c = 0; c < NCHUNK; ++c) { wc[c] = expf(mm[c] - M2); den += wc[c] * ll[c]; }
                const float inv = 1.f / den;
                ushort* d = ppack + (size_t)(t & 3) * ASLOT;
                #pragma unroll
                for (int rep = 0; rep < 4; ++rep) {
                    const int e = tid + rep * 256;
                    float s3 = 0.f;
                    #pragma unroll
                    for (int c = 0; c < NCHUNK; ++c) s3 += wc[c] * attC[((size_t)c * BB + ab) * UU + e];
                    const float xv = s3 * inv + inputs[((size_t)ab * TT + t) * UU + e];
                    ushort vh2, vl2; split2(xv, vh2, vl2);
                    const int ex2 = AEX(e, ab);
                    d[ex2] = vh2; d[APS + ex2] = vl2;
                }
            }
        }
        ++ep;
        grid_barrier(bar, GRIDN * ep);
    }
}

extern "C" void kernel_launch(void* const* d_in, const int* in_sizes, int n_in,
                              void* d_out, int out_size, void* d_ws, size_t ws_size,
                              hipStream_t stream) {
    (void)in_sizes; (void)n_in; (void)out_size; (void)ws_size;
    const float* inputs = (const float*)d_in[0];
    const float* gW   = (const float*)d_in[1];
    const float* gWih = (const float*)d_in[2];
    const float* gWhh = (const float*)d_in[3];
    const float* gbih = (const float*)d_in[4];
    const float* gbhh = (const float*)d_in[5];
    const float* pWih = (const float*)d_in[6];
    const float* pWhh = (const float*)d_in[7];
    const float* pbih = (const float*)d_in[8];
    const float* pbhh = (const float*)d_in[9];
    const float* eWih = (const float*)d_in[10];
    const float* eWhh = (const float*)d_in[11];
    const float* ebih = (const float*)d_in[12];
    const float* ebhh = (const float*)d_in[13];
    float* out = (float*)d_out;

    char* ws = (char*)d_ws;
    size_t off = 0;
    auto alloc = [&](size_t bytes) {
        void* p = ws + off;
        off += (bytes + 255) & ~(size_t)255;
        return p;
    };
    ushort* wpack = (ushort*)alloc((size_t)3 * WCELL * 2);
    ushort* gpack = (ushort*)alloc((size_t)4 * ASLOT * 2);
    ushort* ppack = (ushort*)alloc((size_t)4 * ASLOT * 2);
    ushort* epack = (ushort*)alloc((size_t)4 * ASLOT * 2);
    float* hist  = (float*)alloc((size_t)(TT + 1) * BB * UU * 4);
    float* qall  = (float*)alloc((size_t)TT * BB * UU * 4);
    float* Pf    = (float*)alloc((size_t)4 * BB * UU * 4);
    float* biasp = (float*)alloc((size_t)3 * 4096 * 4);
    float* attC  = (float*)alloc((size_t)NCHUNK * BB * UU * 4);
    float* attML = (float*)alloc((size_t)NCHUNK * BB * 2 * 4);
    int*   cnt   = (int*)alloc(32 * 4);
    int*   bar   = (int*)alloc(4);

    packw_kernel<<<12288, 256, 0, stream>>>(gWih, gWhh, wpack);
    packw_kernel<<<12288, 256, 0, stream>>>(pWih, pWhh, wpack + WCELL);
    packw_kernel<<<12288, 256, 0, stream>>>(eWih, eWhh, wpack + 2 * (size_t)WCELL);
    qall_kernel<<<dim3(256, 32), 256, 0, stream>>>(inputs, gW, qall);
    init_kernel<<<176, 256, 0, stream>>>(inputs, gbih, gbhh, pbih, pbhh, ebih, ebhh,
                                         hist, Pf, gpack, ppack, epack, biasp, cnt, bar);

    hipFuncSetAttribute((const void*)persist_kernel,
                        hipFuncAttributeMaxDynamicSharedMemorySize, LDSB);
    void* args[] = {(void*)&inputs, (void*)&wpack, (void*)&biasp,
                    (void*)&gpack, (void*)&ppack, (void*)&epack,
                    (void*)&hist, (void*)&Pf, (void*)&qall, (void*)&out,
                    (void*)&attC, (void*)&attML, (void*)&cnt, (void*)&bar};
    hipError_t ce = hipLaunchCooperativeKernel((const void*)persist_kernel,
                                               dim3(GRIDN), dim3(256), args,
                                               (unsigned)LDSB, stream);
    if (ce != hipSuccess) {
        (void)hipGetLastError();
        // 192 blocks at 1 block/CU on a 256-CU part are co-resident; the
        // monotone-counter barrier is safe under a plain launch too.
        persist_kernel<<<GRIDN, 256, LDSB, stream>>>(inputs, wpack, biasp,
                                                     gpack, ppack, epack,
                                                     hist, Pf, qall, out,
                                                     attC, attML, cnt, bar);
    }
}

// Round 8
// 6234.003 us; speedup vs baseline: 3.2586x; 1.5602x over previous
//
#include <hip/hip_runtime.h>
#include <math.h>

// Problem constants: U=H=1024, B=32, T=256.
#define UU 1024
#define BB 32
#define TT 256
#define NCHUNK 6
#define GRIDN 192

// Weight pack geometry (ushort elems). Per cell: [2 planes][sections r,z,nx,nh]
#define WPS   6291456u
#define WCELL (2u * WPS)
#define SR  0u
#define SZ  2097152u
#define SNX 4194304u
#define SNH 5242880u
// Act pack: per slot [2 planes][64 ks][4 hi][32 b][8 e]; x-half [0,32768), h-half +32768
#define APS   65536u
#define ASLOT (2u * APS)
#define AEX(u, b) ((((((u) >> 5) * 4 + (((u) >> 3) & 3)) * 32 + (b)) * 8) + ((u) & 7))

// Dynamic LDS layout (bytes): [0,128K) r/z lo-plane weights; then scratch.
#define SCR_OFF  131072   // 16 KB scratch (combine dumps / att ctx reduce)
#define GM_OFF   147456   // 8 KB gate matrix [4 gates][2 bt][64 lane][4]
#define RED_OFF  155648   // 16 f32
#define FLAG_OFF 155712
#define LDSB     155776

typedef __attribute__((ext_vector_type(8))) short bf16x8;
typedef __attribute__((ext_vector_type(4))) float f32x4;
#define MF(a, b, c) __builtin_amdgcn_mfma_f32_16x16x32_bf16((a), (b), (c), 0, 0, 0)

__device__ __forceinline__ ushort bf16rne(float v) {
    uint x = __float_as_uint(v);
    uint r = (x + 0x7fffu + ((x >> 16) & 1u)) >> 16;
    return (ushort)r;
}
__device__ __forceinline__ float ubf2f(ushort u) {
    return __uint_as_float(((uint)u) << 16);
}
__device__ __forceinline__ void split2(float v, ushort& h, ushort& l) {
    h = bf16rne(v);
    l = bf16rne(v - ubf2f(h));
}
// Agent-scope write-through stores (reach L3 directly; no wbl2 needed).
__device__ __forceinline__ void store_f32_sc(float* p, float v) {
    asm volatile("global_store_dword %0, %1, off sc1" :: "v"(p), "v"(v) : "memory");
}
__device__ __forceinline__ void store_u16_sc(ushort* p, ushort v) {
    uint vv = v;
    asm volatile("global_store_short %0, %1, off sc1" :: "v"(p), "v"(vv) : "memory");
}
__device__ __forceinline__ void vm_drain() {
    asm volatile("s_waitcnt vmcnt(0)" ::: "memory");
}

// ---------------------------------------------------------------------------
// Weight pack (unchanged, proven).
// ---------------------------------------------------------------------------
__global__ void packw_kernel(const float* __restrict__ Wih,
                             const float* __restrict__ Whh,
                             ushort* __restrict__ wp) {
    int tile = blockIdx.x;
    int sec, jt, ks, nks;
    size_t soff;
    if (tile < 8192) {
        sec = tile >> 12; int l = tile & 4095; jt = l >> 6; ks = l & 63; nks = 64;
        soff = sec ? SZ : SR;
    } else {
        int l2 = tile - 8192; sec = 2 + (l2 >> 11); int l = l2 & 2047; jt = l >> 5; ks = l & 31; nks = 32;
        soff = (sec == 2) ? SNX : SNH;
    }
    int p = threadIdx.x;
    int e0 = (p & 3) * 2, ul = (p >> 2) & 15, hi = p >> 6;
    int u = jt * 16 + ul;
    int kk = ks * 32 + hi * 8 + e0;
    float2 w;
    if (sec < 2) {
        int row = (sec ? 1024 : 0) + u;
        if (kk < 1024) w = *(const float2*)&Wih[(size_t)row * UU + kk];
        else           w = *(const float2*)&Whh[(size_t)row * UU + kk - 1024];
    } else if (sec == 2) {
        w = *(const float2*)&Wih[(size_t)(2048 + u) * UU + kk];
    } else {
        w = *(const float2*)&Whh[(size_t)(2048 + u) * UU + kk];
    }
    ushort h0, l0, h1, l1;
    split2(w.x, h0, l0); split2(w.y, h1, l1);
    size_t ob = soff + ((((size_t)jt * nks + ks) * 4 + hi) * 16 + ul) * 8 + e0;
    *(uint*)(wp + ob)       = (uint)h0 | ((uint)h1 << 16);
    *(uint*)(wp + WPS + ob) = (uint)l0 | ((uint)l1 << 16);
}

// ---------------------------------------------------------------------------
// q_all[t][b][u] = sum_k inputs[b][t][k] * global_W[k][u]  (fp32)
// ---------------------------------------------------------------------------
__global__ void qall_kernel(const float* __restrict__ x,
                            const float* __restrict__ gW,
                            float* __restrict__ q) {
    __shared__ float xs[32][65];
    int r0 = blockIdx.x * 32, u0 = blockIdx.y * 32;
    int tid = threadIdx.x;
    int rr = tid >> 3, ju = tid & 7;
    float4 acc = {0.f, 0.f, 0.f, 0.f};
    for (int k0 = 0; k0 < UU; k0 += 64) {
        for (int e = tid; e < 32 * 64; e += 256) {
            int lr = e >> 6, lk = e & 63;
            int r = r0 + lr;
            int tt = r >> 5, bb = r & 31;
            xs[lr][lk] = x[((size_t)bb * TT + tt) * UU + k0 + lk];
        }
        __syncthreads();
        #pragma unroll 4
        for (int kk = 0; kk < 64; ++kk) {
            float4 gv = *(const float4*)&gW[(size_t)(k0 + kk) * UU + u0 + ju * 4];
            float xv = xs[rr][kk];
            acc.x += xv * gv.x; acc.y += xv * gv.y;
            acc.z += xv * gv.z; acc.w += xv * gv.w;
        }
        __syncthreads();
    }
    *(float4*)&q[(size_t)(r0 + rr) * UU + u0 + ju * 4] = acc;
}

// ---------------------------------------------------------------------------
// Init (unchanged, proven).
// ---------------------------------------------------------------------------
__global__ void init_kernel(const float* __restrict__ inputs,
                            const float* __restrict__ gbih, const float* __restrict__ gbhh,
                            const float* __restrict__ pbih, const float* __restrict__ pbhh,
                            const float* __restrict__ ebih, const float* __restrict__ ebhh,
                            float* __restrict__ hist, float* __restrict__ Pf,
                            ushort* __restrict__ gpack, ushort* __restrict__ ppack,
                            ushort* __restrict__ epack, float* __restrict__ biasp,
                            int* __restrict__ cnt, int* __restrict__ bar) {
    if (blockIdx.x == 0 && threadIdx.x < 33) {
        if (threadIdx.x < 32) cnt[threadIdx.x] = 0;
        else bar[0] = 0;
    }
    if (blockIdx.x < 128) {
        int i = blockIdx.x * 256 + threadIdx.x;
        int b = i >> 10, u = i & 1023;
        hist[i] = 0.f;
        Pf[i] = 0.f; Pf[32768 + i] = 0.f;
        int ex = AEX(u, b);
        int eh = ex + 32768;
        gpack[eh] = 0; gpack[APS + eh] = 0;
        ppack[eh] = 0; ppack[APS + eh] = 0;
        ppack[ASLOT + eh] = 0; ppack[ASLOT + APS + eh] = 0;
        epack[eh] = 0; epack[APS + eh] = 0;
        float x0 = inputs[((size_t)b * TT + 0) * UU + u];
        float x1 = inputs[((size_t)b * TT + 1) * UU + u];
        ushort h, l;
        split2(x0, h, l); gpack[ex] = h; gpack[APS + ex] = l;
        split2(x1, h, l); gpack[ASLOT + ex] = h; gpack[ASLOT + APS + ex] = l;
    } else {
        int idx = (blockIdx.x - 128) * 256 + threadIdx.x;
        int cell = idx >> 12, g4 = (idx >> 10) & 3, u = idx & 1023;
        const float* bih = (cell == 0) ? gbih : (cell == 1) ? pbih : ebih;
        const float* bhh = (cell == 0) ? gbhh : (cell == 1) ? pbhh : ebhh;
        float v;
        if (g4 == 0) v = bih[u] + bhh[u];
        else if (g4 == 1) v = bih[1024 + u] + bhh[1024 + u];
        else if (g4 == 2) v = bih[2048 + u];
        else v = bhh[2048 + u];
        biasp[idx] = v;
    }
}

// ---------------------------------------------------------------------------
// Grid barrier: drain sc1 stores, relaxed add, relaxed polls, one acquire-inv.
// ---------------------------------------------------------------------------
__device__ __forceinline__ void grid_barrier(int* bar, int target) {
    vm_drain();
    __syncthreads();
    if (threadIdx.x == 0) {
        __hip_atomic_fetch_add(bar, 1, __ATOMIC_RELAXED, __HIP_MEMORY_SCOPE_AGENT);
        while (__hip_atomic_load(bar, __ATOMIC_RELAXED, __HIP_MEMORY_SCOPE_AGENT) < target) {
            __builtin_amdgcn_s_sleep(8);
        }
        (void)__hip_atomic_load(bar, __ATOMIC_ACQUIRE, __HIP_MEMORY_SCOPE_AGENT);  // one inv
    }
    __syncthreads();
}

// ---------------------------------------------------------------------------
// Persistent kernel: 192 blocks x 512 threads (8 waves), 1 block/CU.
// Wave w: R/Z K-eighth ks=8w..8w+7; N reuses the SAME b-frags
// (waves 0-3 -> NX, waves 4-7 -> NH). Weights: hi R/Z/N + lo N in regs
// (32 bf16x8 = 128 regs), lo R/Z in LDS (128 KB). Loaded ONCE.
// ---------------------------------------------------------------------------
__global__ __launch_bounds__(512)
__attribute__((amdgpu_waves_per_eu(2)))
void persist_kernel(const float* __restrict__ inputs,
                    const ushort* __restrict__ wpack,
                    const float* __restrict__ biasp,
                    ushort* __restrict__ gpack, ushort* __restrict__ ppack,
                    ushort* __restrict__ epack,
                    float* __restrict__ hist, float* __restrict__ Pf,
                    const float* __restrict__ qall,
                    float* __restrict__ out,
                    float* __restrict__ attC, float* __restrict__ attML,
                    int* __restrict__ cnt, int* __restrict__ bar) {
    extern __shared__ char smraw[];
    float* lds_scr  = (float*)(smraw + SCR_OFF);
    float* lds_gm   = (float*)(smraw + GM_OFF);
    float* lds_red  = (float*)(smraw + RED_OFF);
    int*   lds_flag = (int*)(smraw + FLAG_OFF);

    const int blk = blockIdx.x, tid = threadIdx.x;
    const int cell = blk >> 6, jt = blk & 63;
    const int w = tid >> 6, lane = tid & 63;
    const int l15 = lane & 15, hi4 = lane >> 4;
    const int ab = blk & 31, ac = blk >> 5;
    const ushort* wp = wpack + (size_t)cell * WCELL;

    // ---- persistent weights ----
    bf16x8 whiR[8], whiZ[8], whiN[8], wloN[8];
    #pragma unroll
    for (int i = 0; i < 8; ++i) {
        const int ks = w * 8 + i;
        const size_t aoff = ((size_t)(jt * 256 + ks * 4 + hi4)) * 128 + (size_t)l15 * 8;
        whiR[i] = *(const bf16x8*)(wp + SR + aoff);
        whiZ[i] = *(const bf16x8*)(wp + SZ + aoff);
        bf16x8 rlo = *(const bf16x8*)(wp + SR + WPS + aoff);
        bf16x8 zlo = *(const bf16x8*)(wp + SZ + WPS + aoff);
        *(bf16x8*)(smraw + (((w * 16 + i) * 64 + lane) << 4)) = rlo;
        *(bf16x8*)(smraw + (((w * 16 + 8 + i) * 64 + lane) << 4)) = zlo;
        const int ksn = (w & 3) * 8 + i;
        const size_t noff = ((size_t)(jt * 128 + ksn * 4 + hi4)) * 128 + (size_t)l15 * 8;
        const size_t sN = (w < 4) ? SNX : SNH;
        whiN[i] = *(const bf16x8*)(wp + sN + noff);
        wloN[i] = *(const bf16x8*)(wp + sN + WPS + noff);
    }
    // ---- epilogue constants (1 output/thread) ----
    const int ebt = tid >> 8, eli = (tid >> 2) & 63, ei = tid & 3;
    const int eb = ebt * 16 + (eli & 15);
    const int eu = jt * 16 + (eli >> 4) * 4 + ei;
    const int eex = AEX(eu, eb);
    const float* bc = biasp + cell * 4096;
    const float bR = bc[eu], bZ = bc[1024 + eu];
    const float bNI = bc[2048 + eu], bNH = bc[3072 + eu];
    __syncthreads();

    int ep = 0;
    for (int t = 0; t <= TT + 1; ++t) {
        const int tc = t - cell;
        const bool gemmWork = (tc >= 0 && tc < TT);
        if (gemmWork) {
            f32x4 aR0 = {0,0,0,0}, aR1 = {0,0,0,0};
            f32x4 aZ0 = {0,0,0,0}, aZ1 = {0,0,0,0};
            f32x4 aN0 = {0,0,0,0}, aN1 = {0,0,0,0};
            ushort* apk = (cell == 0) ? gpack : (cell == 1) ? ppack : epack;
            const ushort* ap = apk + (size_t)(tc & 3) * ASLOT;
            const ushort* bbp = ap + ((size_t)hi4 * 32 + l15) * 8;
            #pragma unroll
            for (int i = 0; i < 8; ++i) {
                const int ks = w * 8 + i;
                const ushort* bp = bbp + (size_t)ks * 1024;
                bf16x8 bh0 = *(const bf16x8*)(bp);
                bf16x8 bh1 = *(const bf16x8*)(bp + 128);
                bf16x8 bl0 = *(const bf16x8*)(bp + APS);
                bf16x8 bl1 = *(const bf16x8*)(bp + APS + 128);
                bf16x8 rlo = *(const bf16x8*)(smraw + (((w * 16 + i) * 64 + lane) << 4));
                bf16x8 zlo = *(const bf16x8*)(smraw + (((w * 16 + 8 + i) * 64 + lane) << 4));
                aR0 = MF(whiR[i], bh0, aR0); aR0 = MF(whiR[i], bl0, aR0); aR0 = MF(rlo, bh0, aR0);
                aR1 = MF(whiR[i], bh1, aR1); aR1 = MF(whiR[i], bl1, aR1); aR1 = MF(rlo, bh1, aR1);
                aZ0 = MF(whiZ[i], bh0, aZ0); aZ0 = MF(whiZ[i], bl0, aZ0); aZ0 = MF(zlo, bh0, aZ0);
                aZ1 = MF(whiZ[i], bh1, aZ1); aZ1 = MF(whiZ[i], bl1, aZ1); aZ1 = MF(zlo, bh1, aZ1);
                aN0 = MF(whiN[i], bh0, aN0); aN0 = MF(whiN[i], bl0, aN0); aN0 = MF(wloN[i], bh0, aN0);
                aN1 = MF(whiN[i], bh1, aN1); aN1 = MF(whiN[i], bl1, aN1); aN1 = MF(wloN[i], bh1, aN1);
            }
            // ---- combine: R -> gm0, Z -> gm1, N -> gm2 (iN, waves 0-3) / gm3 (hN, 4-7)
            const int cbt = tid >> 8, cln = (tid >> 2) & 63, cc = tid & 3;
            __syncthreads();
            *(f32x4*)&lds_scr[((0 * 8 + w) * 64 + lane) * 4] = aR0;
            *(f32x4*)&lds_scr[((1 * 8 + w) * 64 + lane) * 4] = aR1;
            __syncthreads();
            {
                float s = 0.f;
                #pragma unroll
                for (int w2 = 0; w2 < 8; ++w2) s += lds_scr[((cbt * 8 + w2) * 64 + cln) * 4 + cc];
                lds_gm[((0 * 2 + cbt) * 64 + cln) * 4 + cc] = s;
            }
            __syncthreads();
            *(f32x4*)&lds_scr[((0 * 8 + w) * 64 + lane) * 4] = aZ0;
            *(f32x4*)&lds_scr[((1 * 8 + w) * 64 + lane) * 4] = aZ1;
            __syncthreads();
            {
                float s = 0.f;
                #pragma unroll
                for (int w2 = 0; w2 < 8; ++w2) s += lds_scr[((cbt * 8 + w2) * 64 + cln) * 4 + cc];
                lds_gm[((1 * 2 + cbt) * 64 + cln) * 4 + cc] = s;
            }
            __syncthreads();
            *(f32x4*)&lds_scr[((0 * 8 + w) * 64 + lane) * 4] = aN0;
            *(f32x4*)&lds_scr[((1 * 8 + w) * 64 + lane) * 4] = aN1;
            __syncthreads();
            {
                float iN = 0.f, hN = 0.f;
                #pragma unroll
                for (int w2 = 0; w2 < 4; ++w2) iN += lds_scr[((cbt * 8 + w2) * 64 + cln) * 4 + cc];
                #pragma unroll
                for (int w2 = 4; w2 < 8; ++w2) hN += lds_scr[((cbt * 8 + w2) * 64 + cln) * 4 + cc];
                lds_gm[((2 * 2 + cbt) * 64 + cln) * 4 + cc] = iN;
                lds_gm[((3 * 2 + cbt) * 64 + cln) * 4 + cc] = hN;
            }
            __syncthreads();
            // ---- epilogue (1 output/thread), all cross-block stores sc1 ----
            {
                const float R  = lds_gm[((0 * 2 + ebt) * 64 + eli) * 4 + ei];
                const float Z  = lds_gm[((1 * 2 + ebt) * 64 + eli) * 4 + ei];
                const float iN = lds_gm[((2 * 2 + ebt) * 64 + eli) * 4 + ei];
                const float hN = lds_gm[((3 * 2 + ebt) * 64 + eli) * 4 + ei];
                float hprev;
                if (cell == 0)      hprev = hist[((size_t)tc * BB + eb) * UU + eu];
                else if (cell == 1) hprev = Pf[(size_t)(tc & 3) * BB * UU + (size_t)eb * UU + eu];
                else                hprev = (tc > 0) ? out[((size_t)eb * TT + tc - 1) * UU + eu] : 0.f;
                const float r = 1.f / (1.f + expf(-(R + bR)));
                const float z = 1.f / (1.f + expf(-(Z + bZ)));
                const float n2 = tanhf(iN + bNI + r * (hN + bNH));
                const float val = (1.f - z) * n2 + z * hprev;
                ushort vh, vl; split2(val, vh, vl);
                if (cell == 0) {
                    store_f32_sc(&hist[((size_t)(tc + 1) * BB + eb) * UU + eu], val);
                    ushort* d = gpack + (size_t)((tc + 1) & 3) * ASLOT;
                    store_u16_sc(d + eex + 32768, vh);
                    store_u16_sc(d + APS + eex + 32768, vl);
                } else if (cell == 1) {
                    ushort* d = epack + (size_t)(tc & 3) * ASLOT;
                    store_u16_sc(d + eex, vh);
                    store_u16_sc(d + APS + eex, vl);
                    if (tc + 2 < TT) {
                        store_f32_sc(&Pf[(size_t)((tc + 2) & 3) * BB * UU + (size_t)eb * UU + eu], val);
                        ushort* d2 = ppack + (size_t)((tc + 2) & 3) * ASLOT;
                        store_u16_sc(d2 + eex + 32768, vh);
                        store_u16_sc(d2 + APS + eex + 32768, vl);
                        const float gx = val + inputs[((size_t)eb * TT + tc + 2) * UU + eu];
                        ushort gh, gl; split2(gx, gh, gl);
                        ushort* d3 = gpack + (size_t)((tc + 2) & 3) * ASLOT;
                        store_u16_sc(d3 + eex, gh);
                        store_u16_sc(d3 + APS + eex, gl);
                    }
                } else {
                    store_f32_sc(&out[((size_t)eb * TT + tc) * UU + eu], val);
                    if (tc + 1 < TT) {
                        ushort* d = epack + (size_t)((tc + 1) & 3) * ASLOT;
                        store_u16_sc(d + eex + 32768, vh);
                        store_u16_sc(d + APS + eex + 32768, vl);
                    }
                }
            }
        }
        // ---- attention chunk (ac, ab): single-pass online softmax, 8 waves ----
        if (t < TT) {
            const int nt2 = t + 1;
            const int cstr = (nt2 + NCHUNK - 1) / NCHUNK;
            const int r0 = ac * cstr;
            const int r1x = r0 + cstr;
            const int r1 = (r1x < nt2) ? r1x : nt2;
            const int n = r1 - r0;
            if (n <= 0) {
                #pragma unroll
                for (int rep = 0; rep < 2; ++rep)
                    store_f32_sc(&attC[((size_t)ac * BB + ab) * UU + tid + rep * 512], 0.f);
                if (tid == 0) {
                    store_f32_sc(&attML[((size_t)ac * BB + ab) * 2], -INFINITY);
                    store_f32_sc(&attML[((size_t)ac * BB + ab) * 2 + 1], 0.f);
                }
            } else {
                const float* qb = qall + ((size_t)t * BB + ab) * UU;
                float4 q0 = *(const float4*)&qb[lane * 4];
                float4 q1 = *(const float4*)&qb[256 + lane * 4];
                float4 q2 = *(const float4*)&qb[512 + lane * 4];
                float4 q3 = *(const float4*)&qb[768 + lane * 4];
                float m_run = -INFINITY, l_run = 0.f;
                float4 c0 = {0,0,0,0}, c1 = {0,0,0,0}, c2 = {0,0,0,0}, c3 = {0,0,0,0};
                for (int tp = r0 + w; tp < r1; tp += 8) {
                    const float* hr = hist + ((size_t)tp * BB + ab) * UU;
                    float4 h0 = *(const float4*)&hr[lane * 4];
                    float4 h1 = *(const float4*)&hr[256 + lane * 4];
                    float4 h2 = *(const float4*)&hr[512 + lane * 4];
                    float4 h3 = *(const float4*)&hr[768 + lane * 4];
                    float s = h0.x*q0.x + h0.y*q0.y + h0.z*q0.z + h0.w*q0.w
                            + h1.x*q1.x + h1.y*q1.y + h1.z*q1.z + h1.w*q1.w
                            + h2.x*q2.x + h2.y*q2.y + h2.z*q2.z + h2.w*q2.w
                            + h3.x*q3.x + h3.y*q3.y + h3.z*q3.z + h3.w*q3.w;
                    #pragma unroll
                    for (int off = 32; off; off >>= 1) s += __shfl_xor(s, off);
                    const float mn = fmaxf(m_run, s);
                    const float sc = expf(m_run - mn);
                    const float e2 = expf(s - mn);
                    c0.x = c0.x*sc + e2*h0.x; c0.y = c0.y*sc + e2*h0.y; c0.z = c0.z*sc + e2*h0.z; c0.w = c0.w*sc + e2*h0.w;
                    c1.x = c1.x*sc + e2*h1.x; c1.y = c1.y*sc + e2*h1.y; c1.z = c1.z*sc + e2*h1.z; c1.w = c1.w*sc + e2*h1.w;
                    c2.x = c2.x*sc + e2*h2.x; c2.y = c2.y*sc + e2*h2.y; c2.z = c2.z*sc + e2*h2.z; c2.w = c2.w*sc + e2*h2.w;
                    c3.x = c3.x*sc + e2*h3.x; c3.y = c3.y*sc + e2*h3.y; c3.z = c3.z*sc + e2*h3.z; c3.w = c3.w*sc + e2*h3.w;
                    l_run = l_run * sc + e2;
                    m_run = mn;
                }
                // pass 0: elems [0,512) via c0,c1; per-wave m/l publish
                *(float4*)&lds_scr[w * 512 + lane * 4] = c0;
                *(float4*)&lds_scr[w * 512 + 256 + lane * 4] = c1;
                if (lane == 0) { lds_red[w] = m_run; lds_red[8 + w] = l_run; }
                __syncthreads();
                float M = lds_red[0];
                #pragma unroll
                for (int k = 1; k < 8; ++k) M = fmaxf(M, lds_red[k]);
                float ww[8], L = 0.f;
                #pragma unroll
                for (int k = 0; k < 8; ++k) { ww[k] = expf(lds_red[k] - M); L += ww[k] * lds_red[8 + k]; }
                if (tid == 0) {
                    store_f32_sc(&attML[((size_t)ac * BB + ab) * 2], M);
                    store_f32_sc(&attML[((size_t)ac * BB + ab) * 2 + 1], L);
                }
                {
                    float s = 0.f;
                    #pragma unroll
                    for (int w2 = 0; w2 < 8; ++w2) s += ww[w2] * lds_scr[w2 * 512 + tid];
                    store_f32_sc(&attC[((size_t)ac * BB + ab) * UU + tid], s);
                }
                __syncthreads();
                // pass 1: elems [512,1024) via c2,c3
                *(float4*)&lds_scr[w * 512 + lane * 4] = c2;
                *(float4*)&lds_scr[w * 512 + 256 + lane * 4] = c3;
                __syncthreads();
                {
                    float s = 0.f;
                    #pragma unroll
                    for (int w2 = 0; w2 < 8; ++w2) s += ww[w2] * lds_scr[w2 * 512 + tid];
                    store_f32_sc(&attC[((size_t)ac * BB + ab) * UU + 512 + tid], s);
                }
            }
            // publish chunk results, then count arrivals (sc1 stores drained first)
            vm_drain();
            __syncthreads();
            if (tid == 0) {
                int old = __hip_atomic_fetch_add(cnt + ab, 1, __ATOMIC_RELAXED,
                                                 __HIP_MEMORY_SCOPE_AGENT);
                lds_flag[0] = ((old % NCHUNK) == (NCHUNK - 1)) ? 1 : 0;
            }
            __syncthreads();
            if (lds_flag[0]) {
                // Finisher (6th arriver): producers' sc1 stores are in L3; this
                // block's L2 was invalidated at stage start and hasn't cached
                // attC/attML since -> normal loads are fresh.
                float mm[NCHUNK], ll[NCHUNK];
                #pragma unroll
                for (int c = 0; c < NCHUNK; ++c) {
                    mm[c] = attML[((size_t)c * BB + ab) * 2];
                    ll[c] = attML[((size_t)c * BB + ab) * 2 + 1];
                }
                float M2 = mm[0];
                #pragma unroll
                for (int c = 1; c < NCHUNK; ++c) M2 = fmaxf(M2, mm[c]);
                float den = 0.f, wc[NCHUNK];
                #pragma unroll
                for (int c = 0; c < NCHUNK; ++c) { wc[c] = expf(mm[c] - M2); den += wc[c] * ll[c]; }
                const float inv = 1.f / den;
                ushort* d = ppack + (size_t)(t & 3) * ASLOT;
                #pragma unroll
                for (int rep = 0; rep < 2; ++rep) {
                    const int e = tid + rep * 512;
                    float s3 = 0.f;
                    #pragma unroll
                    for (int c = 0; c < NCHUNK; ++c) s3 += wc[c] * attC[((size_t)c * BB + ab) * UU + e];
                    const float xv = s3 * inv + inputs[((size_t)ab * TT + t) * UU + e];
                    ushort vh2, vl2; split2(xv, vh2, vl2);
                    const int ex2 = AEX(e, ab);
                    store_u16_sc(d + ex2, vh2);
                    store_u16_sc(d + APS + ex2, vl2);
                }
            }
        }
        ++ep;
        grid_barrier(bar, GRIDN * ep);
    }
}

extern "C" void kernel_launch(void* const* d_in, const int* in_sizes, int n_in,
                              void* d_out, int out_size, void* d_ws, size_t ws_size,
                              hipStream_t stream) {
    (void)in_sizes; (void)n_in; (void)out_size; (void)ws_size;
    const float* inputs = (const float*)d_in[0];
    const float* gW   = (const float*)d_in[1];
    const float* gWih = (const float*)d_in[2];
    const float* gWhh = (const float*)d_in[3];
    const float* gbih = (const float*)d_in[4];
    const float* gbhh = (const float*)d_in[5];
    const float* pWih = (const float*)d_in[6];
    const float* pWhh = (const float*)d_in[7];
    const float* pbih = (const float*)d_in[8];
    const float* pbhh = (const float*)d_in[9];
    const float* eWih = (const float*)d_in[10];
    const float* eWhh = (const float*)d_in[11];
    const float* ebih = (const float*)d_in[12];
    const float* ebhh = (const float*)d_in[13];
    float* out = (float*)d_out;

    char* ws = (char*)d_ws;
    size_t off = 0;
    auto alloc = [&](size_t bytes) {
        void* p = ws + off;
        off += (bytes + 255) & ~(size_t)255;
        return p;
    };
    ushort* wpack = (ushort*)alloc((size_t)3 * WCELL * 2);
    ushort* gpack = (ushort*)alloc((size_t)4 * ASLOT * 2);
    ushort* ppack = (ushort*)alloc((size_t)4 * ASLOT * 2);
    ushort* epack = (ushort*)alloc((size_t)4 * ASLOT * 2);
    float* hist  = (float*)alloc((size_t)(TT + 1) * BB * UU * 4);
    float* qall  = (float*)alloc((size_t)TT * BB * UU * 4);
    float* Pf    = (float*)alloc((size_t)4 * BB * UU * 4);
    float* biasp = (float*)alloc((size_t)3 * 4096 * 4);
    float* attC  = (float*)alloc((size_t)NCHUNK * BB * UU * 4);
    float* attML = (float*)alloc((size_t)NCHUNK * BB * 2 * 4);
    int*   cnt   = (int*)alloc(32 * 4);
    int*   bar   = (int*)alloc(4);

    packw_kernel<<<12288, 256, 0, stream>>>(gWih, gWhh, wpack);
    packw_kernel<<<12288, 256, 0, stream>>>(pWih, pWhh, wpack + WCELL);
    packw_kernel<<<12288, 256, 0, stream>>>(eWih, eWhh, wpack + 2 * (size_t)WCELL);
    qall_kernel<<<dim3(256, 32), 256, 0, stream>>>(inputs, gW, qall);
    init_kernel<<<176, 256, 0, stream>>>(inputs, gbih, gbhh, pbih, pbhh, ebih, ebhh,
                                         hist, Pf, gpack, ppack, epack, biasp, cnt, bar);

    hipFuncSetAttribute((const void*)persist_kernel,
                        hipFuncAttributeMaxDynamicSharedMemorySize, LDSB);
    void* args[] = {(void*)&inputs, (void*)&wpack, (void*)&biasp,
                    (void*)&gpack, (void*)&ppack, (void*)&epack,
                    (void*)&hist, (void*)&Pf, (void*)&qall, (void*)&out,
                    (void*)&attC, (void*)&attML, (void*)&cnt, (void*)&bar};
    hipError_t ce = hipLaunchCooperativeKernel((const void*)persist_kernel,
                                               dim3(GRIDN), dim3(512), args,
                                               (unsigned)LDSB, stream);
    if (ce != hipSuccess) {
        (void)hipGetLastError();
        // 192 blocks at 1 block/CU on a 256-CU part are co-resident; the
        // monotone-counter barrier is safe under a plain launch too.
        persist_kernel<<<GRIDN, 512, LDSB, stream>>>(inputs, wpack, biasp,
                                                     gpack, ppack, epack,
                                                     hist, Pf, qall, out,
                                                     attC, attML, cnt, bar);
    }
}

// Round 9
// 5931.602 us; speedup vs baseline: 3.4247x; 1.0510x over previous
//
#include <hip/hip_runtime.h>
#include <math.h>

// Problem constants: U=H=1024, B=32, T=256.
#define UU 1024
#define BB 32
#define TT 256
#define NCHUNK 6
#define GRIDN 192

// Weight pack geometry (ushort elems). Per cell: [2 planes][sections r,z,nx,nh]
#define WPS   6291456u
#define WCELL (2u * WPS)
#define SR  0u
#define SZ  2097152u
#define SNX 4194304u
#define SNH 5242880u
// Act pack: per slot [2 planes][64 ks][4 hi][32 b][8 e]; x-half [0,32768), h-half +32768
#define APS   65536u
#define ASLOT (2u * APS)
#define AEX(u, b) ((((((u) >> 5) * 4 + (((u) >> 3) & 3)) * 32 + (b)) * 8) + ((u) & 7))

// Dynamic LDS layout (bytes): [0,128K) r/z lo-plane weights; then scratch.
#define SCR_OFF  131072   // 16 KB scratch (combine dumps / att ctx reduce)
#define GM_OFF   147456   // 8 KB gate matrix [4 gates][2 bt][64 lane][4]
#define RED_OFF  155648   // 16 f32
#define FLAG_OFF 155712
#define LDSB     155776

typedef __attribute__((ext_vector_type(8))) short bf16x8;
typedef __attribute__((ext_vector_type(4))) float f32x4;
#define MF(a, b, c) __builtin_amdgcn_mfma_f32_16x16x32_bf16((a), (b), (c), 0, 0, 0)

__device__ __forceinline__ ushort bf16rne(float v) {
    uint x = __float_as_uint(v);
    uint r = (x + 0x7fffu + ((x >> 16) & 1u)) >> 16;
    return (ushort)r;
}
__device__ __forceinline__ float ubf2f(ushort u) {
    return __uint_as_float(((uint)u) << 16);
}
__device__ __forceinline__ void split2(float v, ushort& h, ushort& l) {
    h = bf16rne(v);
    l = bf16rne(v - ubf2f(h));
}
// Agent-scope write-through stores (reach L3 directly; no wbl2 needed).
__device__ __forceinline__ void store_f32_sc(float* p, float v) {
    asm volatile("global_store_dword %0, %1, off sc1" :: "v"(p), "v"(v) : "memory");
}
__device__ __forceinline__ void store_u16_sc(ushort* p, ushort v) {
    uint vv = v;
    asm volatile("global_store_short %0, %1, off sc1" :: "v"(p), "v"(vv) : "memory");
}
__device__ __forceinline__ void vm_drain() {
    asm volatile("s_waitcnt vmcnt(0)" ::: "memory");
}
// Agent-coherent loads (read at L3 coherence point, never trust local L2).
// Compiler-tracked waitcnt -> pipelines normally.
__device__ __forceinline__ float load_f32_ag(const float* p) {
    return __hip_atomic_load(p, __ATOMIC_RELAXED, __HIP_MEMORY_SCOPE_AGENT);
}
__device__ __forceinline__ bf16x8 load_frag_ag(const ushort* p) {
    union { unsigned long long q[2]; bf16x8 v; } u;
    u.q[0] = __hip_atomic_load((const unsigned long long*)p,
                               __ATOMIC_RELAXED, __HIP_MEMORY_SCOPE_AGENT);
    u.q[1] = __hip_atomic_load((const unsigned long long*)(p + 4),
                               __ATOMIC_RELAXED, __HIP_MEMORY_SCOPE_AGENT);
    return u.v;
}

// ---------------------------------------------------------------------------
// Weight pack (unchanged, proven).
// ---------------------------------------------------------------------------
__global__ void packw_kernel(const float* __restrict__ Wih,
                             const float* __restrict__ Whh,
                             ushort* __restrict__ wp) {
    int tile = blockIdx.x;
    int sec, jt, ks, nks;
    size_t soff;
    if (tile < 8192) {
        sec = tile >> 12; int l = tile & 4095; jt = l >> 6; ks = l & 63; nks = 64;
        soff = sec ? SZ : SR;
    } else {
        int l2 = tile - 8192; sec = 2 + (l2 >> 11); int l = l2 & 2047; jt = l >> 5; ks = l & 31; nks = 32;
        soff = (sec == 2) ? SNX : SNH;
    }
    int p = threadIdx.x;
    int e0 = (p & 3) * 2, ul = (p >> 2) & 15, hi = p >> 6;
    int u = jt * 16 + ul;
    int kk = ks * 32 + hi * 8 + e0;
    float2 w;
    if (sec < 2) {
        int row = (sec ? 1024 : 0) + u;
        if (kk < 1024) w = *(const float2*)&Wih[(size_t)row * UU + kk];
        else           w = *(const float2*)&Whh[(size_t)row * UU + kk - 1024];
    } else if (sec == 2) {
        w = *(const float2*)&Wih[(size_t)(2048 + u) * UU + kk];
    } else {
        w = *(const float2*)&Whh[(size_t)(2048 + u) * UU + kk];
    }
    ushort h0, l0, h1, l1;
    split2(w.x, h0, l0); split2(w.y, h1, l1);
    size_t ob = soff + ((((size_t)jt * nks + ks) * 4 + hi) * 16 + ul) * 8 + e0;
    *(uint*)(wp + ob)       = (uint)h0 | ((uint)h1 << 16);
    *(uint*)(wp + WPS + ob) = (uint)l0 | ((uint)l1 << 16);
}

// ---------------------------------------------------------------------------
// q_all[t][b][u] = sum_k inputs[b][t][k] * global_W[k][u]  (fp32)
// ---------------------------------------------------------------------------
__global__ void qall_kernel(const float* __restrict__ x,
                            const float* __restrict__ gW,
                            float* __restrict__ q) {
    __shared__ float xs[32][65];
    int r0 = blockIdx.x * 32, u0 = blockIdx.y * 32;
    int tid = threadIdx.x;
    int rr = tid >> 3, ju = tid & 7;
    float4 acc = {0.f, 0.f, 0.f, 0.f};
    for (int k0 = 0; k0 < UU; k0 += 64) {
        for (int e = tid; e < 32 * 64; e += 256) {
            int lr = e >> 6, lk = e & 63;
            int r = r0 + lr;
            int tt = r >> 5, bb = r & 31;
            xs[lr][lk] = x[((size_t)bb * TT + tt) * UU + k0 + lk];
        }
        __syncthreads();
        #pragma unroll 4
        for (int kk = 0; kk < 64; ++kk) {
            float4 gv = *(const float4*)&gW[(size_t)(k0 + kk) * UU + u0 + ju * 4];
            float xv = xs[rr][kk];
            acc.x += xv * gv.x; acc.y += xv * gv.y;
            acc.z += xv * gv.z; acc.w += xv * gv.w;
        }
        __syncthreads();
    }
    *(float4*)&q[(size_t)(r0 + rr) * UU + u0 + ju * 4] = acc;
}

// ---------------------------------------------------------------------------
// Init (unchanged, proven).
// ---------------------------------------------------------------------------
__global__ void init_kernel(const float* __restrict__ inputs,
                            const float* __restrict__ gbih, const float* __restrict__ gbhh,
                            const float* __restrict__ pbih, const float* __restrict__ pbhh,
                            const float* __restrict__ ebih, const float* __restrict__ ebhh,
                            float* __restrict__ hist, float* __restrict__ Pf,
                            ushort* __restrict__ gpack, ushort* __restrict__ ppack,
                            ushort* __restrict__ epack, float* __restrict__ biasp,
                            int* __restrict__ cnt, int* __restrict__ bar) {
    if (blockIdx.x == 0 && threadIdx.x < 33) {
        if (threadIdx.x < 32) cnt[threadIdx.x] = 0;
        else bar[0] = 0;
    }
    if (blockIdx.x < 128) {
        int i = blockIdx.x * 256 + threadIdx.x;
        int b = i >> 10, u = i & 1023;
        hist[i] = 0.f;
        Pf[i] = 0.f; Pf[32768 + i] = 0.f;
        int ex = AEX(u, b);
        int eh = ex + 32768;
        gpack[eh] = 0; gpack[APS + eh] = 0;
        ppack[eh] = 0; ppack[APS + eh] = 0;
        ppack[ASLOT + eh] = 0; ppack[ASLOT + APS + eh] = 0;
        epack[eh] = 0; epack[APS + eh] = 0;
        float x0 = inputs[((size_t)b * TT + 0) * UU + u];
        float x1 = inputs[((size_t)b * TT + 1) * UU + u];
        ushort h, l;
        split2(x0, h, l); gpack[ex] = h; gpack[APS + ex] = l;
        split2(x1, h, l); gpack[ASLOT + ex] = h; gpack[ASLOT + APS + ex] = l;
    } else {
        int idx = (blockIdx.x - 128) * 256 + threadIdx.x;
        int cell = idx >> 12, g4 = (idx >> 10) & 3, u = idx & 1023;
        const float* bih = (cell == 0) ? gbih : (cell == 1) ? pbih : ebih;
        const float* bhh = (cell == 0) ? gbhh : (cell == 1) ? pbhh : ebhh;
        float v;
        if (g4 == 0) v = bih[u] + bhh[u];
        else if (g4 == 1) v = bih[1024 + u] + bhh[1024 + u];
        else if (g4 == 2) v = bih[2048 + u];
        else v = bhh[2048 + u];
        biasp[idx] = v;
    }
}

// ---------------------------------------------------------------------------
// Grid barrier: drain sc1 stores, relaxed add, relaxed polls. NO acquire-inv:
// immutable data (hist/qall/inputs) stays L2-resident across stages; mutable
// rings are read with agent-coherent loads instead.
// ---------------------------------------------------------------------------
__device__ __forceinline__ void grid_barrier(int* bar, int target) {
    vm_drain();
    __syncthreads();
    if (threadIdx.x == 0) {
        __hip_atomic_fetch_add(bar, 1, __ATOMIC_RELAXED, __HIP_MEMORY_SCOPE_AGENT);
        while (__hip_atomic_load(bar, __ATOMIC_RELAXED, __HIP_MEMORY_SCOPE_AGENT) < target) {
            __builtin_amdgcn_s_sleep(8);
        }
    }
    __syncthreads();
}

// ---------------------------------------------------------------------------
// Persistent kernel: 192 blocks x 512 threads (8 waves), 1 block/CU.
// Cache policy per buffer (safe because a cached load only needs "no L2 can
// hold a pre-write copy of the line"):
//   hist / out / qall / inputs / biasp : normal cached loads (write-once rows,
//     first read strictly after write; read-only data).
//   act rings (gpack/ppack/epack), Pf ring, attC/attML : agent-coherent loads.
// ---------------------------------------------------------------------------
__global__ __launch_bounds__(512)
__attribute__((amdgpu_waves_per_eu(2)))
void persist_kernel(const float* __restrict__ inputs,
                    const ushort* __restrict__ wpack,
                    const float* __restrict__ biasp,
                    ushort* __restrict__ gpack, ushort* __restrict__ ppack,
                    ushort* __restrict__ epack,
                    float* __restrict__ hist, float* __restrict__ Pf,
                    const float* __restrict__ qall,
                    float* __restrict__ out,
                    float* __restrict__ attC, float* __restrict__ attML,
                    int* __restrict__ cnt, int* __restrict__ bar) {
    extern __shared__ char smraw[];
    float* lds_scr  = (float*)(smraw + SCR_OFF);
    float* lds_gm   = (float*)(smraw + GM_OFF);
    float* lds_red  = (float*)(smraw + RED_OFF);
    int*   lds_flag = (int*)(smraw + FLAG_OFF);

    const int blk = blockIdx.x, tid = threadIdx.x;
    const int cell = blk >> 6, jt = blk & 63;
    const int w = tid >> 6, lane = tid & 63;
    const int l15 = lane & 15, hi4 = lane >> 4;
    const int ab = blk & 31, ac = blk >> 5;
    const ushort* wp = wpack + (size_t)cell * WCELL;

    // ---- persistent weights ----
    bf16x8 whiR[8], whiZ[8], whiN[8], wloN[8];
    #pragma unroll
    for (int i = 0; i < 8; ++i) {
        const int ks = w * 8 + i;
        const size_t aoff = ((size_t)(jt * 256 + ks * 4 + hi4)) * 128 + (size_t)l15 * 8;
        whiR[i] = *(const bf16x8*)(wp + SR + aoff);
        whiZ[i] = *(const bf16x8*)(wp + SZ + aoff);
        bf16x8 rlo = *(const bf16x8*)(wp + SR + WPS + aoff);
        bf16x8 zlo = *(const bf16x8*)(wp + SZ + WPS + aoff);
        *(bf16x8*)(smraw + (((w * 16 + i) * 64 + lane) << 4)) = rlo;
        *(bf16x8*)(smraw + (((w * 16 + 8 + i) * 64 + lane) << 4)) = zlo;
        const int ksn = (w & 3) * 8 + i;
        const size_t noff = ((size_t)(jt * 128 + ksn * 4 + hi4)) * 128 + (size_t)l15 * 8;
        const size_t sN = (w < 4) ? SNX : SNH;
        whiN[i] = *(const bf16x8*)(wp + sN + noff);
        wloN[i] = *(const bf16x8*)(wp + sN + WPS + noff);
    }
    // ---- epilogue constants (1 output/thread) ----
    const int ebt = tid >> 8, eli = (tid >> 2) & 63, ei = tid & 3;
    const int eb = ebt * 16 + (eli & 15);
    const int eu = jt * 16 + (eli >> 4) * 4 + ei;
    const int eex = AEX(eu, eb);
    const float* bc = biasp + cell * 4096;
    const float bR = bc[eu], bZ = bc[1024 + eu];
    const float bNI = bc[2048 + eu], bNH = bc[3072 + eu];
    __syncthreads();

    int ep = 0;
    for (int t = 0; t <= TT + 1; ++t) {
        const int tc = t - cell;
        const bool gemmWork = (tc >= 0 && tc < TT);
        if (gemmWork) {
            f32x4 aR0 = {0,0,0,0}, aR1 = {0,0,0,0};
            f32x4 aZ0 = {0,0,0,0}, aZ1 = {0,0,0,0};
            f32x4 aN0 = {0,0,0,0}, aN1 = {0,0,0,0};
            ushort* apk = (cell == 0) ? gpack : (cell == 1) ? ppack : epack;
            const ushort* ap = apk + (size_t)(tc & 3) * ASLOT;
            const ushort* bbp = ap + ((size_t)hi4 * 32 + l15) * 8;
            #pragma unroll
            for (int i = 0; i < 8; ++i) {
                const int ks = w * 8 + i;
                const ushort* bp = bbp + (size_t)ks * 1024;
                bf16x8 bh0 = load_frag_ag(bp);
                bf16x8 bh1 = load_frag_ag(bp + 128);
                bf16x8 bl0 = load_frag_ag(bp + APS);
                bf16x8 bl1 = load_frag_ag(bp + APS + 128);
                bf16x8 rlo = *(const bf16x8*)(smraw + (((w * 16 + i) * 64 + lane) << 4));
                bf16x8 zlo = *(const bf16x8*)(smraw + (((w * 16 + 8 + i) * 64 + lane) << 4));
                aR0 = MF(whiR[i], bh0, aR0); aR0 = MF(whiR[i], bl0, aR0); aR0 = MF(rlo, bh0, aR0);
                aR1 = MF(whiR[i], bh1, aR1); aR1 = MF(whiR[i], bl1, aR1); aR1 = MF(rlo, bh1, aR1);
                aZ0 = MF(whiZ[i], bh0, aZ0); aZ0 = MF(whiZ[i], bl0, aZ0); aZ0 = MF(zlo, bh0, aZ0);
                aZ1 = MF(whiZ[i], bh1, aZ1); aZ1 = MF(whiZ[i], bl1, aZ1); aZ1 = MF(zlo, bh1, aZ1);
                aN0 = MF(whiN[i], bh0, aN0); aN0 = MF(whiN[i], bl0, aN0); aN0 = MF(wloN[i], bh0, aN0);
                aN1 = MF(whiN[i], bh1, aN1); aN1 = MF(whiN[i], bl1, aN1); aN1 = MF(wloN[i], bh1, aN1);
            }
            // ---- combine: R -> gm0, Z -> gm1, N -> gm2 (iN, waves 0-3) / gm3 (hN, 4-7)
            const int cbt = tid >> 8, cln = (tid >> 2) & 63, cc = tid & 3;
            __syncthreads();
            *(f32x4*)&lds_scr[((0 * 8 + w) * 64 + lane) * 4] = aR0;
            *(f32x4*)&lds_scr[((1 * 8 + w) * 64 + lane) * 4] = aR1;
            __syncthreads();
            {
                float s = 0.f;
                #pragma unroll
                for (int w2 = 0; w2 < 8; ++w2) s += lds_scr[((cbt * 8 + w2) * 64 + cln) * 4 + cc];
                lds_gm[((0 * 2 + cbt) * 64 + cln) * 4 + cc] = s;
            }
            __syncthreads();
            *(f32x4*)&lds_scr[((0 * 8 + w) * 64 + lane) * 4] = aZ0;
            *(f32x4*)&lds_scr[((1 * 8 + w) * 64 + lane) * 4] = aZ1;
            __syncthreads();
            {
                float s = 0.f;
                #pragma unroll
                for (int w2 = 0; w2 < 8; ++w2) s += lds_scr[((cbt * 8 + w2) * 64 + cln) * 4 + cc];
                lds_gm[((1 * 2 + cbt) * 64 + cln) * 4 + cc] = s;
            }
            __syncthreads();
            *(f32x4*)&lds_scr[((0 * 8 + w) * 64 + lane) * 4] = aN0;
            *(f32x4*)&lds_scr[((1 * 8 + w) * 64 + lane) * 4] = aN1;
            __syncthreads();
            {
                float iN = 0.f, hN = 0.f;
                #pragma unroll
                for (int w2 = 0; w2 < 4; ++w2) iN += lds_scr[((cbt * 8 + w2) * 64 + cln) * 4 + cc];
                #pragma unroll
                for (int w2 = 4; w2 < 8; ++w2) hN += lds_scr[((cbt * 8 + w2) * 64 + cln) * 4 + cc];
                lds_gm[((2 * 2 + cbt) * 64 + cln) * 4 + cc] = iN;
                lds_gm[((3 * 2 + cbt) * 64 + cln) * 4 + cc] = hN;
            }
            __syncthreads();
            // ---- epilogue (1 output/thread), all cross-block stores sc1 ----
            {
                const float R  = lds_gm[((0 * 2 + ebt) * 64 + eli) * 4 + ei];
                const float Z  = lds_gm[((1 * 2 + ebt) * 64 + eli) * 4 + ei];
                const float iN = lds_gm[((2 * 2 + ebt) * 64 + eli) * 4 + ei];
                const float hN = lds_gm[((3 * 2 + ebt) * 64 + eli) * 4 + ei];
                float hprev;
                if (cell == 0)      hprev = hist[((size_t)tc * BB + eb) * UU + eu];
                else if (cell == 1) hprev = load_f32_ag(&Pf[(size_t)(tc & 3) * BB * UU + (size_t)eb * UU + eu]);
                else                hprev = (tc > 0) ? out[((size_t)eb * TT + tc - 1) * UU + eu] : 0.f;
                const float r = 1.f / (1.f + expf(-(R + bR)));
                const float z = 1.f / (1.f + expf(-(Z + bZ)));
                const float n2 = tanhf(iN + bNI + r * (hN + bNH));
                const float val = (1.f - z) * n2 + z * hprev;
                ushort vh, vl; split2(val, vh, vl);
                if (cell == 0) {
                    store_f32_sc(&hist[((size_t)(tc + 1) * BB + eb) * UU + eu], val);
                    ushort* d = gpack + (size_t)((tc + 1) & 3) * ASLOT;
                    store_u16_sc(d + eex + 32768, vh);
                    store_u16_sc(d + APS + eex + 32768, vl);
                } else if (cell == 1) {
                    ushort* d = epack + (size_t)(tc & 3) * ASLOT;
                    store_u16_sc(d + eex, vh);
                    store_u16_sc(d + APS + eex, vl);
                    if (tc + 2 < TT) {
                        store_f32_sc(&Pf[(size_t)((tc + 2) & 3) * BB * UU + (size_t)eb * UU + eu], val);
                        ushort* d2 = ppack + (size_t)((tc + 2) & 3) * ASLOT;
                        store_u16_sc(d2 + eex + 32768, vh);
                        store_u16_sc(d2 + APS + eex + 32768, vl);
                        const float gx = val + inputs[((size_t)eb * TT + tc + 2) * UU + eu];
                        ushort gh, gl; split2(gx, gh, gl);
                        ushort* d3 = gpack + (size_t)((tc + 2) & 3) * ASLOT;
                        store_u16_sc(d3 + eex, gh);
                        store_u16_sc(d3 + APS + eex, gl);
                    }
                } else {
                    store_f32_sc(&out[((size_t)eb * TT + tc) * UU + eu], val);
                    if (tc + 1 < TT) {
                        ushort* d = epack + (size_t)((tc + 1) & 3) * ASLOT;
                        store_u16_sc(d + eex + 32768, vh);
                        store_u16_sc(d + APS + eex + 32768, vl);
                    }
                }
            }
        }
        // ---- attention chunk (ac, ab): single-pass online softmax, 8 waves ----
        if (t < TT) {
            const int nt2 = t + 1;
            const int cstr = (nt2 + NCHUNK - 1) / NCHUNK;
            const int r0 = ac * cstr;
            const int r1x = r0 + cstr;
            const int r1 = (r1x < nt2) ? r1x : nt2;
            const int n = r1 - r0;
            if (n <= 0) {
                #pragma unroll
                for (int rep = 0; rep < 2; ++rep)
                    store_f32_sc(&attC[((size_t)ac * BB + ab) * UU + tid + rep * 512], 0.f);
                if (tid == 0) {
                    store_f32_sc(&attML[((size_t)ac * BB + ab) * 2], -INFINITY);
                    store_f32_sc(&attML[((size_t)ac * BB + ab) * 2 + 1], 0.f);
                }
            } else {
                const float* qb = qall + ((size_t)t * BB + ab) * UU;
                float4 q0 = *(const float4*)&qb[lane * 4];
                float4 q1 = *(const float4*)&qb[256 + lane * 4];
                float4 q2 = *(const float4*)&qb[512 + lane * 4];
                float4 q3 = *(const float4*)&qb[768 + lane * 4];
                float m_run = -INFINITY, l_run = 0.f;
                float4 c0 = {0,0,0,0}, c1 = {0,0,0,0}, c2 = {0,0,0,0}, c3 = {0,0,0,0};
                for (int tp = r0 + w; tp < r1; tp += 8) {
                    const float* hr = hist + ((size_t)tp * BB + ab) * UU;
                    float4 h0 = *(const float4*)&hr[lane * 4];
                    float4 h1 = *(const float4*)&hr[256 + lane * 4];
                    float4 h2 = *(const float4*)&hr[512 + lane * 4];
                    float4 h3 = *(const float4*)&hr[768 + lane * 4];
                    float s = h0.x*q0.x + h0.y*q0.y + h0.z*q0.z + h0.w*q0.w
                            + h1.x*q1.x + h1.y*q1.y + h1.z*q1.z + h1.w*q1.w
                            + h2.x*q2.x + h2.y*q2.y + h2.z*q2.z + h2.w*q2.w
                            + h3.x*q3.x + h3.y*q3.y + h3.z*q3.z + h3.w*q3.w;
                    #pragma unroll
                    for (int off = 32; off; off >>= 1) s += __shfl_xor(s, off);
                    const float mn = fmaxf(m_run, s);
                    const float sc = expf(m_run - mn);
                    const float e2 = expf(s - mn);
                    c0.x = c0.x*sc + e2*h0.x; c0.y = c0.y*sc + e2*h0.y; c0.z = c0.z*sc + e2*h0.z; c0.w = c0.w*sc + e2*h0.w;
                    c1.x = c1.x*sc + e2*h1.x; c1.y = c1.y*sc + e2*h1.y; c1.z = c1.z*sc + e2*h1.z; c1.w = c1.w*sc + e2*h1.w;
                    c2.x = c2.x*sc + e2*h2.x; c2.y = c2.y*sc + e2*h2.y; c2.z = c2.z*sc + e2*h2.z; c2.w = c2.w*sc + e2*h2.w;
                    c3.x = c3.x*sc + e2*h3.x; c3.y = c3.y*sc + e2*h3.y; c3.z = c3.z*sc + e2*h3.z; c3.w = c3.w*sc + e2*h3.w;
                    l_run = l_run * sc + e2;
                    m_run = mn;
                }
                // pass 0: elems [0,512) via c0,c1; per-wave m/l publish
                *(float4*)&lds_scr[w * 512 + lane * 4] = c0;
                *(float4*)&lds_scr[w * 512 + 256 + lane * 4] = c1;
                if (lane == 0) { lds_red[w] = m_run; lds_red[8 + w] = l_run; }
                __syncthreads();
                float M = lds_red[0];
                #pragma unroll
                for (int k = 1; k < 8; ++k) M = fmaxf(M, lds_red[k]);
                float ww[8], L = 0.f;
                #pragma unroll
                for (int k = 0; k < 8; ++k) { ww[k] = expf(lds_red[k] - M); L += ww[k] * lds_red[8 + k]; }
                if (tid == 0) {
                    store_f32_sc(&attML[((size_t)ac * BB + ab) * 2], M);
                    store_f32_sc(&attML[((size_t)ac * BB + ab) * 2 + 1], L);
                }
                {
                    float s = 0.f;
                    #pragma unroll
                    for (int w2 = 0; w2 < 8; ++w2) s += ww[w2] * lds_scr[w2 * 512 + tid];
                    store_f32_sc(&attC[((size_t)ac * BB + ab) * UU + tid], s);
                }
                __syncthreads();
                // pass 1: elems [512,1024) via c2,c3
                *(float4*)&lds_scr[w * 512 + lane * 4] = c2;
                *(float4*)&lds_scr[w * 512 + 256 + lane * 4] = c3;
                __syncthreads();
                {
                    float s = 0.f;
                    #pragma unroll
                    for (int w2 = 0; w2 < 8; ++w2) s += ww[w2] * lds_scr[w2 * 512 + tid];
                    store_f32_sc(&attC[((size_t)ac * BB + ab) * UU + 512 + tid], s);
                }
            }
            // publish chunk results, then count arrivals (sc1 stores drained first)
            vm_drain();
            __syncthreads();
            if (tid == 0) {
                int old = __hip_atomic_fetch_add(cnt + ab, 1, __ATOMIC_RELAXED,
                                                 __HIP_MEMORY_SCOPE_AGENT);
                lds_flag[0] = ((old % NCHUNK) == (NCHUNK - 1)) ? 1 : 0;
            }
            __syncthreads();
            if (lds_flag[0]) {
                // Finisher (6th arriver): producers' sc1 stores are in L3;
                // read them with agent-coherent loads (local L2 may be stale).
                float mm[NCHUNK], ll[NCHUNK];
                #pragma unroll
                for (int c = 0; c < NCHUNK; ++c) {
                    mm[c] = load_f32_ag(&attML[((size_t)c * BB + ab) * 2]);
                    ll[c] = load_f32_ag(&attML[((size_t)c * BB + ab) * 2 + 1]);
                }
                float M2 = mm[0];
                #pragma unroll
                for (int c = 1; c < NCHUNK; ++c) M2 = fmaxf(M2, mm[c]);
                float den = 0.f, wc[NCHUNK];
                #pragma unroll
                for (int c = 0; c < NCHUNK; ++c) { wc[c] = expf(mm[c] - M2); den += wc[c] * ll[c]; }
                const float inv = 1.f / den;
                ushort* d = ppack + (size_t)(t & 3) * ASLOT;
                #pragma unroll
                for (int rep = 0; rep < 2; ++rep) {
                    const int e = tid + rep * 512;
                    float s3 = 0.f;
                    #pragma unroll
                    for (int c = 0; c < NCHUNK; ++c)
                        s3 += wc[c] * load_f32_ag(&attC[((size_t)c * BB + ab) * UU + e]);
                    const float xv = s3 * inv + inputs[((size_t)ab * TT + t) * UU + e];
                    ushort vh2, vl2; split2(xv, vh2, vl2);
                    const int ex2 = AEX(e, ab);
                    store_u16_sc(d + ex2, vh2);
                    store_u16_sc(d + APS + ex2, vl2);
                }
            }
        }
        ++ep;
        grid_barrier(bar, GRIDN * ep);
    }
}

extern "C" void kernel_launch(void* const* d_in, const int* in_sizes, int n_in,
                              void* d_out, int out_size, void* d_ws, size_t ws_size,
                              hipStream_t stream) {
    (void)in_sizes; (void)n_in; (void)out_size; (void)ws_size;
    const float* inputs = (const float*)d_in[0];
    const float* gW   = (const float*)d_in[1];
    const float* gWih = (const float*)d_in[2];
    const float* gWhh = (const float*)d_in[3];
    const float* gbih = (const float*)d_in[4];
    const float* gbhh = (const float*)d_in[5];
    const float* pWih = (const float*)d_in[6];
    const float* pWhh = (const float*)d_in[7];
    const float* pbih = (const float*)d_in[8];
    const float* pbhh = (const float*)d_in[9];
    const float* eWih = (const float*)d_in[10];
    const float* eWhh = (const float*)d_in[11];
    const float* ebih = (const float*)d_in[12];
    const float* ebhh = (const float*)d_in[13];
    float* out = (float*)d_out;

    char* ws = (char*)d_ws;
    size_t off = 0;
    auto alloc = [&](size_t bytes) {
        void* p = ws + off;
        off += (bytes + 255) & ~(size_t)255;
        return p;
    };
    ushort* wpack = (ushort*)alloc((size_t)3 * WCELL * 2);
    ushort* gpack = (ushort*)alloc((size_t)4 * ASLOT * 2);
    ushort* ppack = (ushort*)alloc((size_t)4 * ASLOT * 2);
    ushort* epack = (ushort*)alloc((size_t)4 * ASLOT * 2);
    float* hist  = (float*)alloc((size_t)(TT + 1) * BB * UU * 4);
    float* qall  = (float*)alloc((size_t)TT * BB * UU * 4);
    float* Pf    = (float*)alloc((size_t)4 * BB * UU * 4);
    float* biasp = (float*)alloc((size_t)3 * 4096 * 4);
    float* attC  = (float*)alloc((size_t)NCHUNK * BB * UU * 4);
    float* attML = (float*)alloc((size_t)NCHUNK * BB * 2 * 4);
    int*   cnt   = (int*)alloc(32 * 4);
    int*   bar   = (int*)alloc(4);

    packw_kernel<<<12288, 256, 0, stream>>>(gWih, gWhh, wpack);
    packw_kernel<<<12288, 256, 0, stream>>>(pWih, pWhh, wpack + WCELL);
    packw_kernel<<<12288, 256, 0, stream>>>(eWih, eWhh, wpack + 2 * (size_t)WCELL);
    qall_kernel<<<dim3(256, 32), 256, 0, stream>>>(inputs, gW, qall);
    init_kernel<<<176, 256, 0, stream>>>(inputs, gbih, gbhh, pbih, pbhh, ebih, ebhh,
                                         hist, Pf, gpack, ppack, epack, biasp, cnt, bar);

    hipFuncSetAttribute((const void*)persist_kernel,
                        hipFuncAttributeMaxDynamicSharedMemorySize, LDSB);
    void* args[] = {(void*)&inputs, (void*)&wpack, (void*)&biasp,
                    (void*)&gpack, (void*)&ppack, (void*)&epack,
                    (void*)&hist, (void*)&Pf, (void*)&qall, (void*)&out,
                    (void*)&attC, (void*)&attML, (void*)&cnt, (void*)&bar};
    hipError_t ce = hipLaunchCooperativeKernel((const void*)persist_kernel,
                                               dim3(GRIDN), dim3(512), args,
                                               (unsigned)LDSB, stream);
    if (ce != hipSuccess) {
        (void)hipGetLastError();
        // 192 blocks at 1 block/CU on a 256-CU part are co-resident; the
        // monotone-counter barrier is safe under a plain launch too.
        persist_kernel<<<GRIDN, 512, LDSB, stream>>>(inputs, wpack, biasp,
                                                     gpack, ppack, epack,
                                                     hist, Pf, qall, out,
                                                     attC, attML, cnt, bar);
    }
}

// Round 10
// 5764.317 us; speedup vs baseline: 3.5241x; 1.0290x over previous
//
#include <hip/hip_runtime.h>
#include <math.h>

// Problem constants: U=H=1024, B=32, T=256.
#define UU 1024
#define BB 32
#define TT 256
#define NCHUNK 6
#define GRIDN 192
#define RING 8         // act/Pf ring depth; must exceed inv period (7)

// Weight pack geometry (ushort elems). Per cell: [2 planes][sections r,z,nx,nh]
#define WPS   6291456u
#define WCELL (2u * WPS)
#define SR  0u
#define SZ  2097152u
#define SNX 4194304u
#define SNH 5242880u
// Act pack: per slot [2 planes][64 ks][4 hi][32 b][8 e]; x-half [0,32768), h-half +32768
#define APS   65536u
#define ASLOT (2u * APS)
#define AEX(u, b) ((((((u) >> 5) * 4 + (((u) >> 3) & 3)) * 32 + (b)) * 8) + ((u) & 7))

// Dynamic LDS layout (bytes): [0,128K) r/z lo-plane weights; then scratch.
#define SCR_OFF  131072   // 16 KB scratch (combine dumps / att ctx reduce)
#define GM_OFF   147456   // 8 KB gate matrix [4 gates][2 bt][64 lane][4]
#define RED_OFF  155648   // 16 f32
#define FLAG_OFF 155712
#define LDSB     155776

typedef __attribute__((ext_vector_type(8))) short bf16x8;
typedef __attribute__((ext_vector_type(4))) float f32x4;
#define MF(a, b, c) __builtin_amdgcn_mfma_f32_16x16x32_bf16((a), (b), (c), 0, 0, 0)

__device__ __forceinline__ ushort bf16rne(float v) {
    uint x = __float_as_uint(v);
    uint r = (x + 0x7fffu + ((x >> 16) & 1u)) >> 16;
    return (ushort)r;
}
__device__ __forceinline__ float ubf2f(ushort u) {
    return __uint_as_float(((uint)u) << 16);
}
__device__ __forceinline__ void split2(float v, ushort& h, ushort& l) {
    h = bf16rne(v);
    l = bf16rne(v - ubf2f(h));
}
// Agent-scope write-through stores (reach L3 directly; no wbl2 needed).
__device__ __forceinline__ void store_f32_sc(float* p, float v) {
    asm volatile("global_store_dword %0, %1, off sc1" :: "v"(p), "v"(v) : "memory");
}
__device__ __forceinline__ void store_u16_sc(ushort* p, ushort v) {
    uint vv = v;
    asm volatile("global_store_short %0, %1, off sc1" :: "v"(p), "v"(vv) : "memory");
}
__device__ __forceinline__ void vm_drain() {
    asm volatile("s_waitcnt vmcnt(0)" ::: "memory");
}
// Agent-coherent load for 1-stage-lifetime buffers (attC/attML only).
__device__ __forceinline__ float load_f32_ag(const float* p) {
    return __hip_atomic_load(p, __ATOMIC_RELAXED, __HIP_MEMORY_SCOPE_AGENT);
}

// ---------------------------------------------------------------------------
// Weight pack (unchanged, proven).
// ---------------------------------------------------------------------------
__global__ void packw_kernel(const float* __restrict__ Wih,
                             const float* __restrict__ Whh,
                             ushort* __restrict__ wp) {
    int tile = blockIdx.x;
    int sec, jt, ks, nks;
    size_t soff;
    if (tile < 8192) {
        sec = tile >> 12; int l = tile & 4095; jt = l >> 6; ks = l & 63; nks = 64;
        soff = sec ? SZ : SR;
    } else {
        int l2 = tile - 8192; sec = 2 + (l2 >> 11); int l = l2 & 2047; jt = l >> 5; ks = l & 31; nks = 32;
        soff = (sec == 2) ? SNX : SNH;
    }
    int p = threadIdx.x;
    int e0 = (p & 3) * 2, ul = (p >> 2) & 15, hi = p >> 6;
    int u = jt * 16 + ul;
    int kk = ks * 32 + hi * 8 + e0;
    float2 w;
    if (sec < 2) {
        int row = (sec ? 1024 : 0) + u;
        if (kk < 1024) w = *(const float2*)&Wih[(size_t)row * UU + kk];
        else           w = *(const float2*)&Whh[(size_t)row * UU + kk - 1024];
    } else if (sec == 2) {
        w = *(const float2*)&Wih[(size_t)(2048 + u) * UU + kk];
    } else {
        w = *(const float2*)&Whh[(size_t)(2048 + u) * UU + kk];
    }
    ushort h0, l0, h1, l1;
    split2(w.x, h0, l0); split2(w.y, h1, l1);
    size_t ob = soff + ((((size_t)jt * nks + ks) * 4 + hi) * 16 + ul) * 8 + e0;
    *(uint*)(wp + ob)       = (uint)h0 | ((uint)h1 << 16);
    *(uint*)(wp + WPS + ob) = (uint)l0 | ((uint)l1 << 16);
}

// ---------------------------------------------------------------------------
// q_all[t][b][u] = sum_k inputs[b][t][k] * global_W[k][u]  (fp32)
// ---------------------------------------------------------------------------
__global__ void qall_kernel(const float* __restrict__ x,
                            const float* __restrict__ gW,
                            float* __restrict__ q) {
    __shared__ float xs[32][65];
    int r0 = blockIdx.x * 32, u0 = blockIdx.y * 32;
    int tid = threadIdx.x;
    int rr = tid >> 3, ju = tid & 7;
    float4 acc = {0.f, 0.f, 0.f, 0.f};
    for (int k0 = 0; k0 < UU; k0 += 64) {
        for (int e = tid; e < 32 * 64; e += 256) {
            int lr = e >> 6, lk = e & 63;
            int r = r0 + lr;
            int tt = r >> 5, bb = r & 31;
            xs[lr][lk] = x[((size_t)bb * TT + tt) * UU + k0 + lk];
        }
        __syncthreads();
        #pragma unroll 4
        for (int kk = 0; kk < 64; ++kk) {
            float4 gv = *(const float4*)&gW[(size_t)(k0 + kk) * UU + u0 + ju * 4];
            float xv = xs[rr][kk];
            acc.x += xv * gv.x; acc.y += xv * gv.y;
            acc.z += xv * gv.z; acc.w += xv * gv.w;
        }
        __syncthreads();
    }
    *(float4*)&q[(size_t)(r0 + rr) * UU + u0 + ju * 4] = acc;
}

// ---------------------------------------------------------------------------
// Init (ring-of-8 variant; zeroes slots 0/1 which t=0/1 consume).
// ---------------------------------------------------------------------------
__global__ void init_kernel(const float* __restrict__ inputs,
                            const float* __restrict__ gbih, const float* __restrict__ gbhh,
                            const float* __restrict__ pbih, const float* __restrict__ pbhh,
                            const float* __restrict__ ebih, const float* __restrict__ ebhh,
                            float* __restrict__ hist, float* __restrict__ Pf,
                            ushort* __restrict__ gpack, ushort* __restrict__ ppack,
                            ushort* __restrict__ epack, float* __restrict__ biasp,
                            int* __restrict__ cnt, int* __restrict__ bar) {
    if (blockIdx.x == 0 && threadIdx.x < 33) {
        if (threadIdx.x < 32) cnt[threadIdx.x] = 0;
        else bar[0] = 0;
    }
    if (blockIdx.x < 128) {
        int i = blockIdx.x * 256 + threadIdx.x;
        int b = i >> 10, u = i & 1023;
        hist[i] = 0.f;
        Pf[i] = 0.f; Pf[32768 + i] = 0.f;   // Pf slots 0 (t=0) and 1 (t=1)
        int ex = AEX(u, b);
        int eh = ex + 32768;
        gpack[eh] = 0; gpack[APS + eh] = 0;
        ppack[eh] = 0; ppack[APS + eh] = 0;
        ppack[ASLOT + eh] = 0; ppack[ASLOT + APS + eh] = 0;
        epack[eh] = 0; epack[APS + eh] = 0;
        float x0 = inputs[((size_t)b * TT + 0) * UU + u];
        float x1 = inputs[((size_t)b * TT + 1) * UU + u];
        ushort h, l;
        split2(x0, h, l); gpack[ex] = h; gpack[APS + ex] = l;
        split2(x1, h, l); gpack[ASLOT + ex] = h; gpack[ASLOT + APS + ex] = l;
    } else {
        int idx = (blockIdx.x - 128) * 256 + threadIdx.x;
        int cell = idx >> 12, g4 = (idx >> 10) & 3, u = idx & 1023;
        const float* bih = (cell == 0) ? gbih : (cell == 1) ? pbih : ebih;
        const float* bhh = (cell == 0) ? gbhh : (cell == 1) ? pbhh : ebhh;
        float v;
        if (g4 == 0) v = bih[u] + bhh[u];
        else if (g4 == 1) v = bih[1024 + u] + bhh[1024 + u];
        else if (g4 == 2) v = bih[2048 + u];
        else v = bhh[2048 + u];
        biasp[idx] = v;
    }
}

// ---------------------------------------------------------------------------
// Grid barrier: drain sc1 stores, relaxed add, relaxed polls.
// Acquire-inv only when doInv (every 7th stage): ring-of-8 addresses are
// guaranteed invalidated between epochs (any 8-stage window holds one inv),
// so the hot loop may use normal CACHED loads on ring data.
// ---------------------------------------------------------------------------
__device__ __forceinline__ void grid_barrier(int* bar, int target, bool doInv) {
    vm_drain();
    __syncthreads();
    if (threadIdx.x == 0) {
        __hip_atomic_fetch_add(bar, 1, __ATOMIC_RELAXED, __HIP_MEMORY_SCOPE_AGENT);
        while (__hip_atomic_load(bar, __ATOMIC_RELAXED, __HIP_MEMORY_SCOPE_AGENT) < target) {
            __builtin_amdgcn_s_sleep(8);
        }
        if (doInv)
            (void)__hip_atomic_load(bar, __ATOMIC_ACQUIRE, __HIP_MEMORY_SCOPE_AGENT);
    }
    __syncthreads();
}

// ---------------------------------------------------------------------------
// Persistent kernel: 192 blocks x 512 threads (8 waves), 1 block/CU.
// Cache policy: hist/out/qall/inputs/biasp = cached (write-once / RO).
// Act rings + Pf = cached, made safe by RING=8 + inv-every-7.
// attC/attML (1-stage lifetime) = agent-coherent loads.
// ---------------------------------------------------------------------------
__global__ __launch_bounds__(512)
__attribute__((amdgpu_waves_per_eu(2)))
void persist_kernel(const float* __restrict__ inputs,
                    const ushort* __restrict__ wpack,
                    const float* __restrict__ biasp,
                    ushort* __restrict__ gpack, ushort* __restrict__ ppack,
                    ushort* __restrict__ epack,
                    float* __restrict__ hist, float* __restrict__ Pf,
                    const float* __restrict__ qall,
                    float* __restrict__ out,
                    float* __restrict__ attC, float* __restrict__ attML,
                    int* __restrict__ cnt, int* __restrict__ bar) {
    extern __shared__ char smraw[];
    float* lds_scr  = (float*)(smraw + SCR_OFF);
    float* lds_gm   = (float*)(smraw + GM_OFF);
    float* lds_red  = (float*)(smraw + RED_OFF);
    int*   lds_flag = (int*)(smraw + FLAG_OFF);

    const int blk = blockIdx.x, tid = threadIdx.x;
    const int cell = blk >> 6, jt = blk & 63;
    const int w = tid >> 6, lane = tid & 63;
    const int l15 = lane & 15, hi4 = lane >> 4;
    const int ab = blk & 31, ac = blk >> 5;
    const ushort* wp = wpack + (size_t)cell * WCELL;

    // ---- persistent weights ----
    bf16x8 whiR[8], whiZ[8], whiN[8], wloN[8];
    #pragma unroll
    for (int i = 0; i < 8; ++i) {
        const int ks = w * 8 + i;
        const size_t aoff = ((size_t)(jt * 256 + ks * 4 + hi4)) * 128 + (size_t)l15 * 8;
        whiR[i] = *(const bf16x8*)(wp + SR + aoff);
        whiZ[i] = *(const bf16x8*)(wp + SZ + aoff);
        bf16x8 rlo = *(const bf16x8*)(wp + SR + WPS + aoff);
        bf16x8 zlo = *(const bf16x8*)(wp + SZ + WPS + aoff);
        *(bf16x8*)(smraw + (((w * 16 + i) * 64 + lane) << 4)) = rlo;
        *(bf16x8*)(smraw + (((w * 16 + 8 + i) * 64 + lane) << 4)) = zlo;
        const int ksn = (w & 3) * 8 + i;
        const size_t noff = ((size_t)(jt * 128 + ksn * 4 + hi4)) * 128 + (size_t)l15 * 8;
        const size_t sN = (w < 4) ? SNX : SNH;
        whiN[i] = *(const bf16x8*)(wp + sN + noff);
        wloN[i] = *(const bf16x8*)(wp + sN + WPS + noff);
    }
    // ---- epilogue constants (1 output/thread) ----
    const int ebt = tid >> 8, eli = (tid >> 2) & 63, ei = tid & 3;
    const int eb = ebt * 16 + (eli & 15);
    const int eu = jt * 16 + (eli >> 4) * 4 + ei;
    const int eex = AEX(eu, eb);
    const float* bc = biasp + cell * 4096;
    const float bR = bc[eu], bZ = bc[1024 + eu];
    const float bNI = bc[2048 + eu], bNH = bc[3072 + eu];
    __syncthreads();

    int ep = 0;
    for (int t = 0; t <= TT + 1; ++t) {
        const int tc = t - cell;
        const bool gemmWork = (tc >= 0 && tc < TT);
        if (gemmWork) {
            f32x4 aR0 = {0,0,0,0}, aR1 = {0,0,0,0};
            f32x4 aZ0 = {0,0,0,0}, aZ1 = {0,0,0,0};
            f32x4 aN0 = {0,0,0,0}, aN1 = {0,0,0,0};
            ushort* apk = (cell == 0) ? gpack : (cell == 1) ? ppack : epack;
            const ushort* ap = apk + (size_t)(tc & (RING - 1)) * ASLOT;
            const ushort* bbp = ap + ((size_t)hi4 * 32 + l15) * 8;
            #pragma unroll
            for (int i = 0; i < 8; ++i) {
                const int ks = w * 8 + i;
                const ushort* bp = bbp + (size_t)ks * 1024;
                bf16x8 bh0 = *(const bf16x8*)(bp);
                bf16x8 bh1 = *(const bf16x8*)(bp + 128);
                bf16x8 bl0 = *(const bf16x8*)(bp + APS);
                bf16x8 bl1 = *(const bf16x8*)(bp + APS + 128);
                bf16x8 rlo = *(const bf16x8*)(smraw + (((w * 16 + i) * 64 + lane) << 4));
                bf16x8 zlo = *(const bf16x8*)(smraw + (((w * 16 + 8 + i) * 64 + lane) << 4));
                aR0 = MF(whiR[i], bh0, aR0); aR0 = MF(whiR[i], bl0, aR0); aR0 = MF(rlo, bh0, aR0);
                aR1 = MF(whiR[i], bh1, aR1); aR1 = MF(whiR[i], bl1, aR1); aR1 = MF(rlo, bh1, aR1);
                aZ0 = MF(whiZ[i], bh0, aZ0); aZ0 = MF(whiZ[i], bl0, aZ0); aZ0 = MF(zlo, bh0, aZ0);
                aZ1 = MF(whiZ[i], bh1, aZ1); aZ1 = MF(whiZ[i], bl1, aZ1); aZ1 = MF(zlo, bh1, aZ1);
                aN0 = MF(whiN[i], bh0, aN0); aN0 = MF(whiN[i], bl0, aN0); aN0 = MF(wloN[i], bh0, aN0);
                aN1 = MF(whiN[i], bh1, aN1); aN1 = MF(whiN[i], bl1, aN1); aN1 = MF(wloN[i], bh1, aN1);
            }
            // ---- combine: R -> gm0, Z -> gm1, N -> gm2 (iN, waves 0-3) / gm3 (hN, 4-7)
            const int cbt = tid >> 8, cln = (tid >> 2) & 63, cc = tid & 3;
            __syncthreads();
            *(f32x4*)&lds_scr[((0 * 8 + w) * 64 + lane) * 4] = aR0;
            *(f32x4*)&lds_scr[((1 * 8 + w) * 64 + lane) * 4] = aR1;
            __syncthreads();
            {
                float s = 0.f;
                #pragma unroll
                for (int w2 = 0; w2 < 8; ++w2) s += lds_scr[((cbt * 8 + w2) * 64 + cln) * 4 + cc];
                lds_gm[((0 * 2 + cbt) * 64 + cln) * 4 + cc] = s;
            }
            __syncthreads();
            *(f32x4*)&lds_scr[((0 * 8 + w) * 64 + lane) * 4] = aZ0;
            *(f32x4*)&lds_scr[((1 * 8 + w) * 64 + lane) * 4] = aZ1;
            __syncthreads();
            {
                float s = 0.f;
                #pragma unroll
                for (int w2 = 0; w2 < 8; ++w2) s += lds_scr[((cbt * 8 + w2) * 64 + cln) * 4 + cc];
                lds_gm[((1 * 2 + cbt) * 64 + cln) * 4 + cc] = s;
            }
            __syncthreads();
            *(f32x4*)&lds_scr[((0 * 8 + w) * 64 + lane) * 4] = aN0;
            *(f32x4*)&lds_scr[((1 * 8 + w) * 64 + lane) * 4] = aN1;
            __syncthreads();
            {
                float iN = 0.f, hN = 0.f;
                #pragma unroll
                for (int w2 = 0; w2 < 4; ++w2) iN += lds_scr[((cbt * 8 + w2) * 64 + cln) * 4 + cc];
                #pragma unroll
                for (int w2 = 4; w2 < 8; ++w2) hN += lds_scr[((cbt * 8 + w2) * 64 + cln) * 4 + cc];
                lds_gm[((2 * 2 + cbt) * 64 + cln) * 4 + cc] = iN;
                lds_gm[((3 * 2 + cbt) * 64 + cln) * 4 + cc] = hN;
            }
            __syncthreads();
            // ---- epilogue (1 output/thread), all cross-block stores sc1 ----
            {
                const float R  = lds_gm[((0 * 2 + ebt) * 64 + eli) * 4 + ei];
                const float Z  = lds_gm[((1 * 2 + ebt) * 64 + eli) * 4 + ei];
                const float iN = lds_gm[((2 * 2 + ebt) * 64 + eli) * 4 + ei];
                const float hN = lds_gm[((3 * 2 + ebt) * 64 + eli) * 4 + ei];
                float hprev;
                if (cell == 0)      hprev = hist[((size_t)tc * BB + eb) * UU + eu];
                else if (cell == 1) hprev = Pf[(size_t)(tc & (RING - 1)) * BB * UU + (size_t)eb * UU + eu];
                else                hprev = (tc > 0) ? out[((size_t)eb * TT + tc - 1) * UU + eu] : 0.f;
                const float r = 1.f / (1.f + expf(-(R + bR)));
                const float z = 1.f / (1.f + expf(-(Z + bZ)));
                const float n2 = tanhf(iN + bNI + r * (hN + bNH));
                const float val = (1.f - z) * n2 + z * hprev;
                ushort vh, vl; split2(val, vh, vl);
                if (cell == 0) {
                    store_f32_sc(&hist[((size_t)(tc + 1) * BB + eb) * UU + eu], val);
                    ushort* d = gpack + (size_t)((tc + 1) & (RING - 1)) * ASLOT;
                    store_u16_sc(d + eex + 32768, vh);
                    store_u16_sc(d + APS + eex + 32768, vl);
                } else if (cell == 1) {
                    ushort* d = epack + (size_t)(tc & (RING - 1)) * ASLOT;
                    store_u16_sc(d + eex, vh);
                    store_u16_sc(d + APS + eex, vl);
                    if (tc + 2 < TT) {
                        store_f32_sc(&Pf[(size_t)((tc + 2) & (RING - 1)) * BB * UU + (size_t)eb * UU + eu], val);
                        ushort* d2 = ppack + (size_t)((tc + 2) & (RING - 1)) * ASLOT;
                        store_u16_sc(d2 + eex + 32768, vh);
                        store_u16_sc(d2 + APS + eex + 32768, vl);
                        const float gx = val + inputs[((size_t)eb * TT + tc + 2) * UU + eu];
                        ushort gh, gl; split2(gx, gh, gl);
                        ushort* d3 = gpack + (size_t)((tc + 2) & (RING - 1)) * ASLOT;
                        store_u16_sc(d3 + eex, gh);
                        store_u16_sc(d3 + APS + eex, gl);
                    }
                } else {
                    store_f32_sc(&out[((size_t)eb * TT + tc) * UU + eu], val);
                    if (tc + 1 < TT) {
                        ushort* d = epack + (size_t)((tc + 1) & (RING - 1)) * ASLOT;
                        store_u16_sc(d + eex + 32768, vh);
                        store_u16_sc(d + APS + eex + 32768, vl);
                    }
                }
            }
        }
        // ---- attention chunk (ac, ab): single-pass online softmax, 8 waves ----
        if (t < TT) {
            const int nt2 = t + 1;
            const int cstr = (nt2 + NCHUNK - 1) / NCHUNK;
            const int r0 = ac * cstr;
            const int r1x = r0 + cstr;
            const int r1 = (r1x < nt2) ? r1x : nt2;
            const int n = r1 - r0;
            if (n <= 0) {
                #pragma unroll
                for (int rep = 0; rep < 2; ++rep)
                    store_f32_sc(&attC[((size_t)ac * BB + ab) * UU + tid + rep * 512], 0.f);
                if (tid == 0) {
                    store_f32_sc(&attML[((size_t)ac * BB + ab) * 2], -INFINITY);
                    store_f32_sc(&attML[((size_t)ac * BB + ab) * 2 + 1], 0.f);
                }
            } else {
                const float* qb = qall + ((size_t)t * BB + ab) * UU;
                float4 q0 = *(const float4*)&qb[lane * 4];
                float4 q1 = *(const float4*)&qb[256 + lane * 4];
                float4 q2 = *(const float4*)&qb[512 + lane * 4];
                float4 q3 = *(const float4*)&qb[768 + lane * 4];
                float m_run = -INFINITY, l_run = 0.f;
                float4 c0 = {0,0,0,0}, c1 = {0,0,0,0}, c2 = {0,0,0,0}, c3 = {0,0,0,0};
                for (int tp = r0 + w; tp < r1; tp += 8) {
                    const float* hr = hist + ((size_t)tp * BB + ab) * UU;
                    float4 h0 = *(const float4*)&hr[lane * 4];
                    float4 h1 = *(const float4*)&hr[256 + lane * 4];
                    float4 h2 = *(const float4*)&hr[512 + lane * 4];
                    float4 h3 = *(const float4*)&hr[768 + lane * 4];
                    float s = h0.x*q0.x + h0.y*q0.y + h0.z*q0.z + h0.w*q0.w
                            + h1.x*q1.x + h1.y*q1.y + h1.z*q1.z + h1.w*q1.w
                            + h2.x*q2.x + h2.y*q2.y + h2.z*q2.z + h2.w*q2.w
                            + h3.x*q3.x + h3.y*q3.y + h3.z*q3.z + h3.w*q3.w;
                    #pragma unroll
                    for (int off = 32; off; off >>= 1) s += __shfl_xor(s, off);
                    const float mn = fmaxf(m_run, s);
                    const float sc = expf(m_run - mn);
                    const float e2 = expf(s - mn);
                    c0.x = c0.x*sc + e2*h0.x; c0.y = c0.y*sc + e2*h0.y; c0.z = c0.z*sc + e2*h0.z; c0.w = c0.w*sc + e2*h0.w;
                    c1.x = c1.x*sc + e2*h1.x; c1.y = c1.y*sc + e2*h1.y; c1.z = c1.z*sc + e2*h1.z; c1.w = c1.w*sc + e2*h1.w;
                    c2.x = c2.x*sc + e2*h2.x; c2.y = c2.y*sc + e2*h2.y; c2.z = c2.z*sc + e2*h2.z; c2.w = c2.w*sc + e2*h2.w;
                    c3.x = c3.x*sc + e2*h3.x; c3.y = c3.y*sc + e2*h3.y; c3.z = c3.z*sc + e2*h3.z; c3.w = c3.w*sc + e2*h3.w;
                    l_run = l_run * sc + e2;
                    m_run = mn;
                }
                // pass 0: elems [0,512) via c0,c1; per-wave m/l publish
                *(float4*)&lds_scr[w * 512 + lane * 4] = c0;
                *(float4*)&lds_scr[w * 512 + 256 + lane * 4] = c1;
                if (lane == 0) { lds_red[w] = m_run; lds_red[8 + w] = l_run; }
                __syncthreads();
                float M = lds_red[0];
                #pragma unroll
                for (int k = 1; k < 8; ++k) M = fmaxf(M, lds_red[k]);
                float ww[8], L = 0.f;
                #pragma unroll
                for (int k = 0; k < 8; ++k) { ww[k] = expf(lds_red[k] - M); L += ww[k] * lds_red[8 + k]; }
                if (tid == 0) {
                    store_f32_sc(&attML[((size_t)ac * BB + ab) * 2], M);
                    store_f32_sc(&attML[((size_t)ac * BB + ab) * 2 + 1], L);
                }
                {
                    float s = 0.f;
                    #pragma unroll
                    for (int w2 = 0; w2 < 8; ++w2) s += ww[w2] * lds_scr[w2 * 512 + tid];
                    store_f32_sc(&attC[((size_t)ac * BB + ab) * UU + tid], s);
                }
                __syncthreads();
                // pass 1: elems [512,1024) via c2,c3
                *(float4*)&lds_scr[w * 512 + lane * 4] = c2;
                *(float4*)&lds_scr[w * 512 + 256 + lane * 4] = c3;
                __syncthreads();
                {
                    float s = 0.f;
                    #pragma unroll
                    for (int w2 = 0; w2 < 8; ++w2) s += ww[w2] * lds_scr[w2 * 512 + tid];
                    store_f32_sc(&attC[((size_t)ac * BB + ab) * UU + 512 + tid], s);
                }
            }
            // publish chunk results, then count arrivals (sc1 stores drained first)
            vm_drain();
            __syncthreads();
            if (tid == 0) {
                int old = __hip_atomic_fetch_add(cnt + ab, 1, __ATOMIC_RELAXED,
                                                 __HIP_MEMORY_SCOPE_AGENT);
                lds_flag[0] = ((old % NCHUNK) == (NCHUNK - 1)) ? 1 : 0;
            }
            __syncthreads();
            if (lds_flag[0]) {
                // Finisher (6th arriver): producers' sc1 stores are in L3;
                // attC/attML have 1-stage lifetime -> agent-coherent loads.
                float mm[NCHUNK], ll[NCHUNK];
                #pragma unroll
                for (int c = 0; c < NCHUNK; ++c) {
                    mm[c] = load_f32_ag(&attML[((size_t)c * BB + ab) * 2]);
                    ll[c] = load_f32_ag(&attML[((size_t)c * BB + ab) * 2 + 1]);
                }
                float M2 = mm[0];
                #pragma unroll
                for (int c = 1; c < NCHUNK; ++c) M2 = fmaxf(M2, mm[c]);
                float den = 0.f, wc[NCHUNK];
                #pragma unroll
                for (int c = 0; c < NCHUNK; ++c) { wc[c] = expf(mm[c] - M2); den += wc[c] * ll[c]; }
                const float inv = 1.f / den;
                ushort* d = ppack + (size_t)(t & (RING - 1)) * ASLOT;
                #pragma unroll
                for (int rep = 0; rep < 2; ++rep) {
                    const int e = tid + rep * 512;
                    float s3 = 0.f;
                    #pragma unroll
                    for (int c = 0; c < NCHUNK; ++c)
                        s3 += wc[c] * load_f32_ag(&attC[((size_t)c * BB + ab) * UU + e]);
                    const float xv = s3 * inv + inputs[((size_t)ab * TT + t) * UU + e];
                    ushort vh2, vl2; split2(xv, vh2, vl2);
                    const int ex2 = AEX(e, ab);
                    store_u16_sc(d + ex2, vh2);
                    store_u16_sc(d + APS + ex2, vl2);
                }
            }
        }
        ++ep;
        grid_barrier(bar, GRIDN * ep, (ep % 7) == 0);
    }
}

extern "C" void kernel_launch(void* const* d_in, const int* in_sizes, int n_in,
                              void* d_out, int out_size, void* d_ws, size_t ws_size,
                              hipStream_t stream) {
    (void)in_sizes; (void)n_in; (void)out_size; (void)ws_size;
    const float* inputs = (const float*)d_in[0];
    const float* gW   = (const float*)d_in[1];
    const float* gWih = (const float*)d_in[2];
    const float* gWhh = (const float*)d_in[3];
    const float* gbih = (const float*)d_in[4];
    const float* gbhh = (const float*)d_in[5];
    const float* pWih = (const float*)d_in[6];
    const float* pWhh = (const float*)d_in[7];
    const float* pbih = (const float*)d_in[8];
    const float* pbhh = (const float*)d_in[9];
    const float* eWih = (const float*)d_in[10];
    const float* eWhh = (const float*)d_in[11];
    const float* ebih = (const float*)d_in[12];
    const float* ebhh = (const float*)d_in[13];
    float* out = (float*)d_out;

    char* ws = (char*)d_ws;
    size_t off = 0;
    auto alloc = [&](size_t bytes) {
        void* p = ws + off;
        off += (bytes + 255) & ~(size_t)255;
        return p;
    };
    ushort* wpack = (ushort*)alloc((size_t)3 * WCELL * 2);
    ushort* gpack = (ushort*)alloc((size_t)RING * ASLOT * 2);
    ushort* ppack = (ushort*)alloc((size_t)RING * ASLOT * 2);
    ushort* epack = (ushort*)alloc((size_t)RING * ASLOT * 2);
    float* hist  = (float*)alloc((size_t)(TT + 1) * BB * UU * 4);
    float* qall  = (float*)alloc((size_t)TT * BB * UU * 4);
    float* Pf    = (float*)alloc((size_t)RING * BB * UU * 4);
    float* biasp = (float*)alloc((size_t)3 * 4096 * 4);
    float* attC  = (float*)alloc((size_t)NCHUNK * BB * UU * 4);
    float* attML = (float*)alloc((size_t)NCHUNK * BB * 2 * 4);
    int*   cnt   = (int*)alloc(32 * 4);
    int*   bar   = (int*)alloc(4);

    packw_kernel<<<12288, 256, 0, stream>>>(gWih, gWhh, wpack);
    packw_kernel<<<12288, 256, 0, stream>>>(pWih, pWhh, wpack + WCELL);
    packw_kernel<<<12288, 256, 0, stream>>>(eWih, eWhh, wpack + 2 * (size_t)WCELL);
    qall_kernel<<<dim3(256, 32), 256, 0, stream>>>(inputs, gW, qall);
    init_kernel<<<176, 256, 0, stream>>>(inputs, gbih, gbhh, pbih, pbhh, ebih, ebhh,
                                         hist, Pf, gpack, ppack, epack, biasp, cnt, bar);

    hipFuncSetAttribute((const void*)persist_kernel,
                        hipFuncAttributeMaxDynamicSharedMemorySize, LDSB);
    void* args[] = {(void*)&inputs, (void*)&wpack, (void*)&biasp,
                    (void*)&gpack, (void*)&ppack, (void*)&epack,
                    (void*)&hist, (void*)&Pf, (void*)&qall, (void*)&out,
                    (void*)&attC, (void*)&attML, (void*)&cnt, (void*)&bar};
    hipError_t ce = hipLaunchCooperativeKernel((const void*)persist_kernel,
                                               dim3(GRIDN), dim3(512), args,
                                               (unsigned)LDSB, stream);
    if (ce != hipSuccess) {
        (void)hipGetLastError();
        // 192 blocks at 1 block/CU on a 256-CU part are co-resident; the
        // monotone-counter barrier is safe under a plain launch too.
        persist_kernel<<<GRIDN, 512, LDSB, stream>>>(inputs, wpack, biasp,
                                                     gpack, ppack, epack,
                                                     hist, Pf, qall, out,
                                                     attC, attML, cnt, bar);
    }
}

// Round 11
// 3799.371 us; speedup vs baseline: 5.3467x; 1.5172x over previous
//
#include <hip/hip_runtime.h>
#include <math.h>

// Problem constants: U=H=1024, B=32, T=256.
#define UU 1024
#define BB 32
#define TT 256
#define NCHUNK 2       // attention chunks per batch (64 dedicated att blocks)
#define GRIDN 256      // 192 GEMM + 64 attention blocks, 1 per CU
#define RING 32        // act/Pf ring depth; inv period 31 < RING

// Weight pack geometry (ushort elems). Per cell: [2 planes][sections r,z,nx,nh]
#define WPS   6291456u
#define WCELL (2u * WPS)
#define SR  0u
#define SZ  2097152u
#define SNX 4194304u
#define SNH 5242880u
// Act pack: per slot [2 planes][64 ks][4 hi][32 b][8 e]; x-half [0,32768), h-half +32768
#define APS   65536u
#define ASLOT (2u * APS)
#define AEX(u, b) ((((((u) >> 5) * 4 + (((u) >> 3) & 3)) * 32 + (b)) * 8) + ((u) & 7))

// Dynamic LDS layout (bytes): [0,128K) r/z lo-plane weights; then scratch.
#define SCR_OFF  131072   // 16 KB scratch (combine dumps / att ctx reduce)
#define GM_OFF   147456   // 8 KB gate matrix [4 gates][2 bt][64 lane][4]
#define RED_OFF  155648   // 16 f32
#define FLAG_OFF 155712
#define LDSB     155776

typedef __attribute__((ext_vector_type(8))) short bf16x8;
typedef __attribute__((ext_vector_type(4))) float f32x4;
#define MF(a, b, c) __builtin_amdgcn_mfma_f32_16x16x32_bf16((a), (b), (c), 0, 0, 0)

__device__ __forceinline__ ushort bf16rne(float v) {
    uint x = __float_as_uint(v);
    uint r = (x + 0x7fffu + ((x >> 16) & 1u)) >> 16;
    return (ushort)r;
}
__device__ __forceinline__ float ubf2f(ushort u) {
    return __uint_as_float(((uint)u) << 16);
}
__device__ __forceinline__ void split2(float v, ushort& h, ushort& l) {
    h = bf16rne(v);
    l = bf16rne(v - ubf2f(h));
}
// Agent-scope write-through stores (reach L3 directly; no wbl2 needed).
__device__ __forceinline__ void store_f32_sc(float* p, float v) {
    asm volatile("global_store_dword %0, %1, off sc1" :: "v"(p), "v"(v) : "memory");
}
__device__ __forceinline__ void store_u16_sc(ushort* p, ushort v) {
    uint vv = v;
    asm volatile("global_store_short %0, %1, off sc1" :: "v"(p), "v"(vv) : "memory");
}
__device__ __forceinline__ void vm_drain() {
    asm volatile("s_waitcnt vmcnt(0)" ::: "memory");
}
// Agent-coherent load for 1-stage-lifetime buffers (attC/attML only).
__device__ __forceinline__ float load_f32_ag(const float* p) {
    return __hip_atomic_load(p, __ATOMIC_RELAXED, __HIP_MEMORY_SCOPE_AGENT);
}

// ---------------------------------------------------------------------------
// Weight pack (unchanged, proven).
// ---------------------------------------------------------------------------
__global__ void packw_kernel(const float* __restrict__ Wih,
                             const float* __restrict__ Whh,
                             ushort* __restrict__ wp) {
    int tile = blockIdx.x;
    int sec, jt, ks, nks;
    size_t soff;
    if (tile < 8192) {
        sec = tile >> 12; int l = tile & 4095; jt = l >> 6; ks = l & 63; nks = 64;
        soff = sec ? SZ : SR;
    } else {
        int l2 = tile - 8192; sec = 2 + (l2 >> 11); int l = l2 & 2047; jt = l >> 5; ks = l & 31; nks = 32;
        soff = (sec == 2) ? SNX : SNH;
    }
    int p = threadIdx.x;
    int e0 = (p & 3) * 2, ul = (p >> 2) & 15, hi = p >> 6;
    int u = jt * 16 + ul;
    int kk = ks * 32 + hi * 8 + e0;
    float2 w;
    if (sec < 2) {
        int row = (sec ? 1024 : 0) + u;
        if (kk < 1024) w = *(const float2*)&Wih[(size_t)row * UU + kk];
        else           w = *(const float2*)&Whh[(size_t)row * UU + kk - 1024];
    } else if (sec == 2) {
        w = *(const float2*)&Wih[(size_t)(2048 + u) * UU + kk];
    } else {
        w = *(const float2*)&Whh[(size_t)(2048 + u) * UU + kk];
    }
    ushort h0, l0, h1, l1;
    split2(w.x, h0, l0); split2(w.y, h1, l1);
    size_t ob = soff + ((((size_t)jt * nks + ks) * 4 + hi) * 16 + ul) * 8 + e0;
    *(uint*)(wp + ob)       = (uint)h0 | ((uint)h1 << 16);
    *(uint*)(wp + WPS + ob) = (uint)l0 | ((uint)l1 << 16);
}

// ---------------------------------------------------------------------------
// q_all[t][b][u] = sum_k inputs[b][t][k] * global_W[k][u]  (fp32)
// ---------------------------------------------------------------------------
__global__ void qall_kernel(const float* __restrict__ x,
                            const float* __restrict__ gW,
                            float* __restrict__ q) {
    __shared__ float xs[32][65];
    int r0 = blockIdx.x * 32, u0 = blockIdx.y * 32;
    int tid = threadIdx.x;
    int rr = tid >> 3, ju = tid & 7;
    float4 acc = {0.f, 0.f, 0.f, 0.f};
    for (int k0 = 0; k0 < UU; k0 += 64) {
        for (int e = tid; e < 32 * 64; e += 256) {
            int lr = e >> 6, lk = e & 63;
            int r = r0 + lr;
            int tt = r >> 5, bb = r & 31;
            xs[lr][lk] = x[((size_t)bb * TT + tt) * UU + k0 + lk];
        }
        __syncthreads();
        #pragma unroll 4
        for (int kk = 0; kk < 64; ++kk) {
            float4 gv = *(const float4*)&gW[(size_t)(k0 + kk) * UU + u0 + ju * 4];
            float xv = xs[rr][kk];
            acc.x += xv * gv.x; acc.y += xv * gv.y;
            acc.z += xv * gv.z; acc.w += xv * gv.w;
        }
        __syncthreads();
    }
    *(float4*)&q[(size_t)(r0 + rr) * UU + u0 + ju * 4] = acc;
}

// ---------------------------------------------------------------------------
// Init (ring-of-32; zeroes slots 0/1 which t=0/1 consume; bar + release).
// ---------------------------------------------------------------------------
__global__ void init_kernel(const float* __restrict__ inputs,
                            const float* __restrict__ gbih, const float* __restrict__ gbhh,
                            const float* __restrict__ pbih, const float* __restrict__ pbhh,
                            const float* __restrict__ ebih, const float* __restrict__ ebhh,
                            float* __restrict__ hist, float* __restrict__ Pf,
                            ushort* __restrict__ gpack, ushort* __restrict__ ppack,
                            ushort* __restrict__ epack, float* __restrict__ biasp,
                            int* __restrict__ cnt, int* __restrict__ bar) {
    if (blockIdx.x == 0 && threadIdx.x < 96) {
        if (threadIdx.x < 32) cnt[threadIdx.x] = 0;
        else bar[threadIdx.x - 32] = 0;   // bar[0..63]: counter @0, release @32
    }
    if (blockIdx.x < 128) {
        int i = blockIdx.x * 256 + threadIdx.x;
        int b = i >> 10, u = i & 1023;
        hist[i] = 0.f;
        Pf[i] = 0.f; Pf[32768 + i] = 0.f;   // Pf slots 0 (t=0) and 1 (t=1)
        int ex = AEX(u, b);
        int eh = ex + 32768;
        gpack[eh] = 0; gpack[APS + eh] = 0;
        ppack[eh] = 0; ppack[APS + eh] = 0;
        ppack[ASLOT + eh] = 0; ppack[ASLOT + APS + eh] = 0;
        epack[eh] = 0; epack[APS + eh] = 0;
        float x0 = inputs[((size_t)b * TT + 0) * UU + u];
        float x1 = inputs[((size_t)b * TT + 1) * UU + u];
        ushort h, l;
        split2(x0, h, l); gpack[ex] = h; gpack[APS + ex] = l;
        split2(x1, h, l); gpack[ASLOT + ex] = h; gpack[ASLOT + APS + ex] = l;
    } else {
        int idx = (blockIdx.x - 128) * 256 + threadIdx.x;
        int cell = idx >> 12, g4 = (idx >> 10) & 3, u = idx & 1023;
        const float* bih = (cell == 0) ? gbih : (cell == 1) ? pbih : ebih;
        const float* bhh = (cell == 0) ? gbhh : (cell == 1) ? pbhh : ebhh;
        float v;
        if (g4 == 0) v = bih[u] + bhh[u];
        else if (g4 == 1) v = bih[1024 + u] + bhh[1024 + u];
        else if (g4 == 2) v = bih[2048 + u];
        else v = bhh[2048 + u];
        biasp[idx] = v;
    }
}

// ---------------------------------------------------------------------------
// Grid barrier, split-line: counter @bar[0], release @bar[32] (separate line).
// Last arriver (fetch_add return == target-1) stores release = ep; others
// poll the read-only release line. Acquire-inv only every 31st epoch
// (ring-of-32 window argument keeps cached ring reads safe).
// ---------------------------------------------------------------------------
__device__ __forceinline__ void grid_barrier(int* bar, int target, int ep, bool doInv) {
    vm_drain();
    __syncthreads();
    if (threadIdx.x == 0) {
        int old = __hip_atomic_fetch_add(bar, 1, __ATOMIC_RELAXED, __HIP_MEMORY_SCOPE_AGENT);
        if (old == target - 1) {
            __hip_atomic_store(bar + 32, ep, __ATOMIC_RELAXED, __HIP_MEMORY_SCOPE_AGENT);
        } else {
            while (__hip_atomic_load(bar + 32, __ATOMIC_RELAXED, __HIP_MEMORY_SCOPE_AGENT) < ep) {
                __builtin_amdgcn_s_sleep(8);
            }
        }
        if (doInv)
            (void)__hip_atomic_load(bar, __ATOMIC_ACQUIRE, __HIP_MEMORY_SCOPE_AGENT);
    }
    __syncthreads();
}

// ---------------------------------------------------------------------------
// Persistent kernel: 256 blocks x 512 threads, 1 block/CU.
//   blocks [0,192): GEMM, cell = blk>>6, jt = blk&63 (weights reg/LDS resident)
//   blocks [192,256): attention, ab = blk&31, ac = (blk>>5)&1 (NCHUNK=2)
// Cache policy: hist/out/qall/inputs/biasp cached (write-once / RO);
// act+Pf rings cached (RING=32 + inv-every-31); attC/attML agent loads.
// ---------------------------------------------------------------------------
__global__ __launch_bounds__(512)
__attribute__((amdgpu_waves_per_eu(2)))
void persist_kernel(const float* __restrict__ inputs,
                    const ushort* __restrict__ wpack,
                    const float* __restrict__ biasp,
                    ushort* __restrict__ gpack, ushort* __restrict__ ppack,
                    ushort* __restrict__ epack,
                    float* __restrict__ hist, float* __restrict__ Pf,
                    const float* __restrict__ qall,
                    float* __restrict__ out,
                    float* __restrict__ attC, float* __restrict__ attML,
                    int* __restrict__ cnt, int* __restrict__ bar) {
    extern __shared__ char smraw[];
    float* lds_scr  = (float*)(smraw + SCR_OFF);
    float* lds_gm   = (float*)(smraw + GM_OFF);
    float* lds_red  = (float*)(smraw + RED_OFF);
    int*   lds_flag = (int*)(smraw + FLAG_OFF);

    const int blk = blockIdx.x, tid = threadIdx.x;
    const int cell = blk >> 6, jt = blk & 63;       // cell 3 => attention block
    const int w = tid >> 6, lane = tid & 63;
    const int l15 = lane & 15, hi4 = lane >> 4;
    const int ab = blk & 31, ac = (blk >> 5) & 1;   // attention task
    const ushort* wp = wpack + (size_t)cell * WCELL;

    // ---- persistent weights + epilogue constants (GEMM blocks only) ----
    bf16x8 whiR[8], whiZ[8], whiN[8], wloN[8];
    const int ebt = tid >> 8, eli = (tid >> 2) & 63, ei = tid & 3;
    const int eb = ebt * 16 + (eli & 15);
    const int eu = jt * 16 + (eli >> 4) * 4 + ei;
    const int eex = AEX(eu, eb);
    float bR = 0.f, bZ = 0.f, bNI = 0.f, bNH = 0.f;
    if (cell < 3) {
        #pragma unroll
        for (int i = 0; i < 8; ++i) {
            const int ks = w * 8 + i;
            const size_t aoff = ((size_t)(jt * 256 + ks * 4 + hi4)) * 128 + (size_t)l15 * 8;
            whiR[i] = *(const bf16x8*)(wp + SR + aoff);
            whiZ[i] = *(const bf16x8*)(wp + SZ + aoff);
            bf16x8 rlo = *(const bf16x8*)(wp + SR + WPS + aoff);
            bf16x8 zlo = *(const bf16x8*)(wp + SZ + WPS + aoff);
            *(bf16x8*)(smraw + (((w * 16 + i) * 64 + lane) << 4)) = rlo;
            *(bf16x8*)(smraw + (((w * 16 + 8 + i) * 64 + lane) << 4)) = zlo;
            const int ksn = (w & 3) * 8 + i;
            const size_t noff = ((size_t)(jt * 128 + ksn * 4 + hi4)) * 128 + (size_t)l15 * 8;
            const size_t sN = (w < 4) ? SNX : SNH;
            whiN[i] = *(const bf16x8*)(wp + sN + noff);
            wloN[i] = *(const bf16x8*)(wp + sN + WPS + noff);
        }
        const float* bc = biasp + cell * 4096;
        bR = bc[eu]; bZ = bc[1024 + eu];
        bNI = bc[2048 + eu]; bNH = bc[3072 + eu];
    }
    __syncthreads();

    int ep = 0;
    for (int t = 0; t <= TT + 1; ++t) {
        if (cell < 3) {
            // ================= GEMM block =================
            const int tc = t - cell;
            if (tc >= 0 && tc < TT) {
                f32x4 aR0 = {0,0,0,0}, aR1 = {0,0,0,0};
                f32x4 aZ0 = {0,0,0,0}, aZ1 = {0,0,0,0};
                f32x4 aN0 = {0,0,0,0}, aN1 = {0,0,0,0};
                ushort* apk = (cell == 0) ? gpack : (cell == 1) ? ppack : epack;
                const ushort* ap = apk + (size_t)(tc & (RING - 1)) * ASLOT;
                const ushort* bbp = ap + ((size_t)hi4 * 32 + l15) * 8;
                #pragma unroll
                for (int i = 0; i < 8; ++i) {
                    const int ks = w * 8 + i;
                    const ushort* bp = bbp + (size_t)ks * 1024;
                    bf16x8 bh0 = *(const bf16x8*)(bp);
                    bf16x8 bh1 = *(const bf16x8*)(bp + 128);
                    bf16x8 bl0 = *(const bf16x8*)(bp + APS);
                    bf16x8 bl1 = *(const bf16x8*)(bp + APS + 128);
                    bf16x8 rlo = *(const bf16x8*)(smraw + (((w * 16 + i) * 64 + lane) << 4));
                    bf16x8 zlo = *(const bf16x8*)(smraw + (((w * 16 + 8 + i) * 64 + lane) << 4));
                    aR0 = MF(whiR[i], bh0, aR0); aR0 = MF(whiR[i], bl0, aR0); aR0 = MF(rlo, bh0, aR0);
                    aR1 = MF(whiR[i], bh1, aR1); aR1 = MF(whiR[i], bl1, aR1); aR1 = MF(rlo, bh1, aR1);
                    aZ0 = MF(whiZ[i], bh0, aZ0); aZ0 = MF(whiZ[i], bl0, aZ0); aZ0 = MF(zlo, bh0, aZ0);
                    aZ1 = MF(whiZ[i], bh1, aZ1); aZ1 = MF(whiZ[i], bl1, aZ1); aZ1 = MF(zlo, bh1, aZ1);
                    aN0 = MF(whiN[i], bh0, aN0); aN0 = MF(whiN[i], bl0, aN0); aN0 = MF(wloN[i], bh0, aN0);
                    aN1 = MF(whiN[i], bh1, aN1); aN1 = MF(whiN[i], bl1, aN1); aN1 = MF(wloN[i], bh1, aN1);
                }
                // ---- combine: R, Z, N(iN/hN) via 16KB scratch ----
                const int cbt = tid >> 8, cln = (tid >> 2) & 63, cc = tid & 3;
                __syncthreads();
                *(f32x4*)&lds_scr[((0 * 8 + w) * 64 + lane) * 4] = aR0;
                *(f32x4*)&lds_scr[((1 * 8 + w) * 64 + lane) * 4] = aR1;
                __syncthreads();
                {
                    float s = 0.f;
                    #pragma unroll
                    for (int w2 = 0; w2 < 8; ++w2) s += lds_scr[((cbt * 8 + w2) * 64 + cln) * 4 + cc];
                    lds_gm[((0 * 2 + cbt) * 64 + cln) * 4 + cc] = s;
                }
                __syncthreads();
                *(f32x4*)&lds_scr[((0 * 8 + w) * 64 + lane) * 4] = aZ0;
                *(f32x4*)&lds_scr[((1 * 8 + w) * 64 + lane) * 4] = aZ1;
                __syncthreads();
                {
                    float s = 0.f;
                    #pragma unroll
                    for (int w2 = 0; w2 < 8; ++w2) s += lds_scr[((cbt * 8 + w2) * 64 + cln) * 4 + cc];
                    lds_gm[((1 * 2 + cbt) * 64 + cln) * 4 + cc] = s;
                }
                __syncthreads();
                *(f32x4*)&lds_scr[((0 * 8 + w) * 64 + lane) * 4] = aN0;
                *(f32x4*)&lds_scr[((1 * 8 + w) * 64 + lane) * 4] = aN1;
                __syncthreads();
                {
                    float iN = 0.f, hN = 0.f;
                    #pragma unroll
                    for (int w2 = 0; w2 < 4; ++w2) iN += lds_scr[((cbt * 8 + w2) * 64 + cln) * 4 + cc];
                    #pragma unroll
                    for (int w2 = 4; w2 < 8; ++w2) hN += lds_scr[((cbt * 8 + w2) * 64 + cln) * 4 + cc];
                    lds_gm[((2 * 2 + cbt) * 64 + cln) * 4 + cc] = iN;
                    lds_gm[((3 * 2 + cbt) * 64 + cln) * 4 + cc] = hN;
                }
                __syncthreads();
                // ---- epilogue (1 output/thread), cross-block stores sc1 ----
                {
                    const float R  = lds_gm[((0 * 2 + ebt) * 64 + eli) * 4 + ei];
                    const float Z  = lds_gm[((1 * 2 + ebt) * 64 + eli) * 4 + ei];
                    const float iN = lds_gm[((2 * 2 + ebt) * 64 + eli) * 4 + ei];
                    const float hN = lds_gm[((3 * 2 + ebt) * 64 + eli) * 4 + ei];
                    float hprev;
                    if (cell == 0)      hprev = hist[((size_t)tc * BB + eb) * UU + eu];
                    else if (cell == 1) hprev = Pf[(size_t)(tc & (RING - 1)) * BB * UU + (size_t)eb * UU + eu];
                    else                hprev = (tc > 0) ? out[((size_t)eb * TT + tc - 1) * UU + eu] : 0.f;
                    const float r = 1.f / (1.f + expf(-(R + bR)));
                    const float z = 1.f / (1.f + expf(-(Z + bZ)));
                    const float n2 = tanhf(iN + bNI + r * (hN + bNH));
                    const float val = (1.f - z) * n2 + z * hprev;
                    ushort vh, vl; split2(val, vh, vl);
                    if (cell == 0) {
                        store_f32_sc(&hist[((size_t)(tc + 1) * BB + eb) * UU + eu], val);
                        ushort* d = gpack + (size_t)((tc + 1) & (RING - 1)) * ASLOT;
                        store_u16_sc(d + eex + 32768, vh);
                        store_u16_sc(d + APS + eex + 32768, vl);
                    } else if (cell == 1) {
                        ushort* d = epack + (size_t)(tc & (RING - 1)) * ASLOT;
                        store_u16_sc(d + eex, vh);
                        store_u16_sc(d + APS + eex, vl);
                        if (tc + 2 < TT) {
                            store_f32_sc(&Pf[(size_t)((tc + 2) & (RING - 1)) * BB * UU + (size_t)eb * UU + eu], val);
                            ushort* d2 = ppack + (size_t)((tc + 2) & (RING - 1)) * ASLOT;
                            store_u16_sc(d2 + eex + 32768, vh);
                            store_u16_sc(d2 + APS + eex + 32768, vl);
                            const float gx = val + inputs[((size_t)eb * TT + tc + 2) * UU + eu];
                            ushort gh, gl; split2(gx, gh, gl);
                            ushort* d3 = gpack + (size_t)((tc + 2) & (RING - 1)) * ASLOT;
                            store_u16_sc(d3 + eex, gh);
                            store_u16_sc(d3 + APS + eex, gl);
                        }
                    } else {
                        store_f32_sc(&out[((size_t)eb * TT + tc) * UU + eu], val);
                        if (tc + 1 < TT) {
                            ushort* d = epack + (size_t)((tc + 1) & (RING - 1)) * ASLOT;
                            store_u16_sc(d + eex + 32768, vh);
                            store_u16_sc(d + APS + eex + 32768, vl);
                        }
                    }
                }
            }
        } else if (t < TT) {
            // ================= attention block (ac, ab) =================
            const int nt2 = t + 1;
            const int cstr = (nt2 + NCHUNK - 1) / NCHUNK;
            const int r0 = ac * cstr;
            const int r1x = r0 + cstr;
            const int r1 = (r1x < nt2) ? r1x : nt2;
            const int n = r1 - r0;
            if (n <= 0) {
                #pragma unroll
                for (int rep = 0; rep < 2; ++rep)
                    store_f32_sc(&attC[((size_t)ac * BB + ab) * UU + tid + rep * 512], 0.f);
                if (tid == 0) {
                    store_f32_sc(&attML[((size_t)ac * BB + ab) * 2], -INFINITY);
                    store_f32_sc(&attML[((size_t)ac * BB + ab) * 2 + 1], 0.f);
                }
            } else {
                const float* qb = qall + ((size_t)t * BB + ab) * UU;
                float4 q0 = *(const float4*)&qb[lane * 4];
                float4 q1 = *(const float4*)&qb[256 + lane * 4];
                float4 q2 = *(const float4*)&qb[512 + lane * 4];
                float4 q3 = *(const float4*)&qb[768 + lane * 4];
                float m_run = -INFINITY, l_run = 0.f;
                float4 c0 = {0,0,0,0}, c1 = {0,0,0,0}, c2 = {0,0,0,0}, c3 = {0,0,0,0};
                for (int tp = r0 + w; tp < r1; tp += 8) {
                    const float* hr = hist + ((size_t)tp * BB + ab) * UU;
                    float4 h0 = *(const float4*)&hr[lane * 4];
                    float4 h1 = *(const float4*)&hr[256 + lane * 4];
                    float4 h2 = *(const float4*)&hr[512 + lane * 4];
                    float4 h3 = *(const float4*)&hr[768 + lane * 4];
                    float s = h0.x*q0.x + h0.y*q0.y + h0.z*q0.z + h0.w*q0.w
                            + h1.x*q1.x + h1.y*q1.y + h1.z*q1.z + h1.w*q1.w
                            + h2.x*q2.x + h2.y*q2.y + h2.z*q2.z + h2.w*q2.w
                            + h3.x*q3.x + h3.y*q3.y + h3.z*q3.z + h3.w*q3.w;
                    #pragma unroll
                    for (int off = 32; off; off >>= 1) s += __shfl_xor(s, off);
                    const float mn = fmaxf(m_run, s);
                    const float sc = expf(m_run - mn);
                    const float e2 = expf(s - mn);
                    c0.x = c0.x*sc + e2*h0.x; c0.y = c0.y*sc + e2*h0.y; c0.z = c0.z*sc + e2*h0.z; c0.w = c0.w*sc + e2*h0.w;
                    c1.x = c1.x*sc + e2*h1.x; c1.y = c1.y*sc + e2*h1.y; c1.z = c1.z*sc + e2*h1.z; c1.w = c1.w*sc + e2*h1.w;
                    c2.x = c2.x*sc + e2*h2.x; c2.y = c2.y*sc + e2*h2.y; c2.z = c2.z*sc + e2*h2.z; c2.w = c2.w*sc + e2*h2.w;
                    c3.x = c3.x*sc + e2*h3.x; c3.y = c3.y*sc + e2*h3.y; c3.z = c3.z*sc + e2*h3.z; c3.w = c3.w*sc + e2*h3.w;
                    l_run = l_run * sc + e2;
                    m_run = mn;
                }
                // pass 0: elems [0,512) via c0,c1; per-wave m/l publish
                *(float4*)&lds_scr[w * 512 + lane * 4] = c0;
                *(float4*)&lds_scr[w * 512 + 256 + lane * 4] = c1;
                if (lane == 0) { lds_red[w] = m_run; lds_red[8 + w] = l_run; }
                __syncthreads();
                float M = lds_red[0];
                #pragma unroll
                for (int k = 1; k < 8; ++k) M = fmaxf(M, lds_red[k]);
                float ww[8], L = 0.f;
                #pragma unroll
                for (int k = 0; k < 8; ++k) { ww[k] = expf(lds_red[k] - M); L += ww[k] * lds_red[8 + k]; }
                if (tid == 0) {
                    store_f32_sc(&attML[((size_t)ac * BB + ab) * 2], M);
                    store_f32_sc(&attML[((size_t)ac * BB + ab) * 2 + 1], L);
                }
                {
                    float s = 0.f;
                    #pragma unroll
                    for (int w2 = 0; w2 < 8; ++w2) s += ww[w2] * lds_scr[w2 * 512 + tid];
                    store_f32_sc(&attC[((size_t)ac * BB + ab) * UU + tid], s);
                }
                __syncthreads();
                // pass 1: elems [512,1024) via c2,c3
                *(float4*)&lds_scr[w * 512 + lane * 4] = c2;
                *(float4*)&lds_scr[w * 512 + 256 + lane * 4] = c3;
                __syncthreads();
                {
                    float s = 0.f;
                    #pragma unroll
                    for (int w2 = 0; w2 < 8; ++w2) s += ww[w2] * lds_scr[w2 * 512 + tid];
                    store_f32_sc(&attC[((size_t)ac * BB + ab) * UU + 512 + tid], s);
                }
            }
            // publish chunk results, then count arrivals (sc1 stores drained first)
            vm_drain();
            __syncthreads();
            if (tid == 0) {
                int old = __hip_atomic_fetch_add(cnt + ab, 1, __ATOMIC_RELAXED,
                                                 __HIP_MEMORY_SCOPE_AGENT);
                lds_flag[0] = ((old % NCHUNK) == (NCHUNK - 1)) ? 1 : 0;
            }
            __syncthreads();
            if (lds_flag[0]) {
                // Finisher (2nd arriver): merge 2 partials; agent loads (1-stage lifetime).
                float mm[NCHUNK], ll[NCHUNK];
                #pragma unroll
                for (int c = 0; c < NCHUNK; ++c) {
                    mm[c] = load_f32_ag(&attML[((size_t)c * BB + ab) * 2]);
                    ll[c] = load_f32_ag(&attML[((size_t)c * BB + ab) * 2 + 1]);
                }
                float M2 = mm[0];
                #pragma unroll
                for (int c = 1; c < NCHUNK; ++c) M2 = fmaxf(M2, mm[c]);
                float den = 0.f, wc[NCHUNK];
                #pragma unroll
                for (int c = 0; c < NCHUNK; ++c) { wc[c] = expf(mm[c] - M2); den += wc[c] * ll[c]; }
                const float inv = 1.f / den;
                ushort* d = ppack + (size_t)(t & (RING - 1)) * ASLOT;
                #pragma unroll
                for (int rep = 0; rep < 2; ++rep) {
                    const int e = tid + rep * 512;
                    float s3 = 0.f;
                    #pragma unroll
                    for (int c = 0; c < NCHUNK; ++c)
                        s3 += wc[c] * load_f32_ag(&attC[((size_t)c * BB + ab) * UU + e]);
                    const float xv = s3 * inv + inputs[((size_t)ab * TT + t) * UU + e];
                    ushort vh2, vl2; split2(xv, vh2, vl2);
                    const int ex2 = AEX(e, ab);
                    store_u16_sc(d + ex2, vh2);
                    store_u16_sc(d + APS + ex2, vl2);
                }
            }
        }
        ++ep;
        grid_barrier(bar, GRIDN * ep, ep, (ep % 31) == 0);
    }
}

extern "C" void kernel_launch(void* const* d_in, const int* in_sizes, int n_in,
                              void* d_out, int out_size, void* d_ws, size_t ws_size,
                              hipStream_t stream) {
    (void)in_sizes; (void)n_in; (void)out_size; (void)ws_size;
    const float* inputs = (const float*)d_in[0];
    const float* gW   = (const float*)d_in[1];
    const float* gWih = (const float*)d_in[2];
    const float* gWhh = (const float*)d_in[3];
    const float* gbih = (const float*)d_in[4];
    const float* gbhh = (const float*)d_in[5];
    const float* pWih = (const float*)d_in[6];
    const float* pWhh = (const float*)d_in[7];
    const float* pbih = (const float*)d_in[8];
    const float* pbhh = (const float*)d_in[9];
    const float* eWih = (const float*)d_in[10];
    const float* eWhh = (const float*)d_in[11];
    const float* ebih = (const float*)d_in[12];
    const float* ebhh = (const float*)d_in[13];
    float* out = (float*)d_out;

    char* ws = (char*)d_ws;
    size_t off = 0;
    auto alloc = [&](size_t bytes) {
        void* p = ws + off;
        off += (bytes + 255) & ~(size_t)255;
        return p;
    };
    ushort* wpack = (ushort*)alloc((size_t)3 * WCELL * 2);
    ushort* gpack = (ushort*)alloc((size_t)RING * ASLOT * 2);
    ushort* ppack = (ushort*)alloc((size_t)RING * ASLOT * 2);
    ushort* epack = (ushort*)alloc((size_t)RING * ASLOT * 2);
    float* hist  = (float*)alloc((size_t)(TT + 1) * BB * UU * 4);
    float* qall  = (float*)alloc((size_t)TT * BB * UU * 4);
    float* Pf    = (float*)alloc((size_t)RING * BB * UU * 4);
    float* biasp = (float*)alloc((size_t)3 * 4096 * 4);
    float* attC  = (float*)alloc((size_t)NCHUNK * BB * UU * 4);
    float* attML = (float*)alloc((size_t)NCHUNK * BB * 2 * 4);
    int*   cnt   = (int*)alloc(32 * 4);
    int*   bar   = (int*)alloc(64 * 4);

    packw_kernel<<<12288, 256, 0, stream>>>(gWih, gWhh, wpack);
    packw_kernel<<<12288, 256, 0, stream>>>(pWih, pWhh, wpack + WCELL);
    packw_kernel<<<12288, 256, 0, stream>>>(eWih, eWhh, wpack + 2 * (size_t)WCELL);
    qall_kernel<<<dim3(256, 32), 256, 0, stream>>>(inputs, gW, qall);
    init_kernel<<<176, 256, 0, stream>>>(inputs, gbih, gbhh, pbih, pbhh, ebih, ebhh,
                                         hist, Pf, gpack, ppack, epack, biasp, cnt, bar);

    hipFuncSetAttribute((const void*)persist_kernel,
                        hipFuncAttributeMaxDynamicSharedMemorySize, LDSB);
    void* args[] = {(void*)&inputs, (void*)&wpack, (void*)&biasp,
                    (void*)&gpack, (void*)&ppack, (void*)&epack,
                    (void*)&hist, (void*)&Pf, (void*)&qall, (void*)&out,
                    (void*)&attC, (void*)&attML, (void*)&cnt, (void*)&bar};
    hipError_t ce = hipLaunchCooperativeKernel((const void*)persist_kernel,
                                               dim3(GRIDN), dim3(512), args,
                                               (unsigned)LDSB, stream);
    if (ce != hipSuccess) {
        (void)hipGetLastError();
        // 256 blocks at 1 block/CU on a 256-CU part are co-resident; the
        // monotone-counter barrier is safe under a plain launch too.
        persist_kernel<<<GRIDN, 512, LDSB, stream>>>(inputs, wpack, biasp,
                                                     gpack, ppack, epack,
                                                     hist, Pf, qall, out,
                                                     attC, attML, cnt, bar);
    }
}

// Round 12
// 3705.174 us; speedup vs baseline: 5.4827x; 1.0254x over previous
//
#include <hip/hip_runtime.h>
#include <math.h>

// Problem constants: U=H=1024, B=32, T=256.
#define UU 1024
#define BB 32
#define TT 256
#define NCHUNK 2       // attention chunks per batch (64 dedicated att blocks)
#define GRIDN 256      // 192 GEMM + 64 attention blocks, 1 per CU
#define RING 32        // act/Pf ring depth; inv period 31 < RING

// Weight pack geometry (ushort elems). Per cell: [2 planes][sections r,z,nx,nh]
#define WPS   6291456u
#define WCELL (2u * WPS)
#define SR  0u
#define SZ  2097152u
#define SNX 4194304u
#define SNH 5242880u
// Act pack: per slot [2 planes][64 ks][4 hi][32 b][8 e]; x-half [0,32768), h-half +32768
#define APS   65536u
#define ASLOT (2u * APS)
#define AEX(u, b) ((((((u) >> 5) * 4 + (((u) >> 3) & 3)) * 32 + (b)) * 8) + ((u) & 7))

// Dynamic LDS layout (bytes): [0,128K) r/z lo-plane weights; then scratch.
#define SCR_OFF  131072   // 16 KB scratch (combine dumps / att ctx reduce)
#define RED_OFF  147456   // 16 f32
#define FLAG_OFF 147520
#define LDSB     147584

typedef __attribute__((ext_vector_type(8))) short bf16x8;
typedef __attribute__((ext_vector_type(4))) float f32x4;
#define MF(a, b, c) __builtin_amdgcn_mfma_f32_16x16x32_bf16((a), (b), (c), 0, 0, 0)

__device__ __forceinline__ ushort bf16rne(float v) {
    uint x = __float_as_uint(v);
    uint r = (x + 0x7fffu + ((x >> 16) & 1u)) >> 16;
    return (ushort)r;
}
__device__ __forceinline__ float ubf2f(ushort u) {
    return __uint_as_float(((uint)u) << 16);
}
__device__ __forceinline__ void split2(float v, ushort& h, ushort& l) {
    h = bf16rne(v);
    l = bf16rne(v - ubf2f(h));
}
// Agent-scope write-through stores (reach L3 directly; no wbl2 needed).
__device__ __forceinline__ void store_f32_sc(float* p, float v) {
    asm volatile("global_store_dword %0, %1, off sc1" :: "v"(p), "v"(v) : "memory");
}
__device__ __forceinline__ void store_u16_sc(ushort* p, ushort v) {
    uint vv = v;
    asm volatile("global_store_short %0, %1, off sc1" :: "v"(p), "v"(vv) : "memory");
}
__device__ __forceinline__ void vm_drain() {
    asm volatile("s_waitcnt vmcnt(0)" ::: "memory");
}
// Agent-coherent load for 1-stage-lifetime buffers (attC/attML only).
__device__ __forceinline__ float load_f32_ag(const float* p) {
    return __hip_atomic_load(p, __ATOMIC_RELAXED, __HIP_MEMORY_SCOPE_AGENT);
}

// ---------------------------------------------------------------------------
// Weight pack (unchanged, proven).
// ---------------------------------------------------------------------------
__global__ void packw_kernel(const float* __restrict__ Wih,
                             const float* __restrict__ Whh,
                             ushort* __restrict__ wp) {
    int tile = blockIdx.x;
    int sec, jt, ks, nks;
    size_t soff;
    if (tile < 8192) {
        sec = tile >> 12; int l = tile & 4095; jt = l >> 6; ks = l & 63; nks = 64;
        soff = sec ? SZ : SR;
    } else {
        int l2 = tile - 8192; sec = 2 + (l2 >> 11); int l = l2 & 2047; jt = l >> 5; ks = l & 31; nks = 32;
        soff = (sec == 2) ? SNX : SNH;
    }
    int p = threadIdx.x;
    int e0 = (p & 3) * 2, ul = (p >> 2) & 15, hi = p >> 6;
    int u = jt * 16 + ul;
    int kk = ks * 32 + hi * 8 + e0;
    float2 w;
    if (sec < 2) {
        int row = (sec ? 1024 : 0) + u;
        if (kk < 1024) w = *(const float2*)&Wih[(size_t)row * UU + kk];
        else           w = *(const float2*)&Whh[(size_t)row * UU + kk - 1024];
    } else if (sec == 2) {
        w = *(const float2*)&Wih[(size_t)(2048 + u) * UU + kk];
    } else {
        w = *(const float2*)&Whh[(size_t)(2048 + u) * UU + kk];
    }
    ushort h0, l0, h1, l1;
    split2(w.x, h0, l0); split2(w.y, h1, l1);
    size_t ob = soff + ((((size_t)jt * nks + ks) * 4 + hi) * 16 + ul) * 8 + e0;
    *(uint*)(wp + ob)       = (uint)h0 | ((uint)h1 << 16);
    *(uint*)(wp + WPS + ob) = (uint)l0 | ((uint)l1 << 16);
}

// ---------------------------------------------------------------------------
// q_all[t][b][u] = sum_k inputs[b][t][k] * global_W[k][u]  (fp32)
// ---------------------------------------------------------------------------
__global__ void qall_kernel(const float* __restrict__ x,
                            const float* __restrict__ gW,
                            float* __restrict__ q) {
    __shared__ float xs[32][65];
    int r0 = blockIdx.x * 32, u0 = blockIdx.y * 32;
    int tid = threadIdx.x;
    int rr = tid >> 3, ju = tid & 7;
    float4 acc = {0.f, 0.f, 0.f, 0.f};
    for (int k0 = 0; k0 < UU; k0 += 64) {
        for (int e = tid; e < 32 * 64; e += 256) {
            int lr = e >> 6, lk = e & 63;
            int r = r0 + lr;
            int tt = r >> 5, bb = r & 31;
            xs[lr][lk] = x[((size_t)bb * TT + tt) * UU + k0 + lk];
        }
        __syncthreads();
        #pragma unroll 4
        for (int kk = 0; kk < 64; ++kk) {
            float4 gv = *(const float4*)&gW[(size_t)(k0 + kk) * UU + u0 + ju * 4];
            float xv = xs[rr][kk];
            acc.x += xv * gv.x; acc.y += xv * gv.y;
            acc.z += xv * gv.z; acc.w += xv * gv.w;
        }
        __syncthreads();
    }
    *(float4*)&q[(size_t)(r0 + rr) * UU + u0 + ju * 4] = acc;
}

// ---------------------------------------------------------------------------
// Init (ring-of-32; zeroes slots 0/1 which t=0/1 consume; bar tree).
// bar layout (ints): [0]=release, [64]=root counter, [128+g*64]=leaf g (g<8).
// ---------------------------------------------------------------------------
__global__ void init_kernel(const float* __restrict__ inputs,
                            const float* __restrict__ gbih, const float* __restrict__ gbhh,
                            const float* __restrict__ pbih, const float* __restrict__ pbhh,
                            const float* __restrict__ ebih, const float* __restrict__ ebhh,
                            float* __restrict__ hist, float* __restrict__ Pf,
                            ushort* __restrict__ gpack, ushort* __restrict__ ppack,
                            ushort* __restrict__ epack, float* __restrict__ biasp,
                            int* __restrict__ cnt, int* __restrict__ bar) {
    if (blockIdx.x == 0) {
        if (threadIdx.x < 32) cnt[threadIdx.x] = 0;
        for (int i = threadIdx.x; i < 1024; i += 256) bar[i] = 0;
    }
    if (blockIdx.x < 128) {
        int i = blockIdx.x * 256 + threadIdx.x;
        int b = i >> 10, u = i & 1023;
        hist[i] = 0.f;
        Pf[i] = 0.f; Pf[32768 + i] = 0.f;   // Pf slots 0 (t=0) and 1 (t=1)
        int ex = AEX(u, b);
        int eh = ex + 32768;
        gpack[eh] = 0; gpack[APS + eh] = 0;
        ppack[eh] = 0; ppack[APS + eh] = 0;
        ppack[ASLOT + eh] = 0; ppack[ASLOT + APS + eh] = 0;
        epack[eh] = 0; epack[APS + eh] = 0;
        float x0 = inputs[((size_t)b * TT + 0) * UU + u];
        float x1 = inputs[((size_t)b * TT + 1) * UU + u];
        ushort h, l;
        split2(x0, h, l); gpack[ex] = h; gpack[APS + ex] = l;
        split2(x1, h, l); gpack[ASLOT + ex] = h; gpack[ASLOT + APS + ex] = l;
    } else {
        int idx = (blockIdx.x - 128) * 256 + threadIdx.x;
        int cell = idx >> 12, g4 = (idx >> 10) & 3, u = idx & 1023;
        const float* bih = (cell == 0) ? gbih : (cell == 1) ? pbih : ebih;
        const float* bhh = (cell == 0) ? gbhh : (cell == 1) ? pbhh : ebhh;
        float v;
        if (g4 == 0) v = bih[u] + bhh[u];
        else if (g4 == 1) v = bih[1024 + u] + bhh[1024 + u];
        else if (g4 == 2) v = bih[2048 + u];
        else v = bhh[2048 + u];
        biasp[idx] = v;
    }
}

// ---------------------------------------------------------------------------
// Hierarchical grid barrier: 8 leaf counters (32 blocks each, own cachelines)
// -> root counter -> release word. Monotone counters; group-last detected by
// (old mod groupsize) == groupsize-1. Ordering: each block's vm_drain happens
// before its leaf add; leaf->root->release are value/control-chained; so
// release==ep implies all 256 blocks' sc1 stores reached L3.
// Acquire-inv only every 31st epoch (ring-of-32 window keeps cached rings safe).
// ---------------------------------------------------------------------------
__device__ __forceinline__ void grid_barrier(int* bar, int blk, int ep, bool doInv) {
    vm_drain();
    __syncthreads();
    if (threadIdx.x == 0) {
        int* leaf = bar + 128 + ((blk >> 5) << 6);
        int old = __hip_atomic_fetch_add(leaf, 1, __ATOMIC_RELAXED, __HIP_MEMORY_SCOPE_AGENT);
        if ((old & 31) == 31) {
            int ro = __hip_atomic_fetch_add(bar + 64, 1, __ATOMIC_RELAXED, __HIP_MEMORY_SCOPE_AGENT);
            if ((ro & 7) == 7)
                __hip_atomic_store(bar, ep, __ATOMIC_RELAXED, __HIP_MEMORY_SCOPE_AGENT);
        }
        while (__hip_atomic_load(bar, __ATOMIC_RELAXED, __HIP_MEMORY_SCOPE_AGENT) < ep) {
            __builtin_amdgcn_s_sleep(2);
        }
        if (doInv)
            (void)__hip_atomic_load(bar, __ATOMIC_ACQUIRE, __HIP_MEMORY_SCOPE_AGENT);
    }
    __syncthreads();
}

// ---------------------------------------------------------------------------
// Persistent kernel: 256 blocks x 512 threads, 1 block/CU.
//   blocks [0,192): GEMM, cell = blk>>6, jt = blk&63 (weights reg/LDS resident)
//   blocks [192,256): attention, ab = blk&31, ac = (blk>>5)&1 (NCHUNK=2)
// Gate sums held in REGISTERS (combiner thread == epilogue thread).
// ---------------------------------------------------------------------------
__global__ __launch_bounds__(512)
__attribute__((amdgpu_waves_per_eu(2)))
void persist_kernel(const float* __restrict__ inputs,
                    const ushort* __restrict__ wpack,
                    const float* __restrict__ biasp,
                    ushort* __restrict__ gpack, ushort* __restrict__ ppack,
                    ushort* __restrict__ epack,
                    float* __restrict__ hist, float* __restrict__ Pf,
                    const float* __restrict__ qall,
                    float* __restrict__ out,
                    float* __restrict__ attC, float* __restrict__ attML,
                    int* __restrict__ cnt, int* __restrict__ bar) {
    extern __shared__ char smraw[];
    float* lds_scr  = (float*)(smraw + SCR_OFF);
    float* lds_red  = (float*)(smraw + RED_OFF);
    int*   lds_flag = (int*)(smraw + FLAG_OFF);

    const int blk = blockIdx.x, tid = threadIdx.x;
    const int cell = blk >> 6, jt = blk & 63;       // cell 3 => attention block
    const int w = tid >> 6, lane = tid & 63;
    const int l15 = lane & 15, hi4 = lane >> 4;
    const int ab = blk & 31, ac = (blk >> 5) & 1;   // attention task
    const ushort* wp = wpack + (size_t)cell * WCELL;

    // ---- persistent weights + epilogue constants (GEMM blocks only) ----
    bf16x8 whiR[8], whiZ[8], whiN[8], wloN[8];
    const int ebt = tid >> 8, eli = (tid >> 2) & 63, ei = tid & 3;
    const int eb = ebt * 16 + (eli & 15);
    const int eu = jt * 16 + (eli >> 4) * 4 + ei;
    const int eex = AEX(eu, eb);
    float bR = 0.f, bZ = 0.f, bNI = 0.f, bNH = 0.f;
    if (cell < 3) {
        #pragma unroll
        for (int i = 0; i < 8; ++i) {
            const int ks = w * 8 + i;
            const size_t aoff = ((size_t)(jt * 256 + ks * 4 + hi4)) * 128 + (size_t)l15 * 8;
            whiR[i] = *(const bf16x8*)(wp + SR + aoff);
            whiZ[i] = *(const bf16x8*)(wp + SZ + aoff);
            bf16x8 rlo = *(const bf16x8*)(wp + SR + WPS + aoff);
            bf16x8 zlo = *(const bf16x8*)(wp + SZ + WPS + aoff);
            *(bf16x8*)(smraw + (((w * 16 + i) * 64 + lane) << 4)) = rlo;
            *(bf16x8*)(smraw + (((w * 16 + 8 + i) * 64 + lane) << 4)) = zlo;
            const int ksn = (w & 3) * 8 + i;
            const size_t noff = ((size_t)(jt * 128 + ksn * 4 + hi4)) * 128 + (size_t)l15 * 8;
            const size_t sN = (w < 4) ? SNX : SNH;
            whiN[i] = *(const bf16x8*)(wp + sN + noff);
            wloN[i] = *(const bf16x8*)(wp + sN + WPS + noff);
        }
        const float* bc = biasp + cell * 4096;
        bR = bc[eu]; bZ = bc[1024 + eu];
        bNI = bc[2048 + eu]; bNH = bc[3072 + eu];
    }
    __syncthreads();

    int ep = 0;
    for (int t = 0; t <= TT + 1; ++t) {
        if (cell < 3) {
            // ================= GEMM block =================
            const int tc = t - cell;
            if (tc >= 0 && tc < TT) {
                f32x4 aR0 = {0,0,0,0}, aR1 = {0,0,0,0};
                f32x4 aZ0 = {0,0,0,0}, aZ1 = {0,0,0,0};
                f32x4 aN0 = {0,0,0,0}, aN1 = {0,0,0,0};
                ushort* apk = (cell == 0) ? gpack : (cell == 1) ? ppack : epack;
                const ushort* ap = apk + (size_t)(tc & (RING - 1)) * ASLOT;
                const ushort* bbp = ap + ((size_t)hi4 * 32 + l15) * 8;
                #pragma unroll
                for (int i = 0; i < 8; ++i) {
                    const int ks = w * 8 + i;
                    const ushort* bp = bbp + (size_t)ks * 1024;
                    bf16x8 bh0 = *(const bf16x8*)(bp);
                    bf16x8 bh1 = *(const bf16x8*)(bp + 128);
                    bf16x8 bl0 = *(const bf16x8*)(bp + APS);
                    bf16x8 bl1 = *(const bf16x8*)(bp + APS + 128);
                    bf16x8 rlo = *(const bf16x8*)(smraw + (((w * 16 + i) * 64 + lane) << 4));
                    bf16x8 zlo = *(const bf16x8*)(smraw + (((w * 16 + 8 + i) * 64 + lane) << 4));
                    aR0 = MF(whiR[i], bh0, aR0); aR0 = MF(whiR[i], bl0, aR0); aR0 = MF(rlo, bh0, aR0);
                    aR1 = MF(whiR[i], bh1, aR1); aR1 = MF(whiR[i], bl1, aR1); aR1 = MF(rlo, bh1, aR1);
                    aZ0 = MF(whiZ[i], bh0, aZ0); aZ0 = MF(whiZ[i], bl0, aZ0); aZ0 = MF(zlo, bh0, aZ0);
                    aZ1 = MF(whiZ[i], bh1, aZ1); aZ1 = MF(whiZ[i], bl1, aZ1); aZ1 = MF(zlo, bh1, aZ1);
                    aN0 = MF(whiN[i], bh0, aN0); aN0 = MF(whiN[i], bl0, aN0); aN0 = MF(wloN[i], bh0, aN0);
                    aN1 = MF(whiN[i], bh1, aN1); aN1 = MF(whiN[i], bl1, aN1); aN1 = MF(wloN[i], bh1, aN1);
                }
                // ---- combine into REGISTERS (combiner thread == epilogue thread) ----
                float R, Z, iN, hN;
                // R round
                *(f32x4*)&lds_scr[((0 * 8 + w) * 64 + lane) * 4] = aR0;
                *(f32x4*)&lds_scr[((1 * 8 + w) * 64 + lane) * 4] = aR1;
                __syncthreads();
                {
                    float s = 0.f;
                    #pragma unroll
                    for (int w2 = 0; w2 < 8; ++w2) s += lds_scr[((ebt * 8 + w2) * 64 + eli) * 4 + ei];
                    R = s;
                }
                __syncthreads();
                // Z round
                *(f32x4*)&lds_scr[((0 * 8 + w) * 64 + lane) * 4] = aZ0;
                *(f32x4*)&lds_scr[((1 * 8 + w) * 64 + lane) * 4] = aZ1;
                __syncthreads();
                {
                    float s = 0.f;
                    #pragma unroll
                    for (int w2 = 0; w2 < 8; ++w2) s += lds_scr[((ebt * 8 + w2) * 64 + eli) * 4 + ei];
                    Z = s;
                }
                __syncthreads();
                // N round (iN from waves 0-3, hN from 4-7)
                *(f32x4*)&lds_scr[((0 * 8 + w) * 64 + lane) * 4] = aN0;
                *(f32x4*)&lds_scr[((1 * 8 + w) * 64 + lane) * 4] = aN1;
                __syncthreads();
                {
                    float si = 0.f, sh = 0.f;
                    #pragma unroll
                    for (int w2 = 0; w2 < 4; ++w2) si += lds_scr[((ebt * 8 + w2) * 64 + eli) * 4 + ei];
                    #pragma unroll
                    for (int w2 = 4; w2 < 8; ++w2) sh += lds_scr[((ebt * 8 + w2) * 64 + eli) * 4 + ei];
                    iN = si; hN = sh;
                }
                // no trailing sync needed: next scratch write is after grid_barrier
                // ---- epilogue (1 output/thread), cross-block stores sc1 ----
                {
                    float hprev;
                    if (cell == 0)      hprev = hist[((size_t)tc * BB + eb) * UU + eu];
                    else if (cell == 1) hprev = Pf[(size_t)(tc & (RING - 1)) * BB * UU + (size_t)eb * UU + eu];
                    else                hprev = (tc > 0) ? out[((size_t)eb * TT + tc - 1) * UU + eu] : 0.f;
                    const float r = 1.f / (1.f + expf(-(R + bR)));
                    const float z = 1.f / (1.f + expf(-(Z + bZ)));
                    const float n2 = tanhf(iN + bNI + r * (hN + bNH));
                    const float val = (1.f - z) * n2 + z * hprev;
                    ushort vh, vl; split2(val, vh, vl);
                    if (cell == 0) {
                        store_f32_sc(&hist[((size_t)(tc + 1) * BB + eb) * UU + eu], val);
                        ushort* d = gpack + (size_t)((tc + 1) & (RING - 1)) * ASLOT;
                        store_u16_sc(d + eex + 32768, vh);
                        store_u16_sc(d + APS + eex + 32768, vl);
                    } else if (cell == 1) {
                        ushort* d = epack + (size_t)(tc & (RING - 1)) * ASLOT;
                        store_u16_sc(d + eex, vh);
                        store_u16_sc(d + APS + eex, vl);
                        if (tc + 2 < TT) {
                            store_f32_sc(&Pf[(size_t)((tc + 2) & (RING - 1)) * BB * UU + (size_t)eb * UU + eu], val);
                            ushort* d2 = ppack + (size_t)((tc + 2) & (RING - 1)) * ASLOT;
                            store_u16_sc(d2 + eex + 32768, vh);
                            store_u16_sc(d2 + APS + eex + 32768, vl);
                            const float gx = val + inputs[((size_t)eb * TT + tc + 2) * UU + eu];
                            ushort gh, gl; split2(gx, gh, gl);
                            ushort* d3 = gpack + (size_t)((tc + 2) & (RING - 1)) * ASLOT;
                            store_u16_sc(d3 + eex, gh);
                            store_u16_sc(d3 + APS + eex, gl);
                        }
                    } else {
                        store_f32_sc(&out[((size_t)eb * TT + tc) * UU + eu], val);
                        if (tc + 1 < TT) {
                            ushort* d = epack + (size_t)((tc + 1) & (RING - 1)) * ASLOT;
                            store_u16_sc(d + eex + 32768, vh);
                            store_u16_sc(d + APS + eex + 32768, vl);
                        }
                    }
                }
            }
        } else if (t < TT) {
            // ================= attention block (ac, ab) =================
            const int nt2 = t + 1;
            const int cstr = (nt2 + NCHUNK - 1) / NCHUNK;
            const int r0 = ac * cstr;
            const int r1x = r0 + cstr;
            const int r1 = (r1x < nt2) ? r1x : nt2;
            const int n = r1 - r0;
            if (n <= 0) {
                #pragma unroll
                for (int rep = 0; rep < 2; ++rep)
                    store_f32_sc(&attC[((size_t)ac * BB + ab) * UU + tid + rep * 512], 0.f);
                if (tid == 0) {
                    store_f32_sc(&attML[((size_t)ac * BB + ab) * 2], -INFINITY);
                    store_f32_sc(&attML[((size_t)ac * BB + ab) * 2 + 1], 0.f);
                }
            } else {
                const float* qb = qall + ((size_t)t * BB + ab) * UU;
                float4 q0 = *(const float4*)&qb[lane * 4];
                float4 q1 = *(const float4*)&qb[256 + lane * 4];
                float4 q2 = *(const float4*)&qb[512 + lane * 4];
                float4 q3 = *(const float4*)&qb[768 + lane * 4];
                float m_run = -INFINITY, l_run = 0.f;
                float4 c0 = {0,0,0,0}, c1 = {0,0,0,0}, c2 = {0,0,0,0}, c3 = {0,0,0,0};
                for (int tp = r0 + w; tp < r1; tp += 8) {
                    const float* hr = hist + ((size_t)tp * BB + ab) * UU;
                    float4 h0 = *(const float4*)&hr[lane * 4];
                    float4 h1 = *(const float4*)&hr[256 + lane * 4];
                    float4 h2 = *(const float4*)&hr[512 + lane * 4];
                    float4 h3 = *(const float4*)&hr[768 + lane * 4];
                    float s = h0.x*q0.x + h0.y*q0.y + h0.z*q0.z + h0.w*q0.w
                            + h1.x*q1.x + h1.y*q1.y + h1.z*q1.z + h1.w*q1.w
                            + h2.x*q2.x + h2.y*q2.y + h2.z*q2.z + h2.w*q2.w
                            + h3.x*q3.x + h3.y*q3.y + h3.z*q3.z + h3.w*q3.w;
                    #pragma unroll
                    for (int off = 32; off; off >>= 1) s += __shfl_xor(s, off);
                    const float mn = fmaxf(m_run, s);
                    const float sc = expf(m_run - mn);
                    const float e2 = expf(s - mn);
                    c0.x = c0.x*sc + e2*h0.x; c0.y = c0.y*sc + e2*h0.y; c0.z = c0.z*sc + e2*h0.z; c0.w = c0.w*sc + e2*h0.w;
                    c1.x = c1.x*sc + e2*h1.x; c1.y = c1.y*sc + e2*h1.y; c1.z = c1.z*sc + e2*h1.z; c1.w = c1.w*sc + e2*h1.w;
                    c2.x = c2.x*sc + e2*h2.x; c2.y = c2.y*sc + e2*h2.y; c2.z = c2.z*sc + e2*h2.z; c2.w = c2.w*sc + e2*h2.w;
                    c3.x = c3.x*sc + e2*h3.x; c3.y = c3.y*sc + e2*h3.y; c3.z = c3.z*sc + e2*h3.z; c3.w = c3.w*sc + e2*h3.w;
                    l_run = l_run * sc + e2;
                    m_run = mn;
                }
                // pass 0: elems [0,512) via c0,c1; per-wave m/l publish
                *(float4*)&lds_scr[w * 512 + lane * 4] = c0;
                *(float4*)&lds_scr[w * 512 + 256 + lane * 4] = c1;
                if (lane == 0) { lds_red[w] = m_run; lds_red[8 + w] = l_run; }
                __syncthreads();
                float M = lds_red[0];
                #pragma unroll
                for (int k = 1; k < 8; ++k) M = fmaxf(M, lds_red[k]);
                float ww[8], L = 0.f;
                #pragma unroll
                for (int k = 0; k < 8; ++k) { ww[k] = expf(lds_red[k] - M); L += ww[k] * lds_red[8 + k]; }
                if (tid == 0) {
                    store_f32_sc(&attML[((size_t)ac * BB + ab) * 2], M);
                    store_f32_sc(&attML[((size_t)ac * BB + ab) * 2 + 1], L);
                }
                {
                    float s = 0.f;
                    #pragma unroll
                    for (int w2 = 0; w2 < 8; ++w2) s += ww[w2] * lds_scr[w2 * 512 + tid];
                    store_f32_sc(&attC[((size_t)ac * BB + ab) * UU + tid], s);
                }
                __syncthreads();
                // pass 1: elems [512,1024) via c2,c3
                *(float4*)&lds_scr[w * 512 + lane * 4] = c2;
                *(float4*)&lds_scr[w * 512 + 256 + lane * 4] = c3;
                __syncthreads();
                {
                    float s = 0.f;
                    #pragma unroll
                    for (int w2 = 0; w2 < 8; ++w2) s += ww[w2] * lds_scr[w2 * 512 + tid];
                    store_f32_sc(&attC[((size_t)ac * BB + ab) * UU + 512 + tid], s);
                }
            }
            // publish chunk results, then count arrivals (sc1 stores drained first)
            vm_drain();
            __syncthreads();
            if (tid == 0) {
                int old = __hip_atomic_fetch_add(cnt + ab, 1, __ATOMIC_RELAXED,
                                                 __HIP_MEMORY_SCOPE_AGENT);
                lds_flag[0] = ((old % NCHUNK) == (NCHUNK - 1)) ? 1 : 0;
            }
            __syncthreads();
            if (lds_flag[0]) {
                // Finisher (2nd arriver): merge 2 partials; agent loads (1-stage lifetime).
                float mm[NCHUNK], ll[NCHUNK];
                #pragma unroll
                for (int c = 0; c < NCHUNK; ++c) {
                    mm[c] = load_f32_ag(&attML[((size_t)c * BB + ab) * 2]);
                    ll[c] = load_f32_ag(&attML[((size_t)c * BB + ab) * 2 + 1]);
                }
                float M2 = mm[0];
                #pragma unroll
                for (int c = 1; c < NCHUNK; ++c) M2 = fmaxf(M2, mm[c]);
                float den = 0.f, wc[NCHUNK];
                #pragma unroll
                for (int c = 0; c < NCHUNK; ++c) { wc[c] = expf(mm[c] - M2); den += wc[c] * ll[c]; }
                const float inv = 1.f / den;
                ushort* d = ppack + (size_t)(t & (RING - 1)) * ASLOT;
                #pragma unroll
                for (int rep = 0; rep < 2; ++rep) {
                    const int e = tid + rep * 512;
                    float s3 = 0.f;
                    #pragma unroll
                    for (int c = 0; c < NCHUNK; ++c)
                        s3 += wc[c] * load_f32_ag(&attC[((size_t)c * BB + ab) * UU + e]);
                    const float xv = s3 * inv + inputs[((size_t)ab * TT + t) * UU + e];
                    ushort vh2, vl2; split2(xv, vh2, vl2);
                    const int ex2 = AEX(e, ab);
                    store_u16_sc(d + ex2, vh2);
                    store_u16_sc(d + APS + ex2, vl2);
                }
            }
        }
        ++ep;
        grid_barrier(bar, blk, ep, (ep % 31) == 0);
    }
}

extern "C" void kernel_launch(void* const* d_in, const int* in_sizes, int n_in,
                              void* d_out, int out_size, void* d_ws, size_t ws_size,
                              hipStream_t stream) {
    (void)in_sizes; (void)n_in; (void)out_size; (void)ws_size;
    const float* inputs = (const float*)d_in[0];
    const float* gW   = (const float*)d_in[1];
    const float* gWih = (const float*)d_in[2];
    const float* gWhh = (const float*)d_in[3];
    const float* gbih = (const float*)d_in[4];
    const float* gbhh = (const float*)d_in[5];
    const float* pWih = (const float*)d_in[6];
    const float* pWhh = (const float*)d_in[7];
    const float* pbih = (const float*)d_in[8];
    const float* pbhh = (const float*)d_in[9];
    const float* eWih = (const float*)d_in[10];
    const float* eWhh = (const float*)d_in[11];
    const float* ebih = (const float*)d_in[12];
    const float* ebhh = (const float*)d_in[13];
    float* out = (float*)d_out;

    char* ws = (char*)d_ws;
    size_t off = 0;
    auto alloc = [&](size_t bytes) {
        void* p = ws + off;
        off += (bytes + 255) & ~(size_t)255;
        return p;
    };
    ushort* wpack = (ushort*)alloc((size_t)3 * WCELL * 2);
    ushort* gpack = (ushort*)alloc((size_t)RING * ASLOT * 2);
    ushort* ppack = (ushort*)alloc((size_t)RING * ASLOT * 2);
    ushort* epack = (ushort*)alloc((size_t)RING * ASLOT * 2);
    float* hist  = (float*)alloc((size_t)(TT + 1) * BB * UU * 4);
    float* qall  = (float*)alloc((size_t)TT * BB * UU * 4);
    float* Pf    = (float*)alloc((size_t)RING * BB * UU * 4);
    float* biasp = (float*)alloc((size_t)3 * 4096 * 4);
    float* attC  = (float*)alloc((size_t)NCHUNK * BB * UU * 4);
    float* attML = (float*)alloc((size_t)NCHUNK * BB * 2 * 4);
    int*   cnt   = (int*)alloc(32 * 4);
    int*   bar   = (int*)alloc(1024 * 4);

    packw_kernel<<<12288, 256, 0, stream>>>(gWih, gWhh, wpack);
    packw_kernel<<<12288, 256, 0, stream>>>(pWih, pWhh, wpack + WCELL);
    packw_kernel<<<12288, 256, 0, stream>>>(eWih, eWhh, wpack + 2 * (size_t)WCELL);
    qall_kernel<<<dim3(256, 32), 256, 0, stream>>>(inputs, gW, qall);
    init_kernel<<<176, 256, 0, stream>>>(inputs, gbih, gbhh, pbih, pbhh, ebih, ebhh,
                                         hist, Pf, gpack, ppack, epack, biasp, cnt, bar);

    hipFuncSetAttribute((const void*)persist_kernel,
                        hipFuncAttributeMaxDynamicSharedMemorySize, LDSB);
    void* args[] = {(void*)&inputs, (void*)&wpack, (void*)&biasp,
                    (void*)&gpack, (void*)&ppack, (void*)&epack,
                    (void*)&hist, (void*)&Pf, (void*)&qall, (void*)&out,
                    (void*)&attC, (void*)&attML, (void*)&cnt, (void*)&bar};
    hipError_t ce = hipLaunchCooperativeKernel((const void*)persist_kernel,
                                               dim3(GRIDN), dim3(512), args,
                                               (unsigned)LDSB, stream);
    if (ce != hipSuccess) {
        (void)hipGetLastError();
        // 256 blocks at 1 block/CU on a 256-CU part are co-resident; the
        // monotone-counter barrier is safe under a plain launch too.
        persist_kernel<<<GRIDN, 512, LDSB, stream>>>(inputs, wpack, biasp,
                                                     gpack, ppack, epack,
                                                     hist, Pf, qall, out,
                                                     attC, attML, cnt, bar);
    }
}

// Round 15
// 3563.829 us; speedup vs baseline: 5.7001x; 1.0397x over previous
//
#include <hip/hip_runtime.h>
#include <math.h>

// Problem constants: U=H=1024, B=32, T=256.
#define UU 1024
#define BB 32
#define TT 256
#define NCHUNK 2       // attention chunks per batch (64 dedicated att blocks)
#define GRIDN 256      // 192 GEMM + 64 attention blocks, 1 per CU
#define RING 32        // act/Pf ring depth (bounds e-lag via anti-dep wait)

// Weight pack geometry (ushort elems). Per cell: [2 planes][sections r,z,nx,nh]
#define WPS   6291456u
#define WCELL (2u * WPS)
#define SR  0u
#define SZ  2097152u
#define SNX 4194304u
#define SNH 5242880u
// Act pack: per slot [2 planes][64 ks][4 hi][32 b][8 e]; x-half [0,32768), h-half +32768
#define APS   65536u
#define ASLOT (2u * APS)
#define AEX(u, b) ((((((u) >> 5) * 4 + (((u) >> 3) & 3)) * 32 + (b)) * 8) + ((u) & 7))

// Dynamic LDS layout (bytes): [0,128K) r/z lo-plane weights; then scratch.
#define SCR_OFF  131072   // 16 KB scratch (combine dumps / att ctx reduce)
#define RED_OFF  147456   // 16 f32
#define FLAG_OFF 147520
#define LDSB     147584

typedef __attribute__((ext_vector_type(8))) short bf16x8;
typedef __attribute__((ext_vector_type(4))) float f32x4;
#define MF(a, b, c) __builtin_amdgcn_mfma_f32_16x16x32_bf16((a), (b), (c), 0, 0, 0)

__device__ __forceinline__ ushort bf16rne(float v) {
    uint x = __float_as_uint(v);
    uint r = (x + 0x7fffu + ((x >> 16) & 1u)) >> 16;
    return (ushort)r;
}
__device__ __forceinline__ float ubf2f(ushort u) {
    return __uint_as_float(((uint)u) << 16);
}
__device__ __forceinline__ void split2(float v, ushort& h, ushort& l) {
    h = bf16rne(v);
    l = bf16rne(v - ubf2f(h));
}
// Agent-scope write-through stores (reach L3 directly; no wbl2 needed).
__device__ __forceinline__ void store_f32_sc(float* p, float v) {
    asm volatile("global_store_dword %0, %1, off sc1" :: "v"(p), "v"(v) : "memory");
}
__device__ __forceinline__ void store_u16_sc(ushort* p, ushort v) {
    uint vv = v;
    asm volatile("global_store_short %0, %1, off sc1" :: "v"(p), "v"(vv) : "memory");
}
__device__ __forceinline__ void vm_drain() {
    asm volatile("s_waitcnt vmcnt(0)" ::: "memory");
}
// Agent-coherent loads (read at L3 coherence point; never trust local L2).
__device__ __forceinline__ float load_f32_ag(const float* p) {
    return __hip_atomic_load(p, __ATOMIC_RELAXED, __HIP_MEMORY_SCOPE_AGENT);
}
__device__ __forceinline__ int load_i32_ag(const int* p) {
    return __hip_atomic_load(p, __ATOMIC_RELAXED, __HIP_MEMORY_SCOPE_AGENT);
}
__device__ __forceinline__ bf16x8 load_frag_ag(const ushort* p) {
    union { unsigned long long q[2]; bf16x8 v; } u;
    u.q[0] = __hip_atomic_load((const unsigned long long*)p,
                               __ATOMIC_RELAXED, __HIP_MEMORY_SCOPE_AGENT);
    u.q[1] = __hip_atomic_load((const unsigned long long*)(p + 4),
                               __ATOMIC_RELAXED, __HIP_MEMORY_SCOPE_AGENT);
    return u.v;
}

// ---------------------------------------------------------------------------
// Weight pack (unchanged, proven).
// ---------------------------------------------------------------------------
__global__ void packw_kernel(const float* __restrict__ Wih,
                             const float* __restrict__ Whh,
                             ushort* __restrict__ wp) {
    int tile = blockIdx.x;
    int sec, jt, ks, nks;
    size_t soff;
    if (tile < 8192) {
        sec = tile >> 12; int l = tile & 4095; jt = l >> 6; ks = l & 63; nks = 64;
        soff = sec ? SZ : SR;
    } else {
        int l2 = tile - 8192; sec = 2 + (l2 >> 11); int l = l2 & 2047; jt = l >> 5; ks = l & 31; nks = 32;
        soff = (sec == 2) ? SNX : SNH;
    }
    int p = threadIdx.x;
    int e0 = (p & 3) * 2, ul = (p >> 2) & 15, hi = p >> 6;
    int u = jt * 16 + ul;
    int kk = ks * 32 + hi * 8 + e0;
    float2 w;
    if (sec < 2) {
        int row = (sec ? 1024 : 0) + u;
        if (kk < 1024) w = *(const float2*)&Wih[(size_t)row * UU + kk];
        else           w = *(const float2*)&Whh[(size_t)row * UU + kk - 1024];
    } else if (sec == 2) {
        w = *(const float2*)&Wih[(size_t)(2048 + u) * UU + kk];
    } else {
        w = *(const float2*)&Whh[(size_t)(2048 + u) * UU + kk];
    }
    ushort h0, l0, h1, l1;
    split2(w.x, h0, l0); split2(w.y, h1, l1);
    size_t ob = soff + ((((size_t)jt * nks + ks) * 4 + hi) * 16 + ul) * 8 + e0;
    *(uint*)(wp + ob)       = (uint)h0 | ((uint)h1 << 16);
    *(uint*)(wp + WPS + ob) = (uint)l0 | ((uint)l1 << 16);
}

// ---------------------------------------------------------------------------
// q_all[t][b][u] = sum_k inputs[b][t][k] * global_W[k][u]  (fp32)
// ---------------------------------------------------------------------------
__global__ void qall_kernel(const float* __restrict__ x,
                            const float* __restrict__ gW,
                            float* __restrict__ q) {
    __shared__ float xs[32][65];
    int r0 = blockIdx.x * 32, u0 = blockIdx.y * 32;
    int tid = threadIdx.x;
    int rr = tid >> 3, ju = tid & 7;
    float4 acc = {0.f, 0.f, 0.f, 0.f};
    for (int k0 = 0; k0 < UU; k0 += 64) {
        for (int e = tid; e < 32 * 64; e += 256) {
            int lr = e >> 6, lk = e & 63;
            int r = r0 + lr;
            int tt = r >> 5, bb = r & 31;
            xs[lr][lk] = x[((size_t)bb * TT + tt) * UU + k0 + lk];
        }
        __syncthreads();
        #pragma unroll 4
        for (int kk = 0; kk < 64; ++kk) {
            float4 gv = *(const float4*)&gW[(size_t)(k0 + kk) * UU + u0 + ju * 4];
            float xv = xs[rr][kk];
            acc.x += xv * gv.x; acc.y += xv * gv.y;
            acc.z += xv * gv.z; acc.w += xv * gv.w;
        }
        __syncthreads();
    }
    *(float4*)&q[(size_t)(r0 + rr) * UU + u0 + ju * 4] = acc;
}

// ---------------------------------------------------------------------------
// Init. bar layout (ints):
//   [0]=g_rel  [32]=p_rel  [64]=e_rel
//   [128 + cell*128 + slot*32] = class arrival ring counters (slot<4, monotone)
//   [512 + ab*16] = per-ab finisher-done counter
// cnt[ab] = att pair-arrival counter.
// ---------------------------------------------------------------------------
__global__ void init_kernel(const float* __restrict__ inputs,
                            const float* __restrict__ gbih, const float* __restrict__ gbhh,
                            const float* __restrict__ pbih, const float* __restrict__ pbhh,
                            const float* __restrict__ ebih, const float* __restrict__ ebhh,
                            float* __restrict__ hist, float* __restrict__ Pf,
                            ushort* __restrict__ gpack, ushort* __restrict__ ppack,
                            ushort* __restrict__ epack, float* __restrict__ biasp,
                            int* __restrict__ cnt, int* __restrict__ bar) {
    if (blockIdx.x == 0) {
        if (threadIdx.x < 32) cnt[threadIdx.x] = 0;
        for (int i = threadIdx.x; i < 1024; i += 256) bar[i] = 0;
    }
    if (blockIdx.x < 128) {
        int i = blockIdx.x * 256 + threadIdx.x;
        int b = i >> 10, u = i & 1023;
        hist[i] = 0.f;
        Pf[i] = 0.f; Pf[32768 + i] = 0.f;   // Pf slots 0 (t=0) and 1 (t=1)
        int ex = AEX(u, b);
        int eh = ex + 32768;
        gpack[eh] = 0; gpack[APS + eh] = 0;
        ppack[eh] = 0; ppack[APS + eh] = 0;
        ppack[ASLOT + eh] = 0; ppack[ASLOT + APS + eh] = 0;
        epack[eh] = 0; epack[APS + eh] = 0;
        float x0 = inputs[((size_t)b * TT + 0) * UU + u];
        float x1 = inputs[((size_t)b * TT + 1) * UU + u];
        ushort h, l;
        split2(x0, h, l); gpack[ex] = h; gpack[APS + ex] = l;
        split2(x1, h, l); gpack[ASLOT + ex] = h; gpack[ASLOT + APS + ex] = l;
    } else {
        int idx = (blockIdx.x - 128) * 256 + threadIdx.x;
        int cell = idx >> 12, g4 = (idx >> 10) & 3, u = idx & 1023;
        const float* bih = (cell == 0) ? gbih : (cell == 1) ? pbih : ebih;
        const float* bhh = (cell == 0) ? gbhh : (cell == 1) ? pbhh : ebhh;
        float v;
        if (g4 == 0) v = bih[u] + bhh[u];
        else if (g4 == 1) v = bih[1024 + u] + bhh[1024 + u];
        else if (g4 == 2) v = bih[2048 + u];
        else v = bhh[2048 + u];
        biasp[idx] = v;
    }
}

// ---------------------------------------------------------------------------
// Persistent kernel v3.2: dataflow pipeline with MIN-PROGRESS release words.
//   blocks [0,64)=g, [64,128)=p, [128,192)=e, [192,256)=att(ac,ab).
// X_rel = k  <=>  ALL 64 blocks of class X completed steps < k.
// Waits (audited vs every ring read/write + anti-dep):
//   g(tc):  g_rel>=tc (gpack h slot tc by all g(tc-1); self ring-order),
//           p_rel>=tc-1 (gpack x slot tc by all p(tc-2))
//   att(t): g_rel>=t (hist rows<=t), fin[ab]>=t (pair parity + attC slot free)
//   p(tc):  fin[ALL ab]>=tc+1 (ppack x slot tc by all finishers of step tc),
//           p_rel>=tc-1 (ppack h slot tc by all p(tc-2)),
//           e_rel>=tc-31 (epack x slot tc&31 anti-dep vs e(tc-32))
//   e(tc):  p_rel>=tc+1 (epack x slot tc by all p(tc)),
//           e_rel>=tc (epack h slot tc by all e(tc-1))
// Release publish: 64th epoch-tc arriver (ring counter old%64==63) does
// atomic_max(rel, tc+1). Sound: self-waits serialize epochs on each ring slot;
// epoch-tc completion implies all earlier epochs complete.
// Cache policy: cached = hist/out/qall/inputs/biasp/wpack (write-once/RO, never
// pre-read); agent loads = act rings, Pf, attC/attML. Stores sc1 + vm_drain
// before arrival adds.
// ---------------------------------------------------------------------------
__global__ __launch_bounds__(512)
__attribute__((amdgpu_waves_per_eu(2)))
void persist_kernel(const float* __restrict__ inputs,
                    const ushort* __restrict__ wpack,
                    const float* __restrict__ biasp,
                    ushort* __restrict__ gpack, ushort* __restrict__ ppack,
                    ushort* __restrict__ epack,
                    float* __restrict__ hist, float* __restrict__ Pf,
                    const float* __restrict__ qall,
                    float* __restrict__ out,
                    float* __restrict__ attC, float* __restrict__ attML,
                    int* __restrict__ cnt, int* __restrict__ bar) {
    extern __shared__ char smraw[];
    float* lds_scr  = (float*)(smraw + SCR_OFF);
    float* lds_red  = (float*)(smraw + RED_OFF);
    int*   lds_flag = (int*)(smraw + FLAG_OFF);

    const int blk = blockIdx.x, tid = threadIdx.x;
    const int cell = blk >> 6, jt = blk & 63;       // cell 3 => attention block
    const int w = tid >> 6, lane = tid & 63;
    const int l15 = lane & 15, hi4 = lane >> 4;
    const int ab = blk & 31, ac = (blk >> 5) & 1;   // attention task
    const ushort* wp = wpack + (size_t)cell * WCELL;

    if (cell < 3) {
        // ================= GEMM class (g / p / e) =================
        bf16x8 whiR[8], whiZ[8], whiN[8], wloN[8];
        const int ebt = tid >> 8, eli = (tid >> 2) & 63, ei = tid & 3;
        const int eb = ebt * 16 + (eli & 15);
        const int eu = jt * 16 + (eli >> 4) * 4 + ei;
        const int eex = AEX(eu, eb);
        #pragma unroll
        for (int i = 0; i < 8; ++i) {
            const int ks = w * 8 + i;
            const size_t aoff = ((size_t)(jt * 256 + ks * 4 + hi4)) * 128 + (size_t)l15 * 8;
            whiR[i] = *(const bf16x8*)(wp + SR + aoff);
            whiZ[i] = *(const bf16x8*)(wp + SZ + aoff);
            bf16x8 rlo = *(const bf16x8*)(wp + SR + WPS + aoff);
            bf16x8 zlo = *(const bf16x8*)(wp + SZ + WPS + aoff);
            *(bf16x8*)(smraw + (((w * 16 + i) * 64 + lane) << 4)) = rlo;
            *(bf16x8*)(smraw + (((w * 16 + 8 + i) * 64 + lane) << 4)) = zlo;
            const int ksn = (w & 3) * 8 + i;
            const size_t noff = ((size_t)(jt * 128 + ksn * 4 + hi4)) * 128 + (size_t)l15 * 8;
            const size_t sN = (w < 4) ? SNX : SNH;
            whiN[i] = *(const bf16x8*)(wp + sN + noff);
            wloN[i] = *(const bf16x8*)(wp + sN + WPS + noff);
        }
        const float* bc = biasp + cell * 4096;
        const float bR = bc[eu], bZ = bc[1024 + eu];
        const float bNI = bc[2048 + eu], bNH = bc[3072 + eu];
        ushort* apk = (cell == 0) ? gpack : (cell == 1) ? ppack : epack;
        __syncthreads();

        for (int tc = 0; tc < TT; ++tc) {
            // ---- lane-parallel min-progress waits (wave 0) ----
            if (w == 0) {
                const int* wptr; int wneed;
                if (cell == 0) {
                    if (lane == 0)      { wptr = bar;       wneed = tc; }      // g_rel
                    else if (lane == 1) { wptr = bar + 32;  wneed = tc - 1; }  // p_rel
                    else                { wptr = bar;       wneed = -2147483647; }
                } else if (cell == 1) {
                    if (lane < 32)       { wptr = bar + 512 + lane * 16; wneed = tc + 1; } // fin[all]
                    else if (lane == 32) { wptr = bar + 32; wneed = tc - 1; }  // p_rel
                    else if (lane == 33) { wptr = bar + 64; wneed = tc - 31; } // e_rel
                    else                 { wptr = bar;      wneed = -2147483647; }
                } else {
                    if (lane == 0)      { wptr = bar + 32;  wneed = tc + 1; }  // p_rel
                    else if (lane == 1) { wptr = bar + 64;  wneed = tc; }      // e_rel
                    else                { wptr = bar;       wneed = -2147483647; }
                }
                while (!__all(load_i32_ag(wptr) >= wneed))
                    __builtin_amdgcn_s_sleep(8);
            }
            __syncthreads();
            f32x4 aR0 = {0,0,0,0}, aR1 = {0,0,0,0};
            f32x4 aZ0 = {0,0,0,0}, aZ1 = {0,0,0,0};
            f32x4 aN0 = {0,0,0,0}, aN1 = {0,0,0,0};
            const ushort* ap = apk + (size_t)(tc & (RING - 1)) * ASLOT;
            const ushort* bbp = ap + ((size_t)hi4 * 32 + l15) * 8;
            #pragma unroll
            for (int i = 0; i < 8; ++i) {
                const int ks = w * 8 + i;
                const ushort* bp = bbp + (size_t)ks * 1024;
                bf16x8 bh0 = load_frag_ag(bp);
                bf16x8 bh1 = load_frag_ag(bp + 128);
                bf16x8 bl0 = load_frag_ag(bp + APS);
                bf16x8 bl1 = load_frag_ag(bp + APS + 128);
                bf16x8 rlo = *(const bf16x8*)(smraw + (((w * 16 + i) * 64 + lane) << 4));
                bf16x8 zlo = *(const bf16x8*)(smraw + (((w * 16 + 8 + i) * 64 + lane) << 4));
                aR0 = MF(whiR[i], bh0, aR0); aR0 = MF(whiR[i], bl0, aR0); aR0 = MF(rlo, bh0, aR0);
                aR1 = MF(whiR[i], bh1, aR1); aR1 = MF(whiR[i], bl1, aR1); aR1 = MF(rlo, bh1, aR1);
                aZ0 = MF(whiZ[i], bh0, aZ0); aZ0 = MF(whiZ[i], bl0, aZ0); aZ0 = MF(zlo, bh0, aZ0);
                aZ1 = MF(whiZ[i], bh1, aZ1); aZ1 = MF(whiZ[i], bl1, aZ1); aZ1 = MF(zlo, bh1, aZ1);
                aN0 = MF(whiN[i], bh0, aN0); aN0 = MF(whiN[i], bl0, aN0); aN0 = MF(wloN[i], bh0, aN0);
                aN1 = MF(whiN[i], bh1, aN1); aN1 = MF(whiN[i], bl1, aN1); aN1 = MF(wloN[i], bh1, aN1);
            }
            // ---- combine into registers (combiner thread == epilogue thread) ----
            float R, Z, iN, hN;
            *(f32x4*)&lds_scr[((0 * 8 + w) * 64 + lane) * 4] = aR0;
            *(f32x4*)&lds_scr[((1 * 8 + w) * 64 + lane) * 4] = aR1;
            __syncthreads();
            {
                float s = 0.f;
                #pragma unroll
                for (int w2 = 0; w2 < 8; ++w2) s += lds_scr[((ebt * 8 + w2) * 64 + eli) * 4 + ei];
                R = s;
            }
            __syncthreads();
            *(f32x4*)&lds_scr[((0 * 8 + w) * 64 + lane) * 4] = aZ0;
            *(f32x4*)&lds_scr[((1 * 8 + w) * 64 + lane) * 4] = aZ1;
            __syncthreads();
            {
                float s = 0.f;
                #pragma unroll
                for (int w2 = 0; w2 < 8; ++w2) s += lds_scr[((ebt * 8 + w2) * 64 + eli) * 4 + ei];
                Z = s;
            }
            __syncthreads();
            *(f32x4*)&lds_scr[((0 * 8 + w) * 64 + lane) * 4] = aN0;
            *(f32x4*)&lds_scr[((1 * 8 + w) * 64 + lane) * 4] = aN1;
            __syncthreads();
            {
                float si = 0.f, sh = 0.f;
                #pragma unroll
                for (int w2 = 0; w2 < 4; ++w2) si += lds_scr[((ebt * 8 + w2) * 64 + eli) * 4 + ei];
                #pragma unroll
                for (int w2 = 4; w2 < 8; ++w2) sh += lds_scr[((ebt * 8 + w2) * 64 + eli) * 4 + ei];
                iN = si; hN = sh;
            }
            // ---- epilogue (1 output/thread), cross-block stores sc1 ----
            {
                float hprev;
                if (cell == 0)      hprev = hist[((size_t)tc * BB + eb) * UU + eu];
                else if (cell == 1) hprev = load_f32_ag(&Pf[(size_t)(tc & (RING - 1)) * BB * UU + (size_t)eb * UU + eu]);
                else                hprev = (tc > 0) ? out[((size_t)eb * TT + tc - 1) * UU + eu] : 0.f;
                const float r = 1.f / (1.f + expf(-(R + bR)));
                const float z = 1.f / (1.f + expf(-(Z + bZ)));
                const float n2 = tanhf(iN + bNI + r * (hN + bNH));
                const float val = (1.f - z) * n2 + z * hprev;
                ushort vh, vl; split2(val, vh, vl);
                if (cell == 0) {
                    store_f32_sc(&hist[((size_t)(tc + 1) * BB + eb) * UU + eu], val);
                    ushort* d = gpack + (size_t)((tc + 1) & (RING - 1)) * ASLOT;
                    store_u16_sc(d + eex + 32768, vh);
                    store_u16_sc(d + APS + eex + 32768, vl);
                } else if (cell == 1) {
                    ushort* d = epack + (size_t)(tc & (RING - 1)) * ASLOT;
                    store_u16_sc(d + eex, vh);
                    store_u16_sc(d + APS + eex, vl);
                    if (tc + 2 < TT) {
                        store_f32_sc(&Pf[(size_t)((tc + 2) & (RING - 1)) * BB * UU + (size_t)eb * UU + eu], val);
                        ushort* d2 = ppack + (size_t)((tc + 2) & (RING - 1)) * ASLOT;
                        store_u16_sc(d2 + eex + 32768, vh);
                        store_u16_sc(d2 + APS + eex + 32768, vl);
                        const float gx = val + inputs[((size_t)eb * TT + tc + 2) * UU + eu];
                        ushort gh, gl; split2(gx, gh, gl);
                        ushort* d3 = gpack + (size_t)((tc + 2) & (RING - 1)) * ASLOT;
                        store_u16_sc(d3 + eex, gh);
                        store_u16_sc(d3 + APS + eex, gl);
                    }
                } else {
                    store_f32_sc(&out[((size_t)eb * TT + tc) * UU + eu], val);
                    if (tc + 1 < TT) {
                        ushort* d = epack + (size_t)((tc + 1) & (RING - 1)) * ASLOT;
                        store_u16_sc(d + eex + 32768, vh);
                        store_u16_sc(d + APS + eex + 32768, vl);
                    }
                }
            }
            vm_drain();
            __syncthreads();
            if (tid == 0) {
                int* ring = bar + 128 + cell * 128 + (tc & 3) * 32;
                int old = __hip_atomic_fetch_add(ring, 1, __ATOMIC_RELAXED,
                                                 __HIP_MEMORY_SCOPE_AGENT);
                if ((old & 63) == 63) {
                    (void)__hip_atomic_fetch_max(bar + cell * 32, tc + 1,
                                                 __ATOMIC_RELAXED, __HIP_MEMORY_SCOPE_AGENT);
                }
            }
        }
    } else {
        // ================= attention class (ac, ab) =================
        int* fin = bar + 512 + ab * 16;
        for (int t = 0; t < TT; ++t) {
            if (w == 0) {
                const int* wptr; int wneed;
                if (lane == 0)      { wptr = bar; wneed = t; }   // g_rel >= t
                else if (lane == 1) { wptr = fin; wneed = t; }   // finisher of t-1 done
                else                { wptr = bar; wneed = -2147483647; }
                while (!__all(load_i32_ag(wptr) >= wneed))
                    __builtin_amdgcn_s_sleep(8);
            }
            __syncthreads();
            const int slot = t & 3;
            float* aC = attC + (((size_t)slot * NCHUNK + ac) * BB + ab) * UU;
            float* aML = attML + (((size_t)slot * NCHUNK + ac) * BB + ab) * 2;
            const int nt2 = t + 1;
            const int cstr = (nt2 + NCHUNK - 1) / NCHUNK;
            const int r0 = ac * cstr;
            const int r1x = r0 + cstr;
            const int r1 = (r1x < nt2) ? r1x : nt2;
            const int n = r1 - r0;
            if (n <= 0) {
                #pragma unroll
                for (int rep = 0; rep < 2; ++rep)
                    store_f32_sc(aC + tid + rep * 512, 0.f);
                if (tid == 0) {
                    store_f32_sc(aML, -INFINITY);
                    store_f32_sc(aML + 1, 0.f);
                }
            } else {
                const float* qb = qall + ((size_t)t * BB + ab) * UU;
                float4 q0 = *(const float4*)&qb[lane * 4];
                float4 q1 = *(const float4*)&qb[256 + lane * 4];
                float4 q2 = *(const float4*)&qb[512 + lane * 4];
                float4 q3 = *(const float4*)&qb[768 + lane * 4];
                float m_run = -INFINITY, l_run = 0.f;
                float4 c0 = {0,0,0,0}, c1 = {0,0,0,0}, c2 = {0,0,0,0}, c3 = {0,0,0,0};
                for (int tp = r0 + w; tp < r1; tp += 8) {
                    const float* hr = hist + ((size_t)tp * BB + ab) * UU;
                    float4 h0 = *(const float4*)&hr[lane * 4];
                    float4 h1 = *(const float4*)&hr[256 + lane * 4];
                    float4 h2 = *(const float4*)&hr[512 + lane * 4];
                    float4 h3 = *(const float4*)&hr[768 + lane * 4];
                    float s = h0.x*q0.x + h0.y*q0.y + h0.z*q0.z + h0.w*q0.w
                            + h1.x*q1.x + h1.y*q1.y + h1.z*q1.z + h1.w*q1.w
                            + h2.x*q2.x + h2.y*q2.y + h2.z*q2.z + h2.w*q2.w
                            + h3.x*q3.x + h3.y*q3.y + h3.z*q3.z + h3.w*q3.w;
                    #pragma unroll
                    for (int off = 32; off; off >>= 1) s += __shfl_xor(s, off);
                    const float mn = fmaxf(m_run, s);
                    const float sc = expf(m_run - mn);
                    const float e2 = expf(s - mn);
                    c0.x = c0.x*sc + e2*h0.x; c0.y = c0.y*sc + e2*h0.y; c0.z = c0.z*sc + e2*h0.z; c0.w = c0.w*sc + e2*h0.w;
                    c1.x = c1.x*sc + e2*h1.x; c1.y = c1.y*sc + e2*h1.y; c1.z = c1.z*sc + e2*h1.z; c1.w = c1.w*sc + e2*h1.w;
                    c2.x = c2.x*sc + e2*h2.x; c2.y = c2.y*sc + e2*h2.y; c2.z = c2.z*sc + e2*h2.z; c2.w = c2.w*sc + e2*h2.w;
                    c3.x = c3.x*sc + e2*h3.x; c3.y = c3.y*sc + e2*h3.y; c3.z = c3.z*sc + e2*h3.z; c3.w = c3.w*sc + e2*h3.w;
                    l_run = l_run * sc + e2;
                    m_run = mn;
                }
                *(float4*)&lds_scr[w * 512 + lane * 4] = c0;
                *(float4*)&lds_scr[w * 512 + 256 + lane * 4] = c1;
                if (lane == 0) { lds_red[w] = m_run; lds_red[8 + w] = l_run; }
                __syncthreads();
                float M = lds_red[0];
                #pragma unroll
                for (int k = 1; k < 8; ++k) M = fmaxf(M, lds_red[k]);
                float ww[8], L = 0.f;
                #pragma unroll
                for (int k = 0; k < 8; ++k) { ww[k] = expf(lds_red[k] - M); L += ww[k] * lds_red[8 + k]; }
                if (tid == 0) {
                    store_f32_sc(aML, M);
                    store_f32_sc(aML + 1, L);
                }
                {
                    float s = 0.f;
                    #pragma unroll
                    for (int w2 = 0; w2 < 8; ++w2) s += ww[w2] * lds_scr[w2 * 512 + tid];
                    store_f32_sc(aC + tid, s);
                }
                __syncthreads();
                *(float4*)&lds_scr[w * 512 + lane * 4] = c2;
                *(float4*)&lds_scr[w * 512 + 256 + lane * 4] = c3;
                __syncthreads();
                {
                    float s = 0.f;
                    #pragma unroll
                    for (int w2 = 0; w2 < 8; ++w2) s += ww[w2] * lds_scr[w2 * 512 + tid];
                    store_f32_sc(aC + 512 + tid, s);
                }
            }
            // publish chunk, pair handshake (arrivals for step t are {2t, 2t+1})
            vm_drain();
            __syncthreads();
            if (tid == 0) {
                int old = __hip_atomic_fetch_add(cnt + ab, 1, __ATOMIC_RELAXED,
                                                 __HIP_MEMORY_SCOPE_AGENT);
                lds_flag[0] = (old & 1);
            }
            __syncthreads();
            if (lds_flag[0]) {
                // Finisher (2nd arriver of this step): merge 2 partials (agent loads).
                float mm[NCHUNK], ll[NCHUNK];
                #pragma unroll
                for (int c = 0; c < NCHUNK; ++c) {
                    const float* ml = attML + (((size_t)slot * NCHUNK + c) * BB + ab) * 2;
                    mm[c] = load_f32_ag(ml);
                    ll[c] = load_f32_ag(ml + 1);
                }
                float M2 = mm[0];
                #pragma unroll
                for (int c = 1; c < NCHUNK; ++c) M2 = fmaxf(M2, mm[c]);
                float den = 0.f, wc[NCHUNK];
                #pragma unroll
                for (int c = 0; c < NCHUNK; ++c) { wc[c] = expf(mm[c] - M2); den += wc[c] * ll[c]; }
                const float inv = 1.f / den;
                ushort* d = ppack + (size_t)(t & (RING - 1)) * ASLOT;
                #pragma unroll
                for (int rep = 0; rep < 2; ++rep) {
                    const int e = tid + rep * 512;
                    float s3 = 0.f;
                    #pragma unroll
                    for (int c = 0; c < NCHUNK; ++c)
                        s3 += wc[c] * load_f32_ag(&attC[(((size_t)slot * NCHUNK + c) * BB + ab) * UU + e]);
                    const float xv = s3 * inv + inputs[((size_t)ab * TT + t) * UU + e];
                    ushort vh2, vl2; split2(xv, vh2, vl2);
                    const int ex2 = AEX(e, ab);
                    store_u16_sc(d + ex2, vh2);
                    store_u16_sc(d + APS + ex2, vl2);
                }
                vm_drain();
            }
            __syncthreads();
            if (tid == 0 && lds_flag[0])
                __hip_atomic_fetch_add(fin, 1, __ATOMIC_RELAXED, __HIP_MEMORY_SCOPE_AGENT);
        }
    }
}

extern "C" void kernel_launch(void* const* d_in, const int* in_sizes, int n_in,
                              void* d_out, int out_size, void* d_ws, size_t ws_size,
                              hipStream_t stream) {
    (void)in_sizes; (void)n_in; (void)out_size; (void)ws_size;
    const float* inputs = (const float*)d_in[0];
    const float* gW   = (const float*)d_in[1];
    const float* gWih = (const float*)d_in[2];
    const float* gWhh = (const float*)d_in[3];
    const float* gbih = (const float*)d_in[4];
    const float* gbhh = (const float*)d_in[5];
    const float* pWih = (const float*)d_in[6];
    const float* pWhh = (const float*)d_in[7];
    const float* pbih = (const float*)d_in[8];
    const float* pbhh = (const float*)d_in[9];
    const float* eWih = (const float*)d_in[10];
    const float* eWhh = (const float*)d_in[11];
    const float* ebih = (const float*)d_in[12];
    const float* ebhh = (const float*)d_in[13];
    float* out = (float*)d_out;

    char* ws = (char*)d_ws;
    size_t off = 0;
    auto alloc = [&](size_t bytes) {
        void* p = ws + off;
        off += (bytes + 255) & ~(size_t)255;
        return p;
    };
    ushort* wpack = (ushort*)alloc((size_t)3 * WCELL * 2);
    ushort* gpack = (ushort*)alloc((size_t)RING * ASLOT * 2);
    ushort* ppack = (ushort*)alloc((size_t)RING * ASLOT * 2);
    ushort* epack = (ushort*)alloc((size_t)RING * ASLOT * 2);
    float* hist  = (float*)alloc((size_t)(TT + 1) * BB * UU * 4);
    float* qall  = (float*)alloc((size_t)TT * BB * UU * 4);
    float* Pf    = (float*)alloc((size_t)RING * BB * UU * 4);
    float* biasp = (float*)alloc((size_t)3 * 4096 * 4);
    float* attC  = (float*)alloc((size_t)4 * NCHUNK * BB * UU * 4);   // 4-slot parity
    float* attML = (float*)alloc((size_t)4 * NCHUNK * BB * 2 * 4);
    int*   cnt   = (int*)alloc(32 * 4);
    int*   bar   = (int*)alloc(1024 * 4);

    packw_kernel<<<12288, 256, 0, stream>>>(gWih, gWhh, wpack);
    packw_kernel<<<12288, 256, 0, stream>>>(pWih, pWhh, wpack + WCELL);
    packw_kernel<<<12288, 256, 0, stream>>>(eWih, eWhh, wpack + 2 * (size_t)WCELL);
    qall_kernel<<<dim3(256, 32), 256, 0, stream>>>(inputs, gW, qall);
    init_kernel<<<176, 256, 0, stream>>>(inputs, gbih, gbhh, pbih, pbhh, ebih, ebhh,
                                         hist, Pf, gpack, ppack, epack, biasp, cnt, bar);

    hipFuncSetAttribute((const void*)persist_kernel,
                        hipFuncAttributeMaxDynamicSharedMemorySize, LDSB);
    void* args[] = {(void*)&inputs, (void*)&wpack, (void*)&biasp,
                    (void*)&gpack, (void*)&ppack, (void*)&epack,
                    (void*)&hist, (void*)&Pf, (void*)&qall, (void*)&out,
                    (void*)&attC, (void*)&attML, (void*)&cnt, (void*)&bar};
    hipError_t ce = hipLaunchCooperativeKernel((const void*)persist_kernel,
                                               dim3(GRIDN), dim3(512), args,
                                               (unsigned)LDSB, stream);
    if (ce != hipSuccess) {
        (void)hipGetLastError();
        // 256 blocks at 1 block/CU on a 256-CU part are co-resident; the
        // monotone-counter dataflow is safe under a plain launch too.
        persist_kernel<<<GRIDN, 512, LDSB, stream>>>(inputs, wpack, biasp,
                                                     gpack, ppack, epack,
                                                     hist, Pf, qall, out,
                                                     attC, attML, cnt, bar);
    }
}

// Round 16
// 2827.969 us; speedup vs baseline: 7.1833x; 1.2602x over previous
//
#include <hip/hip_runtime.h>
#include <math.h>

// Problem constants: U=H=1024, B=32, T=256.
#define UU 1024
#define BB 32
#define TT 256
#define NCHUNK 2       // attention chunks per batch (64 dedicated att blocks)
#define GRIDN 256      // 192 GEMM + 64 attention blocks, 1 per CU
#define RING 32        // act/Pf ring depth (bounds e-lag via anti-dep wait)

// Weight pack geometry (ushort elems). Per cell: [2 planes][sections r,z,nx,nh]
#define WPS   6291456u
#define WCELL (2u * WPS)
#define SR  0u
#define SZ  2097152u
#define SNX 4194304u
#define SNH 5242880u
// Act pack: per slot [2 planes][64 ks][4 hi][32 b][8 e]; x-half [0,32768), h-half +32768
#define APS   65536u
#define ASLOT (2u * APS)
#define AEX(u, b) ((((((u) >> 5) * 4 + (((u) >> 3) & 3)) * 32 + (b)) * 8) + ((u) & 7))

// Dynamic LDS layout (bytes): [0,128K) r/z lo-plane weights; then scratch.
#define SCR_OFF  131072   // 16 KB scratch (combine dumps / att ctx reduce)
#define RED_OFF  147456   // 16 f32
#define FLAG_OFF 147520
#define LDSB     147584

typedef __attribute__((ext_vector_type(8))) short bf16x8;
typedef __attribute__((ext_vector_type(4))) float f32x4;
#define MF(a, b, c) __builtin_amdgcn_mfma_f32_16x16x32_bf16((a), (b), (c), 0, 0, 0)

__device__ __forceinline__ ushort bf16rne(float v) {
    uint x = __float_as_uint(v);
    uint r = (x + 0x7fffu + ((x >> 16) & 1u)) >> 16;
    return (ushort)r;
}
__device__ __forceinline__ float ubf2f(ushort u) {
    return __uint_as_float(((uint)u) << 16);
}
__device__ __forceinline__ void split2(float v, ushort& h, ushort& l) {
    h = bf16rne(v);
    l = bf16rne(v - ubf2f(h));
}
// Agent-scope write-through stores (reach L3 directly; no wbl2 needed).
__device__ __forceinline__ void store_f32_sc(float* p, float v) {
    asm volatile("global_store_dword %0, %1, off sc1" :: "v"(p), "v"(v) : "memory");
}
__device__ __forceinline__ void store_u16_sc(ushort* p, ushort v) {
    uint vv = v;
    asm volatile("global_store_short %0, %1, off sc1" :: "v"(p), "v"(vv) : "memory");
}
__device__ __forceinline__ void vm_drain() {
    asm volatile("s_waitcnt vmcnt(0)" ::: "memory");
}
// Agent-coherent loads (read at L3 coherence point; never trust local L2).
__device__ __forceinline__ float load_f32_ag(const float* p) {
    return __hip_atomic_load(p, __ATOMIC_RELAXED, __HIP_MEMORY_SCOPE_AGENT);
}
__device__ __forceinline__ int load_i32_ag(const int* p) {
    return __hip_atomic_load(p, __ATOMIC_RELAXED, __HIP_MEMORY_SCOPE_AGENT);
}
__device__ __forceinline__ bf16x8 load_frag_ag(const ushort* p) {
    union { unsigned long long q[2]; bf16x8 v; } u;
    u.q[0] = __hip_atomic_load((const unsigned long long*)p,
                               __ATOMIC_RELAXED, __HIP_MEMORY_SCOPE_AGENT);
    u.q[1] = __hip_atomic_load((const unsigned long long*)(p + 4),
                               __ATOMIC_RELAXED, __HIP_MEMORY_SCOPE_AGENT);
    return u.v;
}

// ---------------------------------------------------------------------------
// Weight pack, all 3 cells in one launch (grid 36864; tile logic proven).
// ---------------------------------------------------------------------------
__global__ void packw_kernel(const float* __restrict__ gWih, const float* __restrict__ gWhh,
                             const float* __restrict__ pWih, const float* __restrict__ pWhh,
                             const float* __restrict__ eWih, const float* __restrict__ eWhh,
                             ushort* __restrict__ wpack) {
    int cellb = blockIdx.x / 12288;
    int tile = blockIdx.x - cellb * 12288;
    const float* Wih = (cellb == 0) ? gWih : (cellb == 1) ? pWih : eWih;
    const float* Whh = (cellb == 0) ? gWhh : (cellb == 1) ? pWhh : eWhh;
    ushort* wp = wpack + (size_t)cellb * WCELL;
    int sec, jt, ks, nks;
    size_t soff;
    if (tile < 8192) {
        sec = tile >> 12; int l = tile & 4095; jt = l >> 6; ks = l & 63; nks = 64;
        soff = sec ? SZ : SR;
    } else {
        int l2 = tile - 8192; sec = 2 + (l2 >> 11); int l = l2 & 2047; jt = l >> 5; ks = l & 31; nks = 32;
        soff = (sec == 2) ? SNX : SNH;
    }
    int p = threadIdx.x;
    int e0 = (p & 3) * 2, ul = (p >> 2) & 15, hi = p >> 6;
    int u = jt * 16 + ul;
    int kk = ks * 32 + hi * 8 + e0;
    float2 w;
    if (sec < 2) {
        int row = (sec ? 1024 : 0) + u;
        if (kk < 1024) w = *(const float2*)&Wih[(size_t)row * UU + kk];
        else           w = *(const float2*)&Whh[(size_t)row * UU + kk - 1024];
    } else if (sec == 2) {
        w = *(const float2*)&Wih[(size_t)(2048 + u) * UU + kk];
    } else {
        w = *(const float2*)&Whh[(size_t)(2048 + u) * UU + kk];
    }
    ushort h0, l0, h1, l1;
    split2(w.x, h0, l0); split2(w.y, h1, l1);
    size_t ob = soff + ((((size_t)jt * nks + ks) * 4 + hi) * 16 + ul) * 8 + e0;
    *(uint*)(wp + ob)       = (uint)h0 | ((uint)h1 << 16);
    *(uint*)(wp + WPS + ob) = (uint)l0 | ((uint)l1 << 16);
}

// ---------------------------------------------------------------------------
// q_all[t][b][u] = sum_k inputs[b][t][k] * global_W[k][u]  (fp32)
// Register-blocked 256x128 tile GEMM. Summation order over k is strictly
// ascending — identical to the previous kernel, so q is bitwise unchanged.
// ---------------------------------------------------------------------------
__global__ __launch_bounds__(256)
void qall_kernel(const float* __restrict__ x,
                 const float* __restrict__ gW,
                 float* __restrict__ q) {
    __shared__ float xs[16][257];   // [k][r]
    __shared__ float gws[16][128];  // [k][n]
    const int r0 = blockIdx.x * 256, n0 = blockIdx.y * 128;
    const int tid = threadIdx.x;
    const int tr = tid & 31, tn = tid >> 5;
    float acc[8][16];
    #pragma unroll
    for (int i = 0; i < 8; ++i)
        #pragma unroll
        for (int j = 0; j < 16; ++j) acc[i][j] = 0.f;
    for (int k0 = 0; k0 < UU; k0 += 16) {
        {   // stage x: 256 rows x 16 k
            int rr = tid >> 2;
            const int f4 = (tid & 3) * 4;
            #pragma unroll
            for (int it = 0; it < 4; ++it, rr += 64) {
                const int r = r0 + rr;
                const int tt = r >> 5, bb = r & 31;
                float4 v = *(const float4*)&x[((size_t)bb * TT + tt) * UU + k0 + f4];
                xs[f4][rr] = v.x; xs[f4 + 1][rr] = v.y;
                xs[f4 + 2][rr] = v.z; xs[f4 + 3][rr] = v.w;
            }
        }
        {   // stage gW: 16 k x 128 n
            int kr = tid >> 5;
            const int nn = (tid & 31) * 4;
            #pragma unroll
            for (int it = 0; it < 2; ++it, kr += 8) {
                float4 v = *(const float4*)&gW[(size_t)(k0 + kr) * UU + n0 + nn];
                *(float4*)&gws[kr][nn] = v;
            }
        }
        __syncthreads();
        #pragma unroll
        for (int kk = 0; kk < 16; ++kk) {
            float xv[8];
            #pragma unroll
            for (int i = 0; i < 8; ++i) xv[i] = xs[kk][tr + 32 * i];
            float gv[16];
            #pragma unroll
            for (int j4 = 0; j4 < 4; ++j4) {
                float4 g = *(const float4*)&gws[kk][tn * 16 + j4 * 4];
                gv[j4 * 4] = g.x; gv[j4 * 4 + 1] = g.y;
                gv[j4 * 4 + 2] = g.z; gv[j4 * 4 + 3] = g.w;
            }
            #pragma unroll
            for (int i = 0; i < 8; ++i)
                #pragma unroll
                for (int j = 0; j < 16; ++j)
                    acc[i][j] += xv[i] * gv[j];
        }
        __syncthreads();
    }
    #pragma unroll
    for (int i = 0; i < 8; ++i) {
        const int r = r0 + tr + 32 * i;
        #pragma unroll
        for (int j4 = 0; j4 < 4; ++j4) {
            float4 v = {acc[i][j4 * 4], acc[i][j4 * 4 + 1],
                        acc[i][j4 * 4 + 2], acc[i][j4 * 4 + 3]};
            *(float4*)&q[(size_t)r * UU + n0 + tn * 16 + j4 * 4] = v;
        }
    }
}

// ---------------------------------------------------------------------------
// Init. bar layout (ints):
//   [0]=g_rel  [32]=p_rel  [64]=e_rel
//   [128 + cell*128 + slot*32] = class arrival ring counters (slot<4, monotone)
//   [512 + ab*16] = per-ab finisher-done counter
// cnt[ab] = att pair-arrival counter.
// ---------------------------------------------------------------------------
__global__ void init_kernel(const float* __restrict__ inputs,
                            const float* __restrict__ gbih, const float* __restrict__ gbhh,
                            const float* __restrict__ pbih, const float* __restrict__ pbhh,
                            const float* __restrict__ ebih, const float* __restrict__ ebhh,
                            float* __restrict__ hist, float* __restrict__ Pf,
                            ushort* __restrict__ gpack, ushort* __restrict__ ppack,
                            ushort* __restrict__ epack, float* __restrict__ biasp,
                            int* __restrict__ cnt, int* __restrict__ bar) {
    if (blockIdx.x == 0) {
        if (threadIdx.x < 32) cnt[threadIdx.x] = 0;
        for (int i = threadIdx.x; i < 1024; i += 256) bar[i] = 0;
    }
    if (blockIdx.x < 128) {
        int i = blockIdx.x * 256 + threadIdx.x;
        int b = i >> 10, u = i & 1023;
        hist[i] = 0.f;
        Pf[i] = 0.f; Pf[32768 + i] = 0.f;   // Pf slots 0 (t=0) and 1 (t=1)
        int ex = AEX(u, b);
        int eh = ex + 32768;
        gpack[eh] = 0; gpack[APS + eh] = 0;
        ppack[eh] = 0; ppack[APS + eh] = 0;
        ppack[ASLOT + eh] = 0; ppack[ASLOT + APS + eh] = 0;
        epack[eh] = 0; epack[APS + eh] = 0;
        float x0 = inputs[((size_t)b * TT + 0) * UU + u];
        float x1 = inputs[((size_t)b * TT + 1) * UU + u];
        ushort h, l;
        split2(x0, h, l); gpack[ex] = h; gpack[APS + ex] = l;
        split2(x1, h, l); gpack[ASLOT + ex] = h; gpack[ASLOT + APS + ex] = l;
    } else {
        int idx = (blockIdx.x - 128) * 256 + threadIdx.x;
        int cell = idx >> 12, g4 = (idx >> 10) & 3, u = idx & 1023;
        const float* bih = (cell == 0) ? gbih : (cell == 1) ? pbih : ebih;
        const float* bhh = (cell == 0) ? gbhh : (cell == 1) ? pbhh : ebhh;
        float v;
        if (g4 == 0) v = bih[u] + bhh[u];
        else if (g4 == 1) v = bih[1024 + u] + bhh[1024 + u];
        else if (g4 == 2) v = bih[2048 + u];
        else v = bhh[2048 + u];
        biasp[idx] = v;
    }
}

// ---------------------------------------------------------------------------
// Persistent kernel v3.2 (passing round-15 version, unchanged): dataflow
// pipeline with MIN-PROGRESS release words.
//   blocks [0,64)=g, [64,128)=p, [128,192)=e, [192,256)=att(ac,ab).
// X_rel = k  <=>  ALL 64 blocks of class X completed steps < k.
// Waits:
//   g(tc):  g_rel>=tc, p_rel>=tc-1
//   att(t): g_rel>=t, fin[ab]>=t
//   p(tc):  fin[ALL ab]>=tc+1, p_rel>=tc-1, e_rel>=tc-31
//   e(tc):  p_rel>=tc+1, e_rel>=tc
// Release publish: 64th epoch-tc arriver (ring counter old%64==63) does
// atomic_max(rel, tc+1).
// Cache policy: cached = hist/out/qall/inputs/biasp/wpack; agent loads =
// act rings, Pf, attC/attML. Stores sc1 + vm_drain before arrival adds.
// ---------------------------------------------------------------------------
__global__ __launch_bounds__(512)
__attribute__((amdgpu_waves_per_eu(2)))
void persist_kernel(const float* __restrict__ inputs,
                    const ushort* __restrict__ wpack,
                    const float* __restrict__ biasp,
                    ushort* __restrict__ gpack, ushort* __restrict__ ppack,
                    ushort* __restrict__ epack,
                    float* __restrict__ hist, float* __restrict__ Pf,
                    const float* __restrict__ qall,
                    float* __restrict__ out,
                    float* __restrict__ attC, float* __restrict__ attML,
                    int* __restrict__ cnt, int* __restrict__ bar) {
    extern __shared__ char smraw[];
    float* lds_scr  = (float*)(smraw + SCR_OFF);
    float* lds_red  = (float*)(smraw + RED_OFF);
    int*   lds_flag = (int*)(smraw + FLAG_OFF);

    const int blk = blockIdx.x, tid = threadIdx.x;
    const int cell = blk >> 6, jt = blk & 63;       // cell 3 => attention block
    const int w = tid >> 6, lane = tid & 63;
    const int l15 = lane & 15, hi4 = lane >> 4;
    const int ab = blk & 31, ac = (blk >> 5) & 1;   // attention task
    const ushort* wp = wpack + (size_t)cell * WCELL;

    if (cell < 3) {
        // ================= GEMM class (g / p / e) =================
        bf16x8 whiR[8], whiZ[8], whiN[8], wloN[8];
        const int ebt = tid >> 8, eli = (tid >> 2) & 63, ei = tid & 3;
        const int eb = ebt * 16 + (eli & 15);
        const int eu = jt * 16 + (eli >> 4) * 4 + ei;
        const int eex = AEX(eu, eb);
        #pragma unroll
        for (int i = 0; i < 8; ++i) {
            const int ks = w * 8 + i;
            const size_t aoff = ((size_t)(jt * 256 + ks * 4 + hi4)) * 128 + (size_t)l15 * 8;
            whiR[i] = *(const bf16x8*)(wp + SR + aoff);
            whiZ[i] = *(const bf16x8*)(wp + SZ + aoff);
            bf16x8 rlo = *(const bf16x8*)(wp + SR + WPS + aoff);
            bf16x8 zlo = *(const bf16x8*)(wp + SZ + WPS + aoff);
            *(bf16x8*)(smraw + (((w * 16 + i) * 64 + lane) << 4)) = rlo;
            *(bf16x8*)(smraw + (((w * 16 + 8 + i) * 64 + lane) << 4)) = zlo;
            const int ksn = (w & 3) * 8 + i;
            const size_t noff = ((size_t)(jt * 128 + ksn * 4 + hi4)) * 128 + (size_t)l15 * 8;
            const size_t sN = (w < 4) ? SNX : SNH;
            whiN[i] = *(const bf16x8*)(wp + sN + noff);
            wloN[i] = *(const bf16x8*)(wp + sN + WPS + noff);
        }
        const float* bc = biasp + cell * 4096;
        const float bR = bc[eu], bZ = bc[1024 + eu];
        const float bNI = bc[2048 + eu], bNH = bc[3072 + eu];
        ushort* apk = (cell == 0) ? gpack : (cell == 1) ? ppack : epack;
        __syncthreads();

        for (int tc = 0; tc < TT; ++tc) {
            // ---- lane-parallel min-progress waits (wave 0) ----
            if (w == 0) {
                const int* wptr; int wneed;
                if (cell == 0) {
                    if (lane == 0)      { wptr = bar;       wneed = tc; }      // g_rel
                    else if (lane == 1) { wptr = bar + 32;  wneed = tc - 1; }  // p_rel
                    else                { wptr = bar;       wneed = -2147483647; }
                } else if (cell == 1) {
                    if (lane < 32)       { wptr = bar + 512 + lane * 16; wneed = tc + 1; } // fin[all]
                    else if (lane == 32) { wptr = bar + 32; wneed = tc - 1; }  // p_rel
                    else if (lane == 33) { wptr = bar + 64; wneed = tc - 31; } // e_rel
                    else                 { wptr = bar;      wneed = -2147483647; }
                } else {
                    if (lane == 0)      { wptr = bar + 32;  wneed = tc + 1; }  // p_rel
                    else if (lane == 1) { wptr = bar + 64;  wneed = tc; }      // e_rel
                    else                { wptr = bar;       wneed = -2147483647; }
                }
                while (!__all(load_i32_ag(wptr) >= wneed))
                    __builtin_amdgcn_s_sleep(8);
            }
            __syncthreads();
            f32x4 aR0 = {0,0,0,0}, aR1 = {0,0,0,0};
            f32x4 aZ0 = {0,0,0,0}, aZ1 = {0,0,0,0};
            f32x4 aN0 = {0,0,0,0}, aN1 = {0,0,0,0};
            const ushort* ap = apk + (size_t)(tc & (RING - 1)) * ASLOT;
            const ushort* bbp = ap + ((size_t)hi4 * 32 + l15) * 8;
            #pragma unroll
            for (int i = 0; i < 8; ++i) {
                const int ks = w * 8 + i;
                const ushort* bp = bbp + (size_t)ks * 1024;
                bf16x8 bh0 = load_frag_ag(bp);
                bf16x8 bh1 = load_frag_ag(bp + 128);
                bf16x8 bl0 = load_frag_ag(bp + APS);
                bf16x8 bl1 = load_frag_ag(bp + APS + 128);
                bf16x8 rlo = *(const bf16x8*)(smraw + (((w * 16 + i) * 64 + lane) << 4));
                bf16x8 zlo = *(const bf16x8*)(smraw + (((w * 16 + 8 + i) * 64 + lane) << 4));
                aR0 = MF(whiR[i], bh0, aR0); aR0 = MF(whiR[i], bl0, aR0); aR0 = MF(rlo, bh0, aR0);
                aR1 = MF(whiR[i], bh1, aR1); aR1 = MF(whiR[i], bl1, aR1); aR1 = MF(rlo, bh1, aR1);
                aZ0 = MF(whiZ[i], bh0, aZ0); aZ0 = MF(whiZ[i], bl0, aZ0); aZ0 = MF(zlo, bh0, aZ0);
                aZ1 = MF(whiZ[i], bh1, aZ1); aZ1 = MF(whiZ[i], bl1, aZ1); aZ1 = MF(zlo, bh1, aZ1);
                aN0 = MF(whiN[i], bh0, aN0); aN0 = MF(whiN[i], bl0, aN0); aN0 = MF(wloN[i], bh0, aN0);
                aN1 = MF(whiN[i], bh1, aN1); aN1 = MF(whiN[i], bl1, aN1); aN1 = MF(wloN[i], bh1, aN1);
            }
            // ---- combine into registers (combiner thread == epilogue thread) ----
            float R, Z, iN, hN;
            *(f32x4*)&lds_scr[((0 * 8 + w) * 64 + lane) * 4] = aR0;
            *(f32x4*)&lds_scr[((1 * 8 + w) * 64 + lane) * 4] = aR1;
            __syncthreads();
            {
                float s = 0.f;
                #pragma unroll
                for (int w2 = 0; w2 < 8; ++w2) s += lds_scr[((ebt * 8 + w2) * 64 + eli) * 4 + ei];
                R = s;
            }
            __syncthreads();
            *(f32x4*)&lds_scr[((0 * 8 + w) * 64 + lane) * 4] = aZ0;
            *(f32x4*)&lds_scr[((1 * 8 + w) * 64 + lane) * 4] = aZ1;
            __syncthreads();
            {
                float s = 0.f;
                #pragma unroll
                for (int w2 = 0; w2 < 8; ++w2) s += lds_scr[((ebt * 8 + w2) * 64 + eli) * 4 + ei];
                Z = s;
            }
            __syncthreads();
            *(f32x4*)&lds_scr[((0 * 8 + w) * 64 + lane) * 4] = aN0;
            *(f32x4*)&lds_scr[((1 * 8 + w) * 64 + lane) * 4] = aN1;
            __syncthreads();
            {
                float si = 0.f, sh = 0.f;
                #pragma unroll
                for (int w2 = 0; w2 < 4; ++w2) si += lds_scr[((ebt * 8 + w2) * 64 + eli) * 4 + ei];
                #pragma unroll
                for (int w2 = 4; w2 < 8; ++w2) sh += lds_scr[((ebt * 8 + w2) * 64 + eli) * 4 + ei];
                iN = si; hN = sh;
            }
            // ---- epilogue (1 output/thread), cross-block stores sc1 ----
            {
                float hprev;
                if (cell == 0)      hprev = hist[((size_t)tc * BB + eb) * UU + eu];
                else if (cell == 1) hprev = load_f32_ag(&Pf[(size_t)(tc & (RING - 1)) * BB * UU + (size_t)eb * UU + eu]);
                else                hprev = (tc > 0) ? out[((size_t)eb * TT + tc - 1) * UU + eu] : 0.f;
                const float r = 1.f / (1.f + expf(-(R + bR)));
                const float z = 1.f / (1.f + expf(-(Z + bZ)));
                const float n2 = tanhf(iN + bNI + r * (hN + bNH));
                const float val = (1.f - z) * n2 + z * hprev;
                ushort vh, vl; split2(val, vh, vl);
                if (cell == 0) {
                    store_f32_sc(&hist[((size_t)(tc + 1) * BB + eb) * UU + eu], val);
                    ushort* d = gpack + (size_t)((tc + 1) & (RING - 1)) * ASLOT;
                    store_u16_sc(d + eex + 32768, vh);
                    store_u16_sc(d + APS + eex + 32768, vl);
                } else if (cell == 1) {
                    ushort* d = epack + (size_t)(tc & (RING - 1)) * ASLOT;
                    store_u16_sc(d + eex, vh);
                    store_u16_sc(d + APS + eex, vl);
                    if (tc + 2 < TT) {
                        store_f32_sc(&Pf[(size_t)((tc + 2) & (RING - 1)) * BB * UU + (size_t)eb * UU + eu], val);
                        ushort* d2 = ppack + (size_t)((tc + 2) & (RING - 1)) * ASLOT;
                        store_u16_sc(d2 + eex + 32768, vh);
                        store_u16_sc(d2 + APS + eex + 32768, vl);
                        const float gx = val + inputs[((size_t)eb * TT + tc + 2) * UU + eu];
                        ushort gh, gl; split2(gx, gh, gl);
                        ushort* d3 = gpack + (size_t)((tc + 2) & (RING - 1)) * ASLOT;
                        store_u16_sc(d3 + eex, gh);
                        store_u16_sc(d3 + APS + eex, gl);
                    }
                } else {
                    store_f32_sc(&out[((size_t)eb * TT + tc) * UU + eu], val);
                    if (tc + 1 < TT) {
                        ushort* d = epack + (size_t)((tc + 1) & (RING - 1)) * ASLOT;
                        store_u16_sc(d + eex + 32768, vh);
                        store_u16_sc(d + APS + eex + 32768, vl);
                    }
                }
            }
            vm_drain();
            __syncthreads();
            if (tid == 0) {
                int* ring = bar + 128 + cell * 128 + (tc & 3) * 32;
                int old = __hip_atomic_fetch_add(ring, 1, __ATOMIC_RELAXED,
                                                 __HIP_MEMORY_SCOPE_AGENT);
                if ((old & 63) == 63) {
                    (void)__hip_atomic_fetch_max(bar + cell * 32, tc + 1,
                                                 __ATOMIC_RELAXED, __HIP_MEMORY_SCOPE_AGENT);
                }
            }
        }
    } else {
        // ================= attention class (ac, ab) =================
        int* fin = bar + 512 + ab * 16;
        for (int t = 0; t < TT; ++t) {
            if (w == 0) {
                const int* wptr; int wneed;
                if (lane == 0)      { wptr = bar; wneed = t; }   // g_rel >= t
                else if (lane == 1) { wptr = fin; wneed = t; }   // finisher of t-1 done
                else                { wptr = bar; wneed = -2147483647; }
                while (!__all(load_i32_ag(wptr) >= wneed))
                    __builtin_amdgcn_s_sleep(8);
            }
            __syncthreads();
            const int slot = t & 3;
            float* aC = attC + (((size_t)slot * NCHUNK + ac) * BB + ab) * UU;
            float* aML = attML + (((size_t)slot * NCHUNK + ac) * BB + ab) * 2;
            const int nt2 = t + 1;
            const int cstr = (nt2 + NCHUNK - 1) / NCHUNK;
            const int r0 = ac * cstr;
            const int r1x = r0 + cstr;
            const int r1 = (r1x < nt2) ? r1x : nt2;
            const int n = r1 - r0;
            if (n <= 0) {
                #pragma unroll
                for (int rep = 0; rep < 2; ++rep)
                    store_f32_sc(aC + tid + rep * 512, 0.f);
                if (tid == 0) {
                    store_f32_sc(aML, -INFINITY);
                    store_f32_sc(aML + 1, 0.f);
                }
            } else {
                const float* qb = qall + ((size_t)t * BB + ab) * UU;
                float4 q0 = *(const float4*)&qb[lane * 4];
                float4 q1 = *(const float4*)&qb[256 + lane * 4];
                float4 q2 = *(const float4*)&qb[512 + lane * 4];
                float4 q3 = *(const float4*)&qb[768 + lane * 4];
                float m_run = -INFINITY, l_run = 0.f;
                float4 c0 = {0,0,0,0}, c1 = {0,0,0,0}, c2 = {0,0,0,0}, c3 = {0,0,0,0};
                for (int tp = r0 + w; tp < r1; tp += 8) {
                    const float* hr = hist + ((size_t)tp * BB + ab) * UU;
                    float4 h0 = *(const float4*)&hr[lane * 4];
                    float4 h1 = *(const float4*)&hr[256 + lane * 4];
                    float4 h2 = *(const float4*)&hr[512 + lane * 4];
                    float4 h3 = *(const float4*)&hr[768 + lane * 4];
                    float s = h0.x*q0.x + h0.y*q0.y + h0.z*q0.z + h0.w*q0.w
                            + h1.x*q1.x + h1.y*q1.y + h1.z*q1.z + h1.w*q1.w
                            + h2.x*q2.x + h2.y*q2.y + h2.z*q2.z + h2.w*q2.w
                            + h3.x*q3.x + h3.y*q3.y + h3.z*q3.z + h3.w*q3.w;
                    #pragma unroll
                    for (int off = 32; off; off >>= 1) s += __shfl_xor(s, off);
                    const float mn = fmaxf(m_run, s);
                    const float sc = expf(m_run - mn);
                    const float e2 = expf(s - mn);
                    c0.x = c0.x*sc + e2*h0.x; c0.y = c0.y*sc + e2*h0.y; c0.z = c0.z*sc + e2*h0.z; c0.w = c0.w*sc + e2*h0.w;
                    c1.x = c1.x*sc + e2*h1.x; c1.y = c1.y*sc + e2*h1.y; c1.z = c1.z*sc + e2*h1.z; c1.w = c1.w*sc + e2*h1.w;
                    c2.x = c2.x*sc + e2*h2.x; c2.y = c2.y*sc + e2*h2.y; c2.z = c2.z*sc + e2*h2.z; c2.w = c2.w*sc + e2*h2.w;
                    c3.x = c3.x*sc + e2*h3.x; c3.y = c3.y*sc + e2*h3.y; c3.z = c3.z*sc + e2*h3.z; c3.w = c3.w*sc + e2*h3.w;
                    l_run = l_run * sc + e2;
                    m_run = mn;
                }
                *(float4*)&lds_scr[w * 512 + lane * 4] = c0;
                *(float4*)&lds_scr[w * 512 + 256 + lane * 4] = c1;
                if (lane == 0) { lds_red[w] = m_run; lds_red[8 + w] = l_run; }
                __syncthreads();
                float M = lds_red[0];
                #pragma unroll
                for (int k = 1; k < 8; ++k) M = fmaxf(M, lds_red[k]);
                float ww[8], L = 0.f;
                #pragma unroll
                for (int k = 0; k < 8; ++k) { ww[k] = expf(lds_red[k] - M); L += ww[k] * lds_red[8 + k]; }
                if (tid == 0) {
                    store_f32_sc(aML, M);
                    store_f32_sc(aML + 1, L);
                }
                {
                    float s = 0.f;
                    #pragma unroll
                    for (int w2 = 0; w2 < 8; ++w2) s += ww[w2] * lds_scr[w2 * 512 + tid];
                    store_f32_sc(aC + tid, s);
                }
                __syncthreads();
                *(float4*)&lds_scr[w * 512 + lane * 4] = c2;
                *(float4*)&lds_scr[w * 512 + 256 + lane * 4] = c3;
                __syncthreads();
                {
                    float s = 0.f;
                    #pragma unroll
                    for (int w2 = 0; w2 < 8; ++w2) s += ww[w2] * lds_scr[w2 * 512 + tid];
                    store_f32_sc(aC + 512 + tid, s);
                }
            }
            // publish chunk, pair handshake (arrivals for step t are {2t, 2t+1})
            vm_drain();
            __syncthreads();
            if (tid == 0) {
                int old = __hip_atomic_fetch_add(cnt + ab, 1, __ATOMIC_RELAXED,
                                                 __HIP_MEMORY_SCOPE_AGENT);
                lds_flag[0] = (old & 1);
            }
            __syncthreads();
            if (lds_flag[0]) {
                // Finisher (2nd arriver of this step): merge 2 partials (agent loads).
                float mm[NCHUNK], ll[NCHUNK];
                #pragma unroll
                for (int c = 0; c < NCHUNK; ++c) {
                    const float* ml = attML + (((size_t)slot * NCHUNK + c) * BB + ab) * 2;
                    mm[c] = load_f32_ag(ml);
                    ll[c] = load_f32_ag(ml + 1);
                }
                float M2 = mm[0];
                #pragma unroll
                for (int c = 1; c < NCHUNK; ++c) M2 = fmaxf(M2, mm[c]);
                float den = 0.f, wc[NCHUNK];
                #pragma unroll
                for (int c = 0; c < NCHUNK; ++c) { wc[c] = expf(mm[c] - M2); den += wc[c] * ll[c]; }
                const float inv = 1.f / den;
                ushort* d = ppack + (size_t)(t & (RING - 1)) * ASLOT;
                #pragma unroll
                for (int rep = 0; rep < 2; ++rep) {
                    const int e = tid + rep * 512;
                    float s3 = 0.f;
                    #pragma unroll
                    for (int c = 0; c < NCHUNK; ++c)
                        s3 += wc[c] * load_f32_ag(&attC[(((size_t)slot * NCHUNK + c) * BB + ab) * UU + e]);
                    const float xv = s3 * inv + inputs[((size_t)ab * TT + t) * UU + e];
                    ushort vh2, vl2; split2(xv, vh2, vl2);
                    const int ex2 = AEX(e, ab);
                    store_u16_sc(d + ex2, vh2);
                    store_u16_sc(d + APS + ex2, vl2);
                }
                vm_drain();
            }
            __syncthreads();
            if (tid == 0 && lds_flag[0])
                __hip_atomic_fetch_add(fin, 1, __ATOMIC_RELAXED, __HIP_MEMORY_SCOPE_AGENT);
        }
    }
}

extern "C" void kernel_launch(void* const* d_in, const int* in_sizes, int n_in,
                              void* d_out, int out_size, void* d_ws, size_t ws_size,
                              hipStream_t stream) {
    (void)in_sizes; (void)n_in; (void)out_size; (void)ws_size;
    const float* inputs = (const float*)d_in[0];
    const float* gW   = (const float*)d_in[1];
    const float* gWih = (const float*)d_in[2];
    const float* gWhh = (const float*)d_in[3];
    const float* gbih = (const float*)d_in[4];
    const float* gbhh = (const float*)d_in[5];
    const float* pWih = (const float*)d_in[6];
    const float* pWhh = (const float*)d_in[7];
    const float* pbih = (const float*)d_in[8];
    const float* pbhh = (const float*)d_in[9];
    const float* eWih = (const float*)d_in[10];
    const float* eWhh = (const float*)d_in[11];
    const float* ebih = (const float*)d_in[12];
    const float* ebhh = (const float*)d_in[13];
    float* out = (float*)d_out;

    char* ws = (char*)d_ws;
    size_t off = 0;
    auto alloc = [&](size_t bytes) {
        void* p = ws + off;
        off += (bytes + 255) & ~(size_t)255;
        return p;
    };
    ushort* wpack = (ushort*)alloc((size_t)3 * WCELL * 2);
    ushort* gpack = (ushort*)alloc((size_t)RING * ASLOT * 2);
    ushort* ppack = (ushort*)alloc((size_t)RING * ASLOT * 2);
    ushort* epack = (ushort*)alloc((size_t)RING * ASLOT * 2);
    float* hist  = (float*)alloc((size_t)(TT + 1) * BB * UU * 4);
    float* qall  = (float*)alloc((size_t)TT * BB * UU * 4);
    float* Pf    = (float*)alloc((size_t)RING * BB * UU * 4);
    float* biasp = (float*)alloc((size_t)3 * 4096 * 4);
    float* attC  = (float*)alloc((size_t)4 * NCHUNK * BB * UU * 4);   // 4-slot parity
    float* attML = (float*)alloc((size_t)4 * NCHUNK * BB * 2 * 4);
    int*   cnt   = (int*)alloc(32 * 4);
    int*   bar   = (int*)alloc(1024 * 4);

    packw_kernel<<<36864, 256, 0, stream>>>(gWih, gWhh, pWih, pWhh, eWih, eWhh, wpack);
    qall_kernel<<<dim3(32, 8), 256, 0, stream>>>(inputs, gW, qall);
    init_kernel<<<176, 256, 0, stream>>>(inputs, gbih, gbhh, pbih, pbhh, ebih, ebhh,
                                         hist, Pf, gpack, ppack, epack, biasp, cnt, bar);

    hipFuncSetAttribute((const void*)persist_kernel,
                        hipFuncAttributeMaxDynamicSharedMemorySize, LDSB);
    void* args[] = {(void*)&inputs, (void*)&wpack, (void*)&biasp,
                    (void*)&gpack, (void*)&ppack, (void*)&epack,
                    (void*)&hist, (void*)&Pf, (void*)&qall, (void*)&out,
                    (void*)&attC, (void*)&attML, (void*)&cnt, (void*)&bar};
    hipError_t ce = hipLaunchCooperativeKernel((const void*)persist_kernel,
                                               dim3(GRIDN), dim3(512), args,
                                               (unsigned)LDSB, stream);
    if (ce != hipSuccess) {
        (void)hipGetLastError();
        // 256 blocks at 1 block/CU on a 256-CU part are co-resident; the
        // monotone-counter dataflow is safe under a plain launch too.
        persist_kernel<<<GRIDN, 512, LDSB, stream>>>(inputs, wpack, biasp,
                                                     gpack, ppack, epack,
                                                     hist, Pf, qall, out,
                                                     attC, attML, cnt, bar);
    }
}